// Round 6
// baseline (704.814 us; speedup 1.0000x reference)
//
#include <hip/hip_runtime.h>
#include <hip/hip_bf16.h>

#define Nn 100000
#define Ee 1000000
#define INF_ 100
#define Hh 4
#define Dd 32
#define HD 128
#define Cc 47
#define HC 188
#define HCP 192
#define EPSV 1e-5f
#define SLOPE 0.2f
#define NBLK ((Nn + 255) / 256)

typedef __hip_bfloat16 bf16;
typedef __attribute__((ext_vector_type(8))) short short8;
typedef __attribute__((ext_vector_type(4))) float f32x4;
typedef __attribute__((ext_vector_type(2))) float f32x2;

__device__ __forceinline__ float tof(bf16 v) { return __bfloat162float(v); }
__device__ __forceinline__ float b2f(unsigned short u) {
    return __uint_as_float((unsigned)u << 16);
}
__device__ __forceinline__ float b2flo(unsigned u) {
    return __uint_as_float(u << 16);
}
__device__ __forceinline__ float b2fhi(unsigned u) {
    return __uint_as_float(u & 0xFFFF0000u);
}
__device__ __forceinline__ float ldb(const bf16* p) {
    return b2f(*(const unsigned short*)p);
}
__device__ __forceinline__ unsigned short f2u(float v) {
    bf16 t = __float2bfloat16(v);
    return *(unsigned short*)&t;
}
__device__ __forceinline__ f32x2 pk2(float x, float y) {
    f32x2 r; r.x = x; r.y = y; return r;
}
__device__ __forceinline__ f32x2 pabs2(f32x2 v) {          // v_pk_max_f32 v, -v
    return __builtin_elementwise_max(v, -v);
}
__device__ __forceinline__ f32x2 pfma2(f32x2 a, f32x2 b, f32x2 c) {
    return __builtin_elementwise_fma(a, b, c);             // v_pk_fma_f32
}

// DPP-fused 16-lane reduces (quad_perm swaps + row rotates; row=16 lanes).
template <int C>
__device__ __forceinline__ float dppadd(float v) {
    int m = __builtin_amdgcn_update_dpp(0, __float_as_int(v), C, 0xF, 0xF, false);
    return v + __int_as_float(m);
}
template <int C>
__device__ __forceinline__ float dppmax(float v) {
    int m = __builtin_amdgcn_update_dpp(0, __float_as_int(v), C, 0xF, 0xF, false);
    return fmaxf(v, __int_as_float(m));
}
__device__ __forceinline__ float sum16(float p) {
    p = dppadd<0xB1>(p);   // quad_perm [1,0,3,2]
    p = dppadd<0x4E>(p);   // quad_perm [2,3,0,1]
    p = dppadd<0x124>(p);  // row_ror:4
    p = dppadd<0x128>(p);  // row_ror:8
    return p;
}
__device__ __forceinline__ float max16(float p) {
    p = dppmax<0xB1>(p); p = dppmax<0x4E>(p);
    p = dppmax<0x124>(p); p = dppmax<0x128>(p);
    return p;
}

#define L2E 1.4426950408889634f
#define LN2 0.6931471805599453f

// ---------------- dtype detect: 1 = bf16 buffers, 0 = fp32 buffers ----------------
__global__ void detect_dtype(const unsigned* __restrict__ x, int* __restrict__ flag) {
    if (blockIdx.x == 0 && threadIdx.x == 0) {
        int good = 0;
        for (int i = 0; i < 256; ++i) {
            unsigned lo = x[i] & 0xFFFFu;
            float v = __uint_as_float(lo << 16);
            float a = fabsf(v);
            if (a > 1e-4f && a < 10.f) good++;
        }
        *flag = (good >= 128) ? 1 : 0;
    }
}

__device__ __forceinline__ float ld_any(const void* p, int i, int isbf) {
    return isbf ? tof(((const bf16*)p)[i]) : ((const float*)p)[i];
}

// ---------------- x -> canonical bf16, padded to row stride 128 ----------------
__global__ void cvt_x(const void* __restrict__ in, bf16* __restrict__ out,
                      const int* __restrict__ flag) {
    int i = blockIdx.x * blockDim.x + threadIdx.x;
    if (i >= Nn * 128) return;
    int row = i >> 7, col = i & 127;
    float v = (col < INF_) ? ld_any(in, row * INF_ + col, *flag) : 0.f;
    out[i] = __float2bfloat16(v);
}

// ---------------- small params (biases/attn/bn) -> canonical bf16 ----------------
#define NSP 15
struct CvtTab { const void* src[NSP]; int off[NSP + 1]; };

__global__ void cvt_params(CvtTab t, bf16* __restrict__ out, int total,
                           const int* __restrict__ flag) {
    int i = blockIdx.x * blockDim.x + threadIdx.x;
    if (i >= total) return;
    int isbf = *flag;
    int seg = 0;
    while (i >= t.off[seg + 1]) seg++;
    out[i] = __float2bfloat16(ld_any(t.src[seg], i - t.off[seg], isbf));
}

// ---------------- all 8 weight mats -> packed transposed Wt[1280][128] ----------------
#define WROWS 1280
struct PrepTab { const void* src[8]; int row0[8]; int K[8]; int M[8]; int MP[8]; };

__global__ void prep_all(PrepTab t, bf16* __restrict__ wtb, const int* __restrict__ flag) {
    int i = blockIdx.x * blockDim.x + threadIdx.x;
    if (i >= WROWS * 128) return;
    int row = i >> 7, k = i & 127;
    int isbf = *flag;
    float v = 0.f;
#pragma unroll
    for (int q = 0; q < 8; ++q) {
        if (row >= t.row0[q] && row < t.row0[q] + t.MP[q]) {
            int m = row - t.row0[q];
            if (m < t.M[q] && k < t.K[q])
                v = ld_any(t.src[q], k * t.M[q] + m, isbf);
        }
    }
    wtb[i] = __float2bfloat16(v);
}

__global__ void zero_u32(unsigned* __restrict__ p, int n) {
    int i = blockIdx.x * blockDim.x + threadIdx.x;
    if (i < n) p[i] = 0u;
}

// ---------------- fused: CSR build (lower_bound) + pre-scaled src byte offsets ----
__global__ void src_scale_ptr(const int* __restrict__ src, const int* __restrict__ dst,
                              unsigned* __restrict__ w384, unsigned* __restrict__ w256,
                              int* __restrict__ ptr) {
    int i = blockIdx.x * blockDim.x + threadIdx.x;
    if (i < Ee) {
        unsigned s = (unsigned)src[i];
        w384[i] = s * 384u;  // stride HCP*2 bytes (layer-2 split-pack fs)
        w256[i] = s << 8;    // stride HD*2 bytes  (layer-0/1 fs)
    }
    if (i <= Nn) {
        if (i == Nn) { ptr[Nn] = Ee; return; }
        int lo = 0, hi = Ee;
        while (lo < hi) {
            int mid = (lo + hi) >> 1;
            if (dst[mid] < i) lo = mid + 1; else hi = mid;
        }
        ptr[i] = lo;
    }
}

// ---------------- degree-descending LPT permutation (block counting sort) ---------
// NO global atomics, NO serial single-CU scans. cnt/base are BIN-MAJOR
// [bin][NBLK] so per-bin walks coalesce across lanes.
__global__ void deg_hist_blk(const int* __restrict__ ptr, int* __restrict__ cnt) {
    __shared__ int lh[256];
    int t = threadIdx.x;
    lh[t] = 0;
    __syncthreads();
    int n = blockIdx.x * 256 + t;
    if (n < Nn) {
        int dg = ptr[n + 1] - ptr[n]; if (dg > 255) dg = 255;
        atomicAdd(&lh[dg], 1);
    }
    __syncthreads();
    cnt[t * NBLK + blockIdx.x] = lh[t];
}

// one wave per bin (64 blocks x 4 waves): lane-strided coalesced total
__global__ void deg_totals(const int* __restrict__ cnt, int* __restrict__ totals) {
    int wave = threadIdx.x >> 6, lane = threadIdx.x & 63;
    int bin = blockIdx.x * 4 + wave;
    int s = 0;
    for (int k = lane; k < NBLK; k += 64) s += cnt[bin * NBLK + k];
#pragma unroll
    for (int o = 1; o < 64; o <<= 1) s += __shfl_xor(s, o);
    if (lane == 0) totals[bin] = s;
}

// one wave per bin: binbase = sum of totals over HIGHER-degree bins, then
// chunked 64-lane exclusive prefix over the NBLK per-block counts.
__global__ void deg_bases(const int* __restrict__ cnt, const int* __restrict__ totals,
                          int* __restrict__ base) {
    int wave = threadIdx.x >> 6, lane = threadIdx.x & 63;
    int bin = blockIdx.x * 4 + wave;
    int bb = 0;
    for (int b = bin + 1 + lane; b < 256; b += 64) bb += totals[b];
#pragma unroll
    for (int o = 1; o < 64; o <<= 1) bb += __shfl_xor(bb, o);
    int run = bb;   // descending-degree base for this bin
    for (int k0 = 0; k0 < NBLK; k0 += 64) {
        int k = k0 + lane;
        int c = (k < NBLK) ? cnt[bin * NBLK + k] : 0;
        int p = c;
#pragma unroll
        for (int o = 1; o < 64; o <<= 1) {
            int t = __shfl_up(p, o);
            if (lane >= o) p += t;
        }
        if (k < NBLK) base[bin * NBLK + k] = run + (p - c);
        run += __shfl(p, 63);
    }
}

__global__ void deg_scatter_blk(const int* __restrict__ ptr, const int* __restrict__ base,
                                int* __restrict__ perm) {
    __shared__ int lh[256];
    int t = threadIdx.x;
    lh[t] = 0;
    __syncthreads();
    int n = blockIdx.x * 256 + t;
    if (n < Nn) {
        int dg = ptr[n + 1] - ptr[n]; if (dg > 255) dg = 255;
        int loc = atomicAdd(&lh[dg], 1);   // LDS atomic: one CU, cheap
        perm[base[dg * NBLK + blockIdx.x] + loc] = n;
    }
}

// ---------------- big-tile MFMA GEMM: 64 rows x (64*CS*NY) cols per block ----------
// A staged in LDS ONCE, then NY sequential column-group passes (no A refetch,
// no extra VGPR: acc reused per pass).
// PACK (layer-2 split layout): col lc -> h=lc/47, cc=lc%47, j=cc&15, k=cc>>4,
// lane l=16h+j; k<2 -> elem 2l+k (dword zone); k=2 -> elem 128+l (ushort zone).
template <int MP, int NOUT, int CS, bool ABN, bool PACK, int OSTR, int NY>
__global__ __launch_bounds__(256, 4) void gemm_big(
    const bf16* __restrict__ A, const bf16* __restrict__ Wt,
    const bf16* __restrict__ b0, const bf16* __restrict__ b1,
    const bf16* __restrict__ b2,
    bf16* __restrict__ o0, bf16* __restrict__ o1, bf16* __restrict__ o2,
    int MR, const float* __restrict__ bnp) {
    __shared__ __align__(16) bf16 Al[64 * 136];
    const int row0 = blockIdx.x * 64;
    const int tid = threadIdx.x;
#pragma unroll
    for (int j = 0; j < 4; ++j) {
        int idx = tid + j * 256;          // 0..1023 int4 slots
        int r = idx >> 4, kk = (idx & 15) * 8;
        int4 val = {0, 0, 0, 0};
        if (row0 + r < Nn) {
            val = *(const int4*)&A[(size_t)(row0 + r) * 128 + kk];
            if (ABN) {
                short8 av = *(short8*)&val;
                bf16 tmp[8];
#pragma unroll
                for (int u = 0; u < 8; ++u) {
                    float v = b2f((unsigned short)av[u]);
                    v = fmaxf(fmaf(v, bnp[kk + u], bnp[128 + kk + u]), 0.f);
                    tmp[u] = __float2bfloat16(v);
                }
                val = *(int4*)tmp;
            }
        }
        *(int4*)&Al[r * 136 + kk] = val;
    }
    __syncthreads();
    const int wave = tid >> 6, lane = tid & 63;
    const int n16 = lane & 15, quad = lane >> 4;
    const bf16* ap = Al + n16 * 136 + quad * 8;
#pragma unroll
    for (int ny = 0; ny < NY; ++ny) {
        const int colbase = ny * (64 * CS) + wave * (16 * CS);
        f32x4 acc[4][CS];
#pragma unroll
        for (int rt = 0; rt < 4; ++rt)
#pragma unroll
            for (int c = 0; c < CS; ++c) acc[rt][c] = (f32x4){0.f, 0.f, 0.f, 0.f};
        const bf16* wb[CS];
#pragma unroll
        for (int c = 0; c < CS; ++c)
            wb[c] = Wt + (size_t)(colbase + c * 16 + n16) * 128 + quad * 8;
#pragma unroll
        for (int ks = 0; ks < 4; ++ks) {
            short8 bf[CS];
#pragma unroll
            for (int c = 0; c < CS; ++c) bf[c] = *(const short8*)(wb[c] + ks * 32);
#pragma unroll
            for (int rt = 0; rt < 4; ++rt) {
                short8 af = *(const short8*)(ap + rt * 16 * 136 + ks * 32);
#pragma unroll
                for (int c = 0; c < CS; ++c)
                    acc[rt][c] = __builtin_amdgcn_mfma_f32_16x16x32_bf16(af, bf[c], acc[rt][c], 0, 0, 0);
            }
        }
#pragma unroll
        for (int c = 0; c < CS; ++c) {
            int col = colbase + c * 16 + n16;
            int oi = col / MP, lc = col - oi * MP;
            if (oi >= NOUT || lc >= MR) continue;
            const bf16* bp = (oi == 0) ? b0 : (oi == 1) ? b1 : b2;
            bf16* o = (oi == 0) ? o0 : (oi == 1) ? o1 : o2;
            float bb = tof(bp[lc]);
            int st;
            if (PACK) {
                int hh = lc / 47, cc = lc - hh * 47;
                int jj = cc & 15, kk2 = cc >> 4;
                int l = hh * 16 + jj;
                st = (kk2 < 2) ? (2 * l + kk2) : (128 + l);
            } else {
                st = lc;
            }
#pragma unroll
            for (int rt = 0; rt < 4; ++rt) {
#pragma unroll
                for (int i = 0; i < 4; ++i) {
                    int row = row0 + rt * 16 + quad * 4 + i;
                    if (row < Nn)
                        o[(size_t)row * OSTR + st] = __float2bfloat16(acc[rt][c][i] + bb);
                }
            }
        }
    }
}

// ---------------- fused GATv2 edge kernel, M=128 (layers 0,1) ----------------
// One wave per dst (degree-sorted via perm); lane holds cols (2*lane, 2*lane+1).
// MAX-FREE softmax with log2e folded into attn consts (v_exp direct).
// Packed-FP32 math; aligned uint4 srcW prefetch (1 VMEM per 4 edges).
template <bool RESBN>
__global__ __launch_bounds__(256) void gat_fused_128(
    const bf16* __restrict__ fs, const bf16* __restrict__ fd,
    const unsigned* __restrict__ srcW, const int* __restrict__ ptr,
    const int* __restrict__ perm,
    const bf16* __restrict__ attn, const bf16* __restrict__ resb,
    const float* __restrict__ bnp, bf16* __restrict__ hout) {
    const int wave = threadIdx.x >> 6, lane = threadIdx.x & 63;
    const int di = blockIdx.x * 4 + wave;
    if (di >= Nn) return;
    const int d = perm[di];
    const int c0 = lane * 2;
    const unsigned c0b = (unsigned)c0 * 2u;
    ushort2 aq = *(const ushort2*)&attn[c0];
    float a0 = b2f(aq.x) * L2E, a1 = b2f(aq.y) * L2E;
    const f32x2 Av = pk2(0.6f * a0, 0.6f * a1);
    const f32x2 Bv = pk2(0.4f * a0, 0.4f * a1);
    ushort2 dq = *(const ushort2*)&fd[(size_t)d * HD + c0];
    const f32x2 fdv = pk2(b2f(dq.x), b2f(dq.y));
    const char* fsb = (const char*)fs;
    float l = 0.f;
    f32x2 Ov = pk2(0.f, 0.f);
    int e = ptr[d];
    const int e1 = ptr[d + 1];
    // peel to 4-alignment so the main loop can use one aligned uint4 load
    for (; e < e1 && (e & 3); ++e) {
        unsigned v = srcW[e] + c0b;
        ushort2 fq = *(const ushort2*)(fsb + v);
        f32x2 f = pk2(b2f(fq.x), b2f(fq.y));
        f32x2 x = f + fdv;
        f32x2 t = pfma2(pabs2(x), Bv, x * Av);
        float p = sum16(t.x + t.y);
        float pe = __builtin_amdgcn_exp2f(p);
        l += pe;
        Ov = pfma2(pk2(pe, pe), f, Ov);
    }
    for (; e + 3 < e1; e += 4) {
        uint4 sw = *(const uint4*)&srcW[e];
        unsigned vA = sw.x + c0b, vB = sw.y + c0b;
        unsigned vC = sw.z + c0b, vD = sw.w + c0b;
        ushort2 qA = *(const ushort2*)(fsb + vA);
        ushort2 qB = *(const ushort2*)(fsb + vB);
        ushort2 qC = *(const ushort2*)(fsb + vC);
        ushort2 qD = *(const ushort2*)(fsb + vD);
        f32x2 fA = pk2(b2f(qA.x), b2f(qA.y));
        f32x2 fB = pk2(b2f(qB.x), b2f(qB.y));
        f32x2 fC = pk2(b2f(qC.x), b2f(qC.y));
        f32x2 fD = pk2(b2f(qD.x), b2f(qD.y));
        f32x2 xA = fA + fdv, xB = fB + fdv, xC = fC + fdv, xD = fD + fdv;
        f32x2 tA = pfma2(pabs2(xA), Bv, xA * Av);
        f32x2 tB = pfma2(pabs2(xB), Bv, xB * Av);
        f32x2 tC = pfma2(pabs2(xC), Bv, xC * Av);
        f32x2 tD = pfma2(pabs2(xD), Bv, xD * Av);
        float pA = tA.x + tA.y, pB = tB.x + tB.y;
        float pC = tC.x + tC.y, pD = tD.x + tD.y;
        pA = sum16(pA); pB = sum16(pB); pC = sum16(pC); pD = sum16(pD);
        float eA = __builtin_amdgcn_exp2f(pA), eB = __builtin_amdgcn_exp2f(pB);
        float eC = __builtin_amdgcn_exp2f(pC), eD = __builtin_amdgcn_exp2f(pD);
        l += (eA + eB) + (eC + eD);
        Ov = pfma2(pk2(eA, eA), fA, Ov);
        Ov = pfma2(pk2(eB, eB), fB, Ov);
        Ov = pfma2(pk2(eC, eC), fC, Ov);
        Ov = pfma2(pk2(eD, eD), fD, Ov);
    }
    for (; e < e1; ++e) {
        unsigned v = srcW[e] + c0b;
        ushort2 fq = *(const ushort2*)(fsb + v);
        f32x2 f = pk2(b2f(fq.x), b2f(fq.y));
        f32x2 x = f + fdv;
        f32x2 t = pfma2(pabs2(x), Bv, x * Av);
        float p = sum16(t.x + t.y);
        float pe = __builtin_amdgcn_exp2f(p);
        l += pe;
        Ov = pfma2(pk2(pe, pe), f, Ov);
    }
    float inv = l > 0.f ? 1.f / l : 0.f;
    ushort2 rq = *(const ushort2*)&resb[(size_t)d * HD + c0];
    float r0 = b2f(rq.x), r1 = b2f(rq.y);
    if (RESBN) {
        r0 = fmaxf(fmaf(r0, bnp[c0], bnp[HD + c0]), 0.f);
        r1 = fmaxf(fmaf(r1, bnp[c0 + 1], bnp[HD + c0 + 1]), 0.f);
    }
    float v0 = fmaxf(fmaf(Ov.x, inv, r0), 0.f);  // conv activation relu
    float v1 = fmaxf(fmaf(Ov.y, inv, r1), 0.f);
    ushort2 ov; ov.x = f2u(v0); ov.y = f2u(v1);
    *(ushort2*)&hout[(size_t)d * HD + c0] = ov;
}

// ---------------- fused GATv2 edge kernel, layer 2, SPLIT-PACK stride 192 --------
// Lane l=16h+j: feats {h*47+j, +16} as ONE dword at byte 4l; feat {+32} as ONE
// ushort at byte 256+2l. 2 loads/edge, 384B/row (no pad traffic). Packed-FP32
// math; aligned uint4 srcW prefetch. j=15 lanes masked by A2=B2=0 / has2.
__global__ __launch_bounds__(256) void gat_fused_188(
    const bf16* __restrict__ fs, const bf16* __restrict__ fd,
    const unsigned* __restrict__ srcW, const int* __restrict__ ptr,
    const int* __restrict__ perm,
    const bf16* __restrict__ attn, const bf16* __restrict__ rs,
    void* __restrict__ out, const int* __restrict__ flag) {
    const int wave = threadIdx.x >> 6, lane = threadIdx.x & 63;
    const int di = blockIdx.x * 4 + wave;
    if (di >= Nn) return;
    const int d = perm[di];
    const int h = lane >> 4, j = lane & 15;
    const unsigned cbA = (unsigned)lane * 4u;          // dword zone
    const unsigned cbB = 256u + (unsigned)lane * 2u;   // ushort zone
    const int ca = h * Cc + j;                         // attn is unpadded [188]
    const bool has2 = (j < 15);
    float a0 = ldb(&attn[ca]) * L2E;
    float a1 = ldb(&attn[ca + 16]) * L2E;
    float a2 = has2 ? ldb(&attn[ca + 32]) * L2E : 0.f;
    const f32x2 Av = pk2(0.6f * a0, 0.6f * a1);
    const f32x2 Bv = pk2(0.4f * a0, 0.4f * a1);
    const float A2 = 0.6f * a2, B2 = 0.4f * a2;
    const char* fdb = (const char*)fd;
    const size_t drow = (size_t)d * 384u;
    unsigned dqa = *(const unsigned*)(fdb + drow + cbA);
    unsigned short dqb = *(const unsigned short*)(fdb + drow + cbB);
    const f32x2 fdv = pk2(b2flo(dqa), b2fhi(dqa));
    const float fd2 = b2f(dqb);   // j=15: stale-but-finite, masked by A2=B2=0
    const char* fsb = (const char*)fs;
    float l = 0.f, O2 = 0.f;
    f32x2 Ov = pk2(0.f, 0.f);
    int e = ptr[d];
    const int e1 = ptr[d + 1];
    for (; e < e1 && (e & 3); ++e) {
        unsigned b = srcW[e];
        unsigned q = *(const unsigned*)(fsb + b + cbA);
        unsigned short u = *(const unsigned short*)(fsb + b + cbB);
        f32x2 f = pk2(b2flo(q), b2fhi(q)); float g = b2f(u);
        f32x2 x = f + fdv;
        float y = g + fd2;
        f32x2 t = pfma2(pabs2(x), Bv, x * Av);
        float p = fmaf(y, A2, fmaf(fabsf(y), B2, t.x + t.y));
        p = sum16(p);
        float pe = __builtin_amdgcn_exp2f(p);
        l += pe;
        Ov = pfma2(pk2(pe, pe), f, Ov); O2 = fmaf(pe, g, O2);
    }
    for (; e + 3 < e1; e += 4) {
        uint4 sw = *(const uint4*)&srcW[e];
        unsigned bA = sw.x, bB = sw.y, bC = sw.z, bD = sw.w;
        unsigned qA = *(const unsigned*)(fsb + bA + cbA);
        unsigned qB = *(const unsigned*)(fsb + bB + cbA);
        unsigned qC = *(const unsigned*)(fsb + bC + cbA);
        unsigned qD = *(const unsigned*)(fsb + bD + cbA);
        unsigned short uA = *(const unsigned short*)(fsb + bA + cbB);
        unsigned short uB = *(const unsigned short*)(fsb + bB + cbB);
        unsigned short uC = *(const unsigned short*)(fsb + bC + cbB);
        unsigned short uD = *(const unsigned short*)(fsb + bD + cbB);
        f32x2 fA = pk2(b2flo(qA), b2fhi(qA)); float gA = b2f(uA);
        f32x2 fB = pk2(b2flo(qB), b2fhi(qB)); float gB = b2f(uB);
        f32x2 fC = pk2(b2flo(qC), b2fhi(qC)); float gC = b2f(uC);
        f32x2 fD = pk2(b2flo(qD), b2fhi(qD)); float gD = b2f(uD);
        f32x2 xA = fA + fdv, xB = fB + fdv, xC = fC + fdv, xD = fD + fdv;
        float yA = gA + fd2, yB = gB + fd2, yC = gC + fd2, yD = gD + fd2;
        f32x2 tA = pfma2(pabs2(xA), Bv, xA * Av);
        f32x2 tB = pfma2(pabs2(xB), Bv, xB * Av);
        f32x2 tC = pfma2(pabs2(xC), Bv, xC * Av);
        f32x2 tD = pfma2(pabs2(xD), Bv, xD * Av);
        float pA = fmaf(yA, A2, fmaf(fabsf(yA), B2, tA.x + tA.y));
        float pB = fmaf(yB, A2, fmaf(fabsf(yB), B2, tB.x + tB.y));
        float pC = fmaf(yC, A2, fmaf(fabsf(yC), B2, tC.x + tC.y));
        float pD = fmaf(yD, A2, fmaf(fabsf(yD), B2, tD.x + tD.y));
        pA = sum16(pA); pB = sum16(pB); pC = sum16(pC); pD = sum16(pD);
        float eA = __builtin_amdgcn_exp2f(pA), eB = __builtin_amdgcn_exp2f(pB);
        float eC = __builtin_amdgcn_exp2f(pC), eD = __builtin_amdgcn_exp2f(pD);
        l += (eA + eB) + (eC + eD);
        Ov = pfma2(pk2(eA, eA), fA, Ov); O2 = fmaf(eA, gA, O2);
        Ov = pfma2(pk2(eB, eB), fB, Ov); O2 = fmaf(eB, gB, O2);
        Ov = pfma2(pk2(eC, eC), fC, Ov); O2 = fmaf(eC, gC, O2);
        Ov = pfma2(pk2(eD, eD), fD, Ov); O2 = fmaf(eD, gD, O2);
    }
    for (; e < e1; ++e) {
        unsigned b = srcW[e];
        unsigned q = *(const unsigned*)(fsb + b + cbA);
        unsigned short u = *(const unsigned short*)(fsb + b + cbB);
        f32x2 f = pk2(b2flo(q), b2fhi(q)); float g = b2f(u);
        f32x2 x = f + fdv;
        float y = g + fd2;
        f32x2 t = pfma2(pabs2(x), Bv, x * Av);
        float p = fmaf(y, A2, fmaf(fabsf(y), B2, t.x + t.y));
        p = sum16(p);
        float pe = __builtin_amdgcn_exp2f(p);
        l += pe;
        Ov = pfma2(pk2(pe, pe), f, Ov); O2 = fmaf(pe, g, O2);
    }
    // epilogue: +res, head-mean across lane groups, log_softmax, store
    float inv = l > 0.f ? 1.f / l : 0.f;
    const char* rb_ = (const char*)rs;
    unsigned rqa = *(const unsigned*)(rb_ + drow + cbA);
    unsigned short rqb = *(const unsigned short*)(rb_ + drow + cbB);
    float v0 = fmaf(Ov.x, inv, b2flo(rqa));
    float v1 = fmaf(Ov.y, inv, b2fhi(rqa));
    float v2 = has2 ? fmaf(O2, inv, b2f(rqb)) : 0.f;
    v0 += __shfl_xor(v0, 16); v0 += __shfl_xor(v0, 32); v0 *= 0.25f;
    v1 += __shfl_xor(v1, 16); v1 += __shfl_xor(v1, 32); v1 *= 0.25f;
    v2 += __shfl_xor(v2, 16); v2 += __shfl_xor(v2, 32); v2 *= 0.25f;
    float mx = fmaxf(v0, v1);
    if (has2) mx = fmaxf(mx, v2);
    mx = max16(mx);
    float sm = __expf(v0 - mx) + __expf(v1 - mx) + (has2 ? __expf(v2 - mx) : 0.f);
    sm = sum16(sm);
    if (h == 0) {
        float ls = mx + __log2f(sm) * LN2;
        if (*flag) {
            bf16* o = (bf16*)out + (size_t)d * Cc;
            o[j] = __float2bfloat16(v0 - ls);
            o[j + 16] = __float2bfloat16(v1 - ls);
            if (has2) o[j + 32] = __float2bfloat16(v2 - ls);
        } else {
            float* o = (float*)out + (size_t)d * Cc;
            o[j] = v0 - ls;
            o[j + 16] = v1 - ls;
            if (has2) o[j + 32] = v2 - ls;
        }
    }
}

// ---------------- per-column BN stats over bf16 h (atomic combine) ----------------
// 391 blocks x 128 threads; ONE atomicAdd per thread per stat (block-reduced
// first). ~100K total atomics over 256 addrs = a few us. (A single-block
// serial finalize regressed to 92us - do NOT revisit that design.)
__global__ void col_stats(const bf16* __restrict__ in, float* __restrict__ sums) {
    int c = threadIdx.x;  // 128
    int r0 = blockIdx.x * 256;
    int r1 = r0 + 256; if (r1 > Nn) r1 = Nn;
    float s = 0.f, s2 = 0.f;
    for (int r = r0; r < r1; ++r) {
        float v = ldb(&in[(size_t)r * HD + c]);
        s += v; s2 += v * v;
    }
    atomicAdd(&sums[c], s);
    atomicAdd(&sums[HD + c], s2);
}

__global__ void bn_finalize(const float* __restrict__ sums, const bf16* __restrict__ g,
                            const bf16* __restrict__ be, float* __restrict__ ss) {
    int c = threadIdx.x;  // 128
    float mu = sums[c] * (1.f / Nn);
    float var = sums[HD + c] * (1.f / Nn) - mu * mu;
    float sc = tof(g[c]) * rsqrtf(var + EPSV);
    ss[c] = sc;
    ss[HD + c] = tof(be[c]) - mu * sc;
}

extern "C" void kernel_launch(void* const* d_in, const int* in_sizes, int n_in,
                              void* d_out, int out_size, void* d_ws, size_t ws_size,
                              hipStream_t stream) {
    (void)in_sizes; (void)n_in; (void)out_size; (void)ws_size;
    const void* x = d_in[0];
    const int* src = (const int*)d_in[1];
    const int* dst = (const int*)d_in[2];

    char* ws = (char*)d_ws;
    size_t off = 0;
    auto alloc = [&](size_t bytes) {
        void* p = ws + off;
        off += (bytes + 255) & ~(size_t)255;
        return p;
    };
    // rs (38.4 MB, [Nn][192]) aliases xb+rb (51.2 MB): both dead before L2 GEMM.
    bf16* xb = (bf16*)alloc((size_t)Nn * 128 * 2);    // 25.6 MB (stride-128 padded x)
    bf16* rb = (bf16*)alloc((size_t)Nn * HD * 2);     // 25.6 MB
    bf16* rs = xb;                                    // [Nn][HCP] alias
    bf16* fs = (bf16*)alloc((size_t)Nn * HCP * 2);    // 38.4 MB
    bf16* fd = (bf16*)alloc((size_t)Nn * HCP * 2);    // 38.4 MB
    bf16* hbA = (bf16*)alloc((size_t)Nn * HD * 2);    // 25.6 MB
    bf16* hbB = (bf16*)alloc((size_t)Nn * HD * 2);    // 25.6 MB
    int* ptr = (int*)alloc((Nn + 1) * 4);             // 400 KB
    bf16* wtb = (bf16*)alloc((size_t)WROWS * 128 * 2);// 328 KB
    float* bns = (float*)alloc(2 * HD * 4);
    float* bnss0 = (float*)alloc(2 * HD * 4);
    float* bnss1 = (float*)alloc(2 * HD * 4);
    bf16* pb = (bf16*)alloc(4096 * 2);
    int* flag = (int*)alloc(256);
    unsigned* w384 = (unsigned*)alloc((size_t)Ee * 4);// 4 MB
    unsigned* w256 = (unsigned*)alloc((size_t)Ee * 4);// 4 MB
    int* cnt = (int*)alloc((size_t)256 * NBLK * 4);   // 400 KB
    int* cbase = (int*)alloc((size_t)256 * NBLK * 4); // 400 KB
    int* totals = (int*)alloc(256 * 4);
    int* perm = (int*)alloc((size_t)Nn * 4);          // 400 KB

    // ---- small-param conversion (biases/attn/bn): d_in idx -> pb arena ----
    static const int spIdx[NSP] = {4, 6, 7, 9, 11, 13, 14, 16, 18, 19, 21, 22, 23, 24, 25};
    static const int spSz[NSP]  = {HD, HD, HD, HD, HD, HD, HD, HC, HC, HC, HC, HD, HD, HD, HD};
    CvtTab tab;
    int tot = 0;
    for (int i = 0; i < NSP; ++i) { tab.src[i] = d_in[spIdx[i]]; tab.off[i] = tot; tot += spSz[i]; }
    tab.off[NSP] = tot;
    const bf16 *bsrc0 = pb + tab.off[0], *bdst0 = pb + tab.off[1], *attn0 = pb + tab.off[2],
               *bres0 = pb + tab.off[3], *bsrc1 = pb + tab.off[4], *bdst1 = pb + tab.off[5],
               *attn1 = pb + tab.off[6], *bsrc2 = pb + tab.off[7], *bdst2 = pb + tab.off[8],
               *attn2 = pb + tab.off[9], *bres2 = pb + tab.off[10],
               *g0 = pb + tab.off[11], *be0 = pb + tab.off[12],
               *g1 = pb + tab.off[13], *be1 = pb + tab.off[14];

    // ---- packed Wt: rows [0,384)=L0, [384,640)=L1, [640,1216)=L2 @MP=192, pad->1280 ----
    PrepTab pt;
    static const int wIdx[8] = {3, 5, 8, 10, 12, 15, 17, 20};
    static const int wK[8]   = {INF_, INF_, INF_, HD, HD, HD, HD, HD};
    static const int wM[8]   = {HD, HD, HD, HD, HD, HC, HC, HC};
    static const int wMP[8]  = {128, 128, 128, 128, 128, 192, 192, 192};
    static const int wR0[8]  = {0, 128, 256, 384, 512, 640, 832, 1024};
    for (int i = 0; i < 8; ++i) {
        pt.src[i] = d_in[wIdx[i]]; pt.row0[i] = wR0[i];
        pt.K[i] = wK[i]; pt.M[i] = wM[i]; pt.MP[i] = wMP[i];
    }

    detect_dtype<<<1, 64, 0, stream>>>((const unsigned*)x, flag);
    cvt_x<<<(Nn * 128 + 255) / 256, 256, 0, stream>>>(x, xb, flag);
    cvt_params<<<(tot + 255) / 256, 256, 0, stream>>>(tab, pb, tot, flag);
    prep_all<<<(WROWS * 128 + 255) / 256, 256, 0, stream>>>(pt, wtb, flag);
    src_scale_ptr<<<(Ee + 255) / 256, 256, 0, stream>>>(src, dst, w384, w256, ptr);
    deg_hist_blk<<<NBLK, 256, 0, stream>>>(ptr, cnt);
    deg_totals<<<64, 256, 0, stream>>>(cnt, totals);
    deg_bases<<<64, 256, 0, stream>>>(cnt, totals, cbase);
    deg_scatter_blk<<<NBLK, 256, 0, stream>>>(ptr, cbase, perm);

    const int fusedGrid = (Nn + 3) / 4;
    const int statsGrid = NBLK;
    const int rowBlk = (Nn + 63) / 64;  // 1563

    // ---------------- layer 0 (384 cols: NY=2 x CS=3, A staged ONCE) --------------
    gemm_big<128, 3, 3, false, false, HD, 2><<<rowBlk, 256, 0, stream>>>(
        xb, wtb, bsrc0, bdst0, bres0, fs, fd, rb, HD, nullptr);
    gat_fused_128<false><<<fusedGrid, 256, 0, stream>>>(fs, fd, w256, ptr, perm,
                                                        attn0, rb, nullptr, hbA);
    zero_u32<<<1, 256, 0, stream>>>((unsigned*)bns, 2 * HD);
    col_stats<<<statsGrid, 128, 0, stream>>>(hbA, bns);
    bn_finalize<<<1, HD, 0, stream>>>(bns, g0, be0, bnss0);

    // ---------------- layer 1 (256 cols: NY=2 x CS=2) ----------------
    gemm_big<128, 2, 2, true, false, HD, 2><<<rowBlk, 256, 0, stream>>>(
        hbA, wtb + (size_t)384 * 128, bsrc1, bdst1, nullptr, fs, fd, nullptr, HD, bnss0);
    gat_fused_128<true><<<fusedGrid, 256, 0, stream>>>(fs, fd, w256, ptr, perm,
                                                       attn1, hbA, bnss0, hbB);
    zero_u32<<<1, 256, 0, stream>>>((unsigned*)bns, 2 * HD);
    col_stats<<<statsGrid, 128, 0, stream>>>(hbB, bns);
    bn_finalize<<<1, HD, 0, stream>>>(bns, g1, be1, bnss1);

    // ---------------- layer 2 (576 cols: NY=3 x CS=3, split-pack outputs) ---------
    gemm_big<192, 3, 3, true, true, HCP, 3><<<rowBlk, 256, 0, stream>>>(
        hbB, wtb + (size_t)640 * 128, bsrc2, bdst2, bres2, fs, fd, rs, HC, bnss1);
    gat_fused_188<<<fusedGrid, 256, 0, stream>>>(fs, fd, w384, ptr, perm, attn2, rs,
                                                 d_out, flag);
}

// Round 7
// 698.288 us; speedup vs baseline: 1.0093x; 1.0093x over previous
//
#include <hip/hip_runtime.h>
#include <hip/hip_bf16.h>

#define Nn 100000
#define Ee 1000000
#define INF_ 100
#define Hh 4
#define Dd 32
#define HD 128
#define Cc 47
#define HC 188
#define HCP 192
#define EPSV 1e-5f
#define SLOPE 0.2f
#define NBLK ((Nn + 255) / 256)

typedef __hip_bfloat16 bf16;
typedef __attribute__((ext_vector_type(8))) short short8;
typedef __attribute__((ext_vector_type(4))) float f32x4;
typedef __attribute__((ext_vector_type(2))) float f32x2;

__device__ __forceinline__ float tof(bf16 v) { return __bfloat162float(v); }
__device__ __forceinline__ float b2f(unsigned short u) {
    return __uint_as_float((unsigned)u << 16);
}
__device__ __forceinline__ float b2flo(unsigned u) {
    return __uint_as_float(u << 16);
}
__device__ __forceinline__ float b2fhi(unsigned u) {
    return __uint_as_float(u & 0xFFFF0000u);
}
__device__ __forceinline__ float ldb(const bf16* p) {
    return b2f(*(const unsigned short*)p);
}
__device__ __forceinline__ unsigned short f2u(float v) {
    bf16 t = __float2bfloat16(v);
    return *(unsigned short*)&t;
}
__device__ __forceinline__ f32x2 pk2(float x, float y) {
    f32x2 r; r.x = x; r.y = y; return r;
}
__device__ __forceinline__ f32x2 pabs2(f32x2 v) {          // v_pk_max_f32 v, -v
    return __builtin_elementwise_max(v, -v);
}
__device__ __forceinline__ f32x2 pfma2(f32x2 a, f32x2 b, f32x2 c) {
    return __builtin_elementwise_fma(a, b, c);             // v_pk_fma_f32
}

// DPP-fused 16-lane reduces (quad_perm swaps + row rotates; row=16 lanes).
template <int C>
__device__ __forceinline__ float dppadd(float v) {
    int m = __builtin_amdgcn_update_dpp(0, __float_as_int(v), C, 0xF, 0xF, false);
    return v + __int_as_float(m);
}
template <int C>
__device__ __forceinline__ float dppmax(float v) {
    int m = __builtin_amdgcn_update_dpp(0, __float_as_int(v), C, 0xF, 0xF, false);
    return fmaxf(v, __int_as_float(m));
}
__device__ __forceinline__ float sum16(float p) {
    p = dppadd<0xB1>(p);   // quad_perm [1,0,3,2]
    p = dppadd<0x4E>(p);   // quad_perm [2,3,0,1]
    p = dppadd<0x124>(p);  // row_ror:4
    p = dppadd<0x128>(p);  // row_ror:8
    return p;
}
__device__ __forceinline__ float max16(float p) {
    p = dppmax<0xB1>(p); p = dppmax<0x4E>(p);
    p = dppmax<0x124>(p); p = dppmax<0x128>(p);
    return p;
}

#define L2E 1.4426950408889634f
#define LN2 0.6931471805599453f

// ---------------- dtype detect: 1 = bf16 buffers, 0 = fp32 buffers ----------------
__global__ void detect_dtype(const unsigned* __restrict__ x, int* __restrict__ flag) {
    if (blockIdx.x == 0 && threadIdx.x == 0) {
        int good = 0;
        for (int i = 0; i < 256; ++i) {
            unsigned lo = x[i] & 0xFFFFu;
            float v = __uint_as_float(lo << 16);
            float a = fabsf(v);
            if (a > 1e-4f && a < 10.f) good++;
        }
        *flag = (good >= 128) ? 1 : 0;
    }
}

__device__ __forceinline__ float ld_any(const void* p, int i, int isbf) {
    return isbf ? tof(((const bf16*)p)[i]) : ((const float*)p)[i];
}

// ---------------- x -> canonical bf16, padded to row stride 128 ----------------
__global__ void cvt_x(const void* __restrict__ in, bf16* __restrict__ out,
                      const int* __restrict__ flag) {
    int i = blockIdx.x * blockDim.x + threadIdx.x;
    if (i >= Nn * 128) return;
    int row = i >> 7, col = i & 127;
    float v = (col < INF_) ? ld_any(in, row * INF_ + col, *flag) : 0.f;
    out[i] = __float2bfloat16(v);
}

// ---------------- weights -> packed transposed Wt[1280][128]  (+ small params) ----
#define WROWS 1280
#define NSP 15
struct PrepTab { const void* src[8]; int row0[8]; int K[8]; int M[8]; int MP[8]; };
struct CvtTab { const void* src[NSP]; int off[NSP + 1]; };

__global__ void prep_all(PrepTab t, CvtTab ct, bf16* __restrict__ wtb,
                         bf16* __restrict__ pb, int total,
                         const int* __restrict__ flag) {
    int i = blockIdx.x * blockDim.x + threadIdx.x;
    int isbf = *flag;
    if (i < WROWS * 128) {
        int row = i >> 7, k = i & 127;
        float v = 0.f;
#pragma unroll
        for (int q = 0; q < 8; ++q) {
            if (row >= t.row0[q] && row < t.row0[q] + t.MP[q]) {
                int m = row - t.row0[q];
                if (m < t.M[q] && k < t.K[q])
                    v = ld_any(t.src[q], k * t.M[q] + m, isbf);
            }
        }
        wtb[i] = __float2bfloat16(v);
    }
    if (i < total) {   // small params (biases/attn/bn) -> canonical bf16
        int seg = 0;
        while (i >= ct.off[seg + 1]) seg++;
        pb[i] = __float2bfloat16(ld_any(ct.src[seg], i - ct.off[seg], isbf));
    }
}

// ---------------- fused: CSR build + pre-scaled src offsets + bns zeroing ---------
__global__ void src_scale_ptr(const int* __restrict__ src, const int* __restrict__ dst,
                              unsigned* __restrict__ w384, unsigned* __restrict__ w256,
                              int* __restrict__ ptr,
                              float* __restrict__ z0, float* __restrict__ z1) {
    int i = blockIdx.x * blockDim.x + threadIdx.x;
    if (i < Ee) {
        unsigned s = (unsigned)src[i];
        w384[i] = s * 384u;  // stride HCP*2 bytes (layer-2 split-pack fs)
        w256[i] = s << 8;    // stride HD*2 bytes  (layer-0/1 fs)
    }
    if (i < 2 * HD) { z0[i] = 0.f; z1[i] = 0.f; }   // BN stat accumulators
    if (i <= Nn) {
        if (i == Nn) { ptr[Nn] = Ee; return; }
        int lo = 0, hi = Ee;
        while (lo < hi) {
            int mid = (lo + hi) >> 1;
            if (dst[mid] < i) lo = mid + 1; else hi = mid;
        }
        ptr[i] = lo;
    }
}

// ---------------- degree-descending LPT permutation (block counting sort) ---------
// NO global atomics, NO serial single-CU scans. cnt/base are BIN-MAJOR
// [bin][NBLK] so per-bin walks coalesce across lanes.
__global__ void deg_hist_blk(const int* __restrict__ ptr, int* __restrict__ cnt) {
    __shared__ int lh[256];
    int t = threadIdx.x;
    lh[t] = 0;
    __syncthreads();
    int n = blockIdx.x * 256 + t;
    if (n < Nn) {
        int dg = ptr[n + 1] - ptr[n]; if (dg > 255) dg = 255;
        atomicAdd(&lh[dg], 1);
    }
    __syncthreads();
    cnt[t * NBLK + blockIdx.x] = lh[t];
}

// one wave per bin (64 blocks x 4 waves): lane-strided coalesced total
__global__ void deg_totals(const int* __restrict__ cnt, int* __restrict__ totals) {
    int wave = threadIdx.x >> 6, lane = threadIdx.x & 63;
    int bin = blockIdx.x * 4 + wave;
    int s = 0;
    for (int k = lane; k < NBLK; k += 64) s += cnt[bin * NBLK + k];
#pragma unroll
    for (int o = 1; o < 64; o <<= 1) s += __shfl_xor(s, o);
    if (lane == 0) totals[bin] = s;
}

// one wave per bin: binbase = sum of totals over HIGHER-degree bins, then
// chunked 64-lane exclusive prefix over the NBLK per-block counts.
__global__ void deg_bases(const int* __restrict__ cnt, const int* __restrict__ totals,
                          int* __restrict__ base) {
    int wave = threadIdx.x >> 6, lane = threadIdx.x & 63;
    int bin = blockIdx.x * 4 + wave;
    int bb = 0;
    for (int b = bin + 1 + lane; b < 256; b += 64) bb += totals[b];
#pragma unroll
    for (int o = 1; o < 64; o <<= 1) bb += __shfl_xor(bb, o);
    int run = bb;   // descending-degree base for this bin
    for (int k0 = 0; k0 < NBLK; k0 += 64) {
        int k = k0 + lane;
        int c = (k < NBLK) ? cnt[bin * NBLK + k] : 0;
        int p = c;
#pragma unroll
        for (int o = 1; o < 64; o <<= 1) {
            int t = __shfl_up(p, o);
            if (lane >= o) p += t;
        }
        if (k < NBLK) base[bin * NBLK + k] = run + (p - c);
        run += __shfl(p, 63);
    }
}

__global__ void deg_scatter_blk(const int* __restrict__ ptr, const int* __restrict__ base,
                                int* __restrict__ perm) {
    __shared__ int lh[256];
    int t = threadIdx.x;
    lh[t] = 0;
    __syncthreads();
    int n = blockIdx.x * 256 + t;
    if (n < Nn) {
        int dg = ptr[n + 1] - ptr[n]; if (dg > 255) dg = 255;
        int loc = atomicAdd(&lh[dg], 1);   // LDS atomic: one CU, cheap
        perm[base[dg * NBLK + blockIdx.x] + loc] = n;
    }
}

// ---------------- big-tile MFMA GEMM: 64 rows x (64*CS) cols per block -------------
// y-grid column split (4689/3126 blocks): A re-fetched per y, but the deep grid
// hides the scattered-store latency. (NY-in-kernel loop regressed 41us - keep grid.)
// PACK (layer-2 split layout): col lc -> h=lc/47, cc=lc%47, j=cc&15, k=cc>>4,
// lane l=16h+j; k<2 -> elem 2l+k (dword zone); k=2 -> elem 128+l (ushort zone).
template <int MP, int NOUT, int CS, bool ABN, bool PACK, int OSTR>
__global__ __launch_bounds__(256, 4) void gemm_big(
    const bf16* __restrict__ A, const bf16* __restrict__ Wt,
    const bf16* __restrict__ b0, const bf16* __restrict__ b1,
    const bf16* __restrict__ b2,
    bf16* __restrict__ o0, bf16* __restrict__ o1, bf16* __restrict__ o2,
    int MR, const float* __restrict__ bnp) {
    __shared__ __align__(16) bf16 Al[64 * 136];
    const int row0 = blockIdx.x * 64;
    const int tid = threadIdx.x;
#pragma unroll
    for (int j = 0; j < 4; ++j) {
        int idx = tid + j * 256;          // 0..1023 int4 slots
        int r = idx >> 4, kk = (idx & 15) * 8;
        int4 val = {0, 0, 0, 0};
        if (row0 + r < Nn) {
            val = *(const int4*)&A[(size_t)(row0 + r) * 128 + kk];
            if (ABN) {
                short8 av = *(short8*)&val;
                bf16 tmp[8];
#pragma unroll
                for (int u = 0; u < 8; ++u) {
                    float v = b2f((unsigned short)av[u]);
                    v = fmaxf(fmaf(v, bnp[kk + u], bnp[128 + kk + u]), 0.f);
                    tmp[u] = __float2bfloat16(v);
                }
                val = *(int4*)tmp;
            }
        }
        *(int4*)&Al[r * 136 + kk] = val;
    }
    __syncthreads();
    const int wave = tid >> 6, lane = tid & 63;
    const int n16 = lane & 15, quad = lane >> 4;
    const int colbase = blockIdx.y * (64 * CS) + wave * (16 * CS);
    f32x4 acc[4][CS];
#pragma unroll
    for (int rt = 0; rt < 4; ++rt)
#pragma unroll
        for (int c = 0; c < CS; ++c) acc[rt][c] = (f32x4){0.f, 0.f, 0.f, 0.f};
    const bf16* wb[CS];
#pragma unroll
    for (int c = 0; c < CS; ++c)
        wb[c] = Wt + (size_t)(colbase + c * 16 + n16) * 128 + quad * 8;
    const bf16* ap = Al + n16 * 136 + quad * 8;
#pragma unroll
    for (int ks = 0; ks < 4; ++ks) {
        short8 bf[CS];
#pragma unroll
        for (int c = 0; c < CS; ++c) bf[c] = *(const short8*)(wb[c] + ks * 32);
#pragma unroll
        for (int rt = 0; rt < 4; ++rt) {
            short8 af = *(const short8*)(ap + rt * 16 * 136 + ks * 32);
#pragma unroll
            for (int c = 0; c < CS; ++c)
                acc[rt][c] = __builtin_amdgcn_mfma_f32_16x16x32_bf16(af, bf[c], acc[rt][c], 0, 0, 0);
        }
    }
#pragma unroll
    for (int c = 0; c < CS; ++c) {
        int col = colbase + c * 16 + n16;
        int oi = col / MP, lc = col - oi * MP;
        if (oi >= NOUT || lc >= MR) continue;
        const bf16* bp = (oi == 0) ? b0 : (oi == 1) ? b1 : b2;
        bf16* o = (oi == 0) ? o0 : (oi == 1) ? o1 : o2;
        float bb = tof(bp[lc]);
        int st;
        if (PACK) {
            int hh = lc / 47, cc = lc - hh * 47;
            int jj = cc & 15, kk2 = cc >> 4;
            int l = hh * 16 + jj;
            st = (kk2 < 2) ? (2 * l + kk2) : (128 + l);
        } else {
            st = lc;
        }
#pragma unroll
        for (int rt = 0; rt < 4; ++rt) {
#pragma unroll
            for (int i = 0; i < 4; ++i) {
                int row = row0 + rt * 16 + quad * 4 + i;
                if (row < Nn)
                    o[(size_t)row * OSTR + st] = __float2bfloat16(acc[rt][c][i] + bb);
            }
        }
    }
}

// ---------------- fused GATv2 edge kernel, M=128 (layers 0,1) ----------------
// 512 threads = 8 dsts/block (degree-sorted via perm -> uniform intra-block).
// Lane holds cols (2*lane, 2*lane+1). MAX-FREE softmax, log2e folded into attn.
// Packed-FP32 math; aligned uint4 srcW prefetch (1 VMEM per 4 edges).
template <bool RESBN>
__global__ __launch_bounds__(512) void gat_fused_128(
    const bf16* __restrict__ fs, const bf16* __restrict__ fd,
    const unsigned* __restrict__ srcW, const int* __restrict__ ptr,
    const int* __restrict__ perm,
    const bf16* __restrict__ attn, const bf16* __restrict__ resb,
    const float* __restrict__ bnp, bf16* __restrict__ hout) {
    const int wave = threadIdx.x >> 6, lane = threadIdx.x & 63;
    const int di = blockIdx.x * 8 + wave;
    if (di >= Nn) return;
    const int d = perm[di];
    const int c0 = lane * 2;
    const unsigned c0b = (unsigned)c0 * 2u;
    ushort2 aq = *(const ushort2*)&attn[c0];
    float a0 = b2f(aq.x) * L2E, a1 = b2f(aq.y) * L2E;
    const f32x2 Av = pk2(0.6f * a0, 0.6f * a1);
    const f32x2 Bv = pk2(0.4f * a0, 0.4f * a1);
    ushort2 dq = *(const ushort2*)&fd[(size_t)d * HD + c0];
    const f32x2 fdv = pk2(b2f(dq.x), b2f(dq.y));
    const char* fsb = (const char*)fs;
    float l = 0.f;
    f32x2 Ov = pk2(0.f, 0.f);
    int e = ptr[d];
    const int e1 = ptr[d + 1];
    // peel to 4-alignment so the main loop can use one aligned uint4 load
    for (; e < e1 && (e & 3); ++e) {
        unsigned v = srcW[e] + c0b;
        ushort2 fq = *(const ushort2*)(fsb + v);
        f32x2 f = pk2(b2f(fq.x), b2f(fq.y));
        f32x2 x = f + fdv;
        f32x2 t = pfma2(pabs2(x), Bv, x * Av);
        float p = sum16(t.x + t.y);
        float pe = __builtin_amdgcn_exp2f(p);
        l += pe;
        Ov = pfma2(pk2(pe, pe), f, Ov);
    }
    for (; e + 3 < e1; e += 4) {
        uint4 sw = *(const uint4*)&srcW[e];
        unsigned vA = sw.x + c0b, vB = sw.y + c0b;
        unsigned vC = sw.z + c0b, vD = sw.w + c0b;
        ushort2 qA = *(const ushort2*)(fsb + vA);
        ushort2 qB = *(const ushort2*)(fsb + vB);
        ushort2 qC = *(const ushort2*)(fsb + vC);
        ushort2 qD = *(const ushort2*)(fsb + vD);
        f32x2 fA = pk2(b2f(qA.x), b2f(qA.y));
        f32x2 fB = pk2(b2f(qB.x), b2f(qB.y));
        f32x2 fC = pk2(b2f(qC.x), b2f(qC.y));
        f32x2 fD = pk2(b2f(qD.x), b2f(qD.y));
        f32x2 xA = fA + fdv, xB = fB + fdv, xC = fC + fdv, xD = fD + fdv;
        f32x2 tA = pfma2(pabs2(xA), Bv, xA * Av);
        f32x2 tB = pfma2(pabs2(xB), Bv, xB * Av);
        f32x2 tC = pfma2(pabs2(xC), Bv, xC * Av);
        f32x2 tD = pfma2(pabs2(xD), Bv, xD * Av);
        float pA = tA.x + tA.y, pB = tB.x + tB.y;
        float pC = tC.x + tC.y, pD = tD.x + tD.y;
        pA = sum16(pA); pB = sum16(pB); pC = sum16(pC); pD = sum16(pD);
        float eA = __builtin_amdgcn_exp2f(pA), eB = __builtin_amdgcn_exp2f(pB);
        float eC = __builtin_amdgcn_exp2f(pC), eD = __builtin_amdgcn_exp2f(pD);
        l += (eA + eB) + (eC + eD);
        Ov = pfma2(pk2(eA, eA), fA, Ov);
        Ov = pfma2(pk2(eB, eB), fB, Ov);
        Ov = pfma2(pk2(eC, eC), fC, Ov);
        Ov = pfma2(pk2(eD, eD), fD, Ov);
    }
    for (; e < e1; ++e) {
        unsigned v = srcW[e] + c0b;
        ushort2 fq = *(const ushort2*)(fsb + v);
        f32x2 f = pk2(b2f(fq.x), b2f(fq.y));
        f32x2 x = f + fdv;
        f32x2 t = pfma2(pabs2(x), Bv, x * Av);
        float p = sum16(t.x + t.y);
        float pe = __builtin_amdgcn_exp2f(p);
        l += pe;
        Ov = pfma2(pk2(pe, pe), f, Ov);
    }
    float inv = l > 0.f ? 1.f / l : 0.f;
    ushort2 rq = *(const ushort2*)&resb[(size_t)d * HD + c0];
    float r0 = b2f(rq.x), r1 = b2f(rq.y);
    if (RESBN) {
        r0 = fmaxf(fmaf(r0, bnp[c0], bnp[HD + c0]), 0.f);
        r1 = fmaxf(fmaf(r1, bnp[c0 + 1], bnp[HD + c0 + 1]), 0.f);
    }
    float v0 = fmaxf(fmaf(Ov.x, inv, r0), 0.f);  // conv activation relu
    float v1 = fmaxf(fmaf(Ov.y, inv, r1), 0.f);
    ushort2 ov; ov.x = f2u(v0); ov.y = f2u(v1);
    *(ushort2*)&hout[(size_t)d * HD + c0] = ov;
}

// ---------------- fused GATv2 edge kernel, layer 2, SPLIT-PACK stride 192 --------
// 512 threads = 8 dsts/block. Lane l=16h+j: feats {h*47+j, +16} as ONE dword at
// byte 4l; feat {+32} as ONE ushort at byte 256+2l. 2 loads/edge, 384B/row.
// Packed-FP32 math; aligned uint4 srcW prefetch. j=15 lanes masked by A2=B2=0.
__global__ __launch_bounds__(512) void gat_fused_188(
    const bf16* __restrict__ fs, const bf16* __restrict__ fd,
    const unsigned* __restrict__ srcW, const int* __restrict__ ptr,
    const int* __restrict__ perm,
    const bf16* __restrict__ attn, const bf16* __restrict__ rs,
    void* __restrict__ out, const int* __restrict__ flag) {
    const int wave = threadIdx.x >> 6, lane = threadIdx.x & 63;
    const int di = blockIdx.x * 8 + wave;
    if (di >= Nn) return;
    const int d = perm[di];
    const int h = lane >> 4, j = lane & 15;
    const unsigned cbA = (unsigned)lane * 4u;          // dword zone
    const unsigned cbB = 256u + (unsigned)lane * 2u;   // ushort zone
    const int ca = h * Cc + j;                         // attn is unpadded [188]
    const bool has2 = (j < 15);
    float a0 = ldb(&attn[ca]) * L2E;
    float a1 = ldb(&attn[ca + 16]) * L2E;
    float a2 = has2 ? ldb(&attn[ca + 32]) * L2E : 0.f;
    const f32x2 Av = pk2(0.6f * a0, 0.6f * a1);
    const f32x2 Bv = pk2(0.4f * a0, 0.4f * a1);
    const float A2 = 0.6f * a2, B2 = 0.4f * a2;
    const char* fdb = (const char*)fd;
    const size_t drow = (size_t)d * 384u;
    unsigned dqa = *(const unsigned*)(fdb + drow + cbA);
    unsigned short dqb = *(const unsigned short*)(fdb + drow + cbB);
    const f32x2 fdv = pk2(b2flo(dqa), b2fhi(dqa));
    const float fd2 = b2f(dqb);   // j=15: stale-but-finite, masked by A2=B2=0
    const char* fsb = (const char*)fs;
    float l = 0.f, O2 = 0.f;
    f32x2 Ov = pk2(0.f, 0.f);
    int e = ptr[d];
    const int e1 = ptr[d + 1];
    for (; e < e1 && (e & 3); ++e) {
        unsigned b = srcW[e];
        unsigned q = *(const unsigned*)(fsb + b + cbA);
        unsigned short u = *(const unsigned short*)(fsb + b + cbB);
        f32x2 f = pk2(b2flo(q), b2fhi(q)); float g = b2f(u);
        f32x2 x = f + fdv;
        float y = g + fd2;
        f32x2 t = pfma2(pabs2(x), Bv, x * Av);
        float p = fmaf(y, A2, fmaf(fabsf(y), B2, t.x + t.y));
        p = sum16(p);
        float pe = __builtin_amdgcn_exp2f(p);
        l += pe;
        Ov = pfma2(pk2(pe, pe), f, Ov); O2 = fmaf(pe, g, O2);
    }
    for (; e + 3 < e1; e += 4) {
        uint4 sw = *(const uint4*)&srcW[e];
        unsigned bA = sw.x, bB = sw.y, bC = sw.z, bD = sw.w;
        unsigned qA = *(const unsigned*)(fsb + bA + cbA);
        unsigned qB = *(const unsigned*)(fsb + bB + cbA);
        unsigned qC = *(const unsigned*)(fsb + bC + cbA);
        unsigned qD = *(const unsigned*)(fsb + bD + cbA);
        unsigned short uA = *(const unsigned short*)(fsb + bA + cbB);
        unsigned short uB = *(const unsigned short*)(fsb + bB + cbB);
        unsigned short uC = *(const unsigned short*)(fsb + bC + cbB);
        unsigned short uD = *(const unsigned short*)(fsb + bD + cbB);
        f32x2 fA = pk2(b2flo(qA), b2fhi(qA)); float gA = b2f(uA);
        f32x2 fB = pk2(b2flo(qB), b2fhi(qB)); float gB = b2f(uB);
        f32x2 fC = pk2(b2flo(qC), b2fhi(qC)); float gC = b2f(uC);
        f32x2 fD = pk2(b2flo(qD), b2fhi(qD)); float gD = b2f(uD);
        f32x2 xA = fA + fdv, xB = fB + fdv, xC = fC + fdv, xD = fD + fdv;
        float yA = gA + fd2, yB = gB + fd2, yC = gC + fd2, yD = gD + fd2;
        f32x2 tA = pfma2(pabs2(xA), Bv, xA * Av);
        f32x2 tB = pfma2(pabs2(xB), Bv, xB * Av);
        f32x2 tC = pfma2(pabs2(xC), Bv, xC * Av);
        f32x2 tD = pfma2(pabs2(xD), Bv, xD * Av);
        float pA = fmaf(yA, A2, fmaf(fabsf(yA), B2, tA.x + tA.y));
        float pB = fmaf(yB, A2, fmaf(fabsf(yB), B2, tB.x + tB.y));
        float pC = fmaf(yC, A2, fmaf(fabsf(yC), B2, tC.x + tC.y));
        float pD = fmaf(yD, A2, fmaf(fabsf(yD), B2, tD.x + tD.y));
        pA = sum16(pA); pB = sum16(pB); pC = sum16(pC); pD = sum16(pD);
        float eA = __builtin_amdgcn_exp2f(pA), eB = __builtin_amdgcn_exp2f(pB);
        float eC = __builtin_amdgcn_exp2f(pC), eD = __builtin_amdgcn_exp2f(pD);
        l += (eA + eB) + (eC + eD);
        Ov = pfma2(pk2(eA, eA), fA, Ov); O2 = fmaf(eA, gA, O2);
        Ov = pfma2(pk2(eB, eB), fB, Ov); O2 = fmaf(eB, gB, O2);
        Ov = pfma2(pk2(eC, eC), fC, Ov); O2 = fmaf(eC, gC, O2);
        Ov = pfma2(pk2(eD, eD), fD, Ov); O2 = fmaf(eD, gD, O2);
    }
    for (; e < e1; ++e) {
        unsigned b = srcW[e];
        unsigned q = *(const unsigned*)(fsb + b + cbA);
        unsigned short u = *(const unsigned short*)(fsb + b + cbB);
        f32x2 f = pk2(b2flo(q), b2fhi(q)); float g = b2f(u);
        f32x2 x = f + fdv;
        float y = g + fd2;
        f32x2 t = pfma2(pabs2(x), Bv, x * Av);
        float p = fmaf(y, A2, fmaf(fabsf(y), B2, t.x + t.y));
        p = sum16(p);
        float pe = __builtin_amdgcn_exp2f(p);
        l += pe;
        Ov = pfma2(pk2(pe, pe), f, Ov); O2 = fmaf(pe, g, O2);
    }
    // epilogue: +res, head-mean across lane groups, log_softmax, store
    float inv = l > 0.f ? 1.f / l : 0.f;
    const char* rb_ = (const char*)rs;
    unsigned rqa = *(const unsigned*)(rb_ + drow + cbA);
    unsigned short rqb = *(const unsigned short*)(rb_ + drow + cbB);
    float v0 = fmaf(Ov.x, inv, b2flo(rqa));
    float v1 = fmaf(Ov.y, inv, b2fhi(rqa));
    float v2 = has2 ? fmaf(O2, inv, b2f(rqb)) : 0.f;
    v0 += __shfl_xor(v0, 16); v0 += __shfl_xor(v0, 32); v0 *= 0.25f;
    v1 += __shfl_xor(v1, 16); v1 += __shfl_xor(v1, 32); v1 *= 0.25f;
    v2 += __shfl_xor(v2, 16); v2 += __shfl_xor(v2, 32); v2 *= 0.25f;
    float mx = fmaxf(v0, v1);
    if (has2) mx = fmaxf(mx, v2);
    mx = max16(mx);
    float sm = __expf(v0 - mx) + __expf(v1 - mx) + (has2 ? __expf(v2 - mx) : 0.f);
    sm = sum16(sm);
    if (h == 0) {
        float ls = mx + __log2f(sm) * LN2;
        if (*flag) {
            bf16* o = (bf16*)out + (size_t)d * Cc;
            o[j] = __float2bfloat16(v0 - ls);
            o[j + 16] = __float2bfloat16(v1 - ls);
            if (has2) o[j + 32] = __float2bfloat16(v2 - ls);
        } else {
            float* o = (float*)out + (size_t)d * Cc;
            o[j] = v0 - ls;
            o[j + 16] = v1 - ls;
            if (has2) o[j + 32] = v2 - ls;
        }
    }
}

// ---------------- per-column BN stats over bf16 h (atomic combine) ----------------
// 391 blocks x 128 threads; ONE atomicAdd per thread per stat (block-reduced
// first). ~100K total atomics over 256 addrs = a few us. (A single-block
// serial finalize regressed to 92us - do NOT revisit that design.)
__global__ void col_stats(const bf16* __restrict__ in, float* __restrict__ sums) {
    int c = threadIdx.x;  // 128
    int r0 = blockIdx.x * 256;
    int r1 = r0 + 256; if (r1 > Nn) r1 = Nn;
    float s = 0.f, s2 = 0.f;
    for (int r = r0; r < r1; ++r) {
        float v = ldb(&in[(size_t)r * HD + c]);
        s += v; s2 += v * v;
    }
    atomicAdd(&sums[c], s);
    atomicAdd(&sums[HD + c], s2);
}

__global__ void bn_finalize(const float* __restrict__ sums, const bf16* __restrict__ g,
                            const bf16* __restrict__ be, float* __restrict__ ss) {
    int c = threadIdx.x;  // 128
    float mu = sums[c] * (1.f / Nn);
    float var = sums[HD + c] * (1.f / Nn) - mu * mu;
    float sc = tof(g[c]) * rsqrtf(var + EPSV);
    ss[c] = sc;
    ss[HD + c] = tof(be[c]) - mu * sc;
}

extern "C" void kernel_launch(void* const* d_in, const int* in_sizes, int n_in,
                              void* d_out, int out_size, void* d_ws, size_t ws_size,
                              hipStream_t stream) {
    (void)in_sizes; (void)n_in; (void)out_size; (void)ws_size;
    const void* x = d_in[0];
    const int* src = (const int*)d_in[1];
    const int* dst = (const int*)d_in[2];

    char* ws = (char*)d_ws;
    size_t off = 0;
    auto alloc = [&](size_t bytes) {
        void* p = ws + off;
        off += (bytes + 255) & ~(size_t)255;
        return p;
    };
    // rs (38.4 MB, [Nn][192]) aliases xb+rb (51.2 MB): both dead before L2 GEMM.
    bf16* xb = (bf16*)alloc((size_t)Nn * 128 * 2);    // 25.6 MB (stride-128 padded x)
    bf16* rb = (bf16*)alloc((size_t)Nn * HD * 2);     // 25.6 MB
    bf16* rs = xb;                                    // [Nn][HCP] alias
    bf16* fs = (bf16*)alloc((size_t)Nn * HCP * 2);    // 38.4 MB
    bf16* fd = (bf16*)alloc((size_t)Nn * HCP * 2);    // 38.4 MB
    bf16* hbA = (bf16*)alloc((size_t)Nn * HD * 2);    // 25.6 MB
    bf16* hbB = (bf16*)alloc((size_t)Nn * HD * 2);    // 25.6 MB
    int* ptr = (int*)alloc((Nn + 1) * 4);             // 400 KB
    bf16* wtb = (bf16*)alloc((size_t)WROWS * 128 * 2);// 328 KB
    float* bns0 = (float*)alloc(2 * HD * 4);
    float* bns1 = (float*)alloc(2 * HD * 4);
    float* bnss0 = (float*)alloc(2 * HD * 4);
    float* bnss1 = (float*)alloc(2 * HD * 4);
    bf16* pb = (bf16*)alloc(4096 * 2);
    int* flag = (int*)alloc(256);
    unsigned* w384 = (unsigned*)alloc((size_t)Ee * 4);// 4 MB
    unsigned* w256 = (unsigned*)alloc((size_t)Ee * 4);// 4 MB
    int* cnt = (int*)alloc((size_t)256 * NBLK * 4);   // 400 KB
    int* cbase = (int*)alloc((size_t)256 * NBLK * 4); // 400 KB
    int* totals = (int*)alloc(256 * 4);
    int* perm = (int*)alloc((size_t)Nn * 4);          // 400 KB

    // ---- small-param conversion (biases/attn/bn): d_in idx -> pb arena ----
    static const int spIdx[NSP] = {4, 6, 7, 9, 11, 13, 14, 16, 18, 19, 21, 22, 23, 24, 25};
    static const int spSz[NSP]  = {HD, HD, HD, HD, HD, HD, HD, HC, HC, HC, HC, HD, HD, HD, HD};
    CvtTab tab;
    int tot = 0;
    for (int i = 0; i < NSP; ++i) { tab.src[i] = d_in[spIdx[i]]; tab.off[i] = tot; tot += spSz[i]; }
    tab.off[NSP] = tot;
    const bf16 *bsrc0 = pb + tab.off[0], *bdst0 = pb + tab.off[1], *attn0 = pb + tab.off[2],
               *bres0 = pb + tab.off[3], *bsrc1 = pb + tab.off[4], *bdst1 = pb + tab.off[5],
               *attn1 = pb + tab.off[6], *bsrc2 = pb + tab.off[7], *bdst2 = pb + tab.off[8],
               *attn2 = pb + tab.off[9], *bres2 = pb + tab.off[10],
               *g0 = pb + tab.off[11], *be0 = pb + tab.off[12],
               *g1 = pb + tab.off[13], *be1 = pb + tab.off[14];

    // ---- packed Wt: rows [0,384)=L0, [384,640)=L1, [640,1216)=L2 @MP=192, pad->1280 ----
    PrepTab pt;
    static const int wIdx[8] = {3, 5, 8, 10, 12, 15, 17, 20};
    static const int wK[8]   = {INF_, INF_, INF_, HD, HD, HD, HD, HD};
    static const int wM[8]   = {HD, HD, HD, HD, HD, HC, HC, HC};
    static const int wMP[8]  = {128, 128, 128, 128, 128, 192, 192, 192};
    static const int wR0[8]  = {0, 128, 256, 384, 512, 640, 832, 1024};
    for (int i = 0; i < 8; ++i) {
        pt.src[i] = d_in[wIdx[i]]; pt.row0[i] = wR0[i];
        pt.K[i] = wK[i]; pt.M[i] = wM[i]; pt.MP[i] = wMP[i];
    }

    detect_dtype<<<1, 64, 0, stream>>>((const unsigned*)x, flag);
    cvt_x<<<(Nn * 128 + 255) / 256, 256, 0, stream>>>(x, xb, flag);
    prep_all<<<(WROWS * 128 + 255) / 256, 256, 0, stream>>>(pt, tab, wtb, pb, tot, flag);
    src_scale_ptr<<<(Ee + 255) / 256, 256, 0, stream>>>(src, dst, w384, w256, ptr,
                                                        bns0, bns1);
    deg_hist_blk<<<NBLK, 256, 0, stream>>>(ptr, cnt);
    deg_totals<<<64, 256, 0, stream>>>(cnt, totals);
    deg_bases<<<64, 256, 0, stream>>>(cnt, totals, cbase);
    deg_scatter_blk<<<NBLK, 256, 0, stream>>>(ptr, cbase, perm);

    const int fusedGrid = (Nn + 7) / 8;   // 512-thread blocks, 8 dsts each
    const int statsGrid = NBLK;
    const int rowBlk = (Nn + 63) / 64;  // 1563

    // ---------------- layer 0 (384 cols: y=2 x CS=3) ----------------
    gemm_big<128, 3, 3, false, false, HD><<<dim3(rowBlk, 2), 256, 0, stream>>>(
        xb, wtb, bsrc0, bdst0, bres0, fs, fd, rb, HD, nullptr);
    gat_fused_128<false><<<fusedGrid, 512, 0, stream>>>(fs, fd, w256, ptr, perm,
                                                        attn0, rb, nullptr, hbA);
    col_stats<<<statsGrid, 128, 0, stream>>>(hbA, bns0);
    bn_finalize<<<1, HD, 0, stream>>>(bns0, g0, be0, bnss0);

    // ---------------- layer 1 (256 cols: y=2 x CS=2) ----------------
    gemm_big<128, 2, 2, true, false, HD><<<dim3(rowBlk, 2), 256, 0, stream>>>(
        hbA, wtb + (size_t)384 * 128, bsrc1, bdst1, nullptr, fs, fd, nullptr, HD, bnss0);
    gat_fused_128<true><<<fusedGrid, 512, 0, stream>>>(fs, fd, w256, ptr, perm,
                                                       attn1, hbA, bnss0, hbB);
    col_stats<<<statsGrid, 128, 0, stream>>>(hbB, bns1);
    bn_finalize<<<1, HD, 0, stream>>>(bns1, g1, be1, bnss1);

    // ---------------- layer 2 (576 cols: y=3 x CS=3, split-pack outputs) ----------
    gemm_big<192, 3, 3, true, true, HCP><<<dim3(rowBlk, 3), 256, 0, stream>>>(
        hbB, wtb + (size_t)640 * 128, bsrc2, bdst2, bres2, fs, fd, rs, HC, bnss1);
    gat_fused_188<<<fusedGrid, 512, 0, stream>>>(fs, fd, w384, ptr, perm, attn2, rs,
                                                 d_out, flag);
}

// Round 8
// 676.895 us; speedup vs baseline: 1.0412x; 1.0316x over previous
//
#include <hip/hip_runtime.h>
#include <hip/hip_bf16.h>

#define Nn 100000
#define Ee 1000000
#define INF_ 100
#define Hh 4
#define Dd 32
#define HD 128
#define Cc 47
#define HC 188
#define HCP 192
#define EPSV 1e-5f
#define SLOPE 0.2f
#define NBLK ((Nn + 255) / 256)

typedef __hip_bfloat16 bf16;
typedef __attribute__((ext_vector_type(8))) short short8;
typedef __attribute__((ext_vector_type(4))) float f32x4;
typedef __attribute__((ext_vector_type(2))) float f32x2;

__device__ __forceinline__ float tof(bf16 v) { return __bfloat162float(v); }
__device__ __forceinline__ float b2f(unsigned short u) {
    return __uint_as_float((unsigned)u << 16);
}
__device__ __forceinline__ float ldb(const bf16* p) {
    return b2f(*(const unsigned short*)p);
}
__device__ __forceinline__ unsigned short f2u(float v) {
    bf16 t = __float2bfloat16(v);
    return *(unsigned short*)&t;
}
__device__ __forceinline__ f32x2 pk2(float x, float y) {
    f32x2 r; r.x = x; r.y = y; return r;
}
__device__ __forceinline__ f32x2 pabs2(f32x2 v) {          // v_pk_max_f32 v, -v
    return __builtin_elementwise_max(v, -v);
}
__device__ __forceinline__ f32x2 pfma2(f32x2 a, f32x2 b, f32x2 c) {
    return __builtin_elementwise_fma(a, b, c);             // v_pk_fma_f32
}

// DPP-fused 16-lane reduces (quad_perm swaps + row rotates; row=16 lanes).
template <int C>
__device__ __forceinline__ float dppadd(float v) {
    int m = __builtin_amdgcn_update_dpp(0, __float_as_int(v), C, 0xF, 0xF, false);
    return v + __int_as_float(m);
}
template <int C>
__device__ __forceinline__ float dppmax(float v) {
    int m = __builtin_amdgcn_update_dpp(0, __float_as_int(v), C, 0xF, 0xF, false);
    return fmaxf(v, __int_as_float(m));
}
__device__ __forceinline__ float sum16(float p) {
    p = dppadd<0xB1>(p);   // quad_perm [1,0,3,2]
    p = dppadd<0x4E>(p);   // quad_perm [2,3,0,1]
    p = dppadd<0x124>(p);  // row_ror:4
    p = dppadd<0x128>(p);  // row_ror:8
    return p;
}
__device__ __forceinline__ float max16(float p) {
    p = dppmax<0xB1>(p); p = dppmax<0x4E>(p);
    p = dppmax<0x124>(p); p = dppmax<0x128>(p);
    return p;
}

#define L2E 1.4426950408889634f
#define LN2 0.6931471805599453f

// ---------------- dtype detect: 1 = bf16 buffers, 0 = fp32 buffers ----------------
__global__ void detect_dtype(const unsigned* __restrict__ x, int* __restrict__ flag) {
    if (blockIdx.x == 0 && threadIdx.x == 0) {
        int good = 0;
        for (int i = 0; i < 256; ++i) {
            unsigned lo = x[i] & 0xFFFFu;
            float v = __uint_as_float(lo << 16);
            float a = fabsf(v);
            if (a > 1e-4f && a < 10.f) good++;
        }
        *flag = (good >= 128) ? 1 : 0;
    }
}

__device__ __forceinline__ float ld_any(const void* p, int i, int isbf) {
    return isbf ? tof(((const bf16*)p)[i]) : ((const float*)p)[i];
}

// ---------------- x -> canonical bf16, padded to row stride 128 ----------------
__global__ void cvt_x(const void* __restrict__ in, bf16* __restrict__ out,
                      const int* __restrict__ flag) {
    int i = blockIdx.x * blockDim.x + threadIdx.x;
    if (i >= Nn * 128) return;
    int row = i >> 7, col = i & 127;
    float v = (col < INF_) ? ld_any(in, row * INF_ + col, *flag) : 0.f;
    out[i] = __float2bfloat16(v);
}

// ---------------- weights -> packed transposed Wt[1280][128]  (+ small params) ----
#define WROWS 1280
#define NSP 15
struct PrepTab { const void* src[8]; int row0[8]; int K[8]; int M[8]; int MP[8]; };
struct CvtTab { const void* src[NSP]; int off[NSP + 1]; };

__global__ void prep_all(PrepTab t, CvtTab ct, bf16* __restrict__ wtb,
                         bf16* __restrict__ pb, int total,
                         const int* __restrict__ flag) {
    int i = blockIdx.x * blockDim.x + threadIdx.x;
    int isbf = *flag;
    if (i < WROWS * 128) {
        int row = i >> 7, k = i & 127;
        float v = 0.f;
#pragma unroll
        for (int q = 0; q < 8; ++q) {
            if (row >= t.row0[q] && row < t.row0[q] + t.MP[q]) {
                int m = row - t.row0[q];
                if (m < t.M[q] && k < t.K[q])
                    v = ld_any(t.src[q], k * t.M[q] + m, isbf);
            }
        }
        wtb[i] = __float2bfloat16(v);
    }
    if (i < total) {   // small params (biases/attn/bn) -> canonical bf16
        int seg = 0;
        while (i >= ct.off[seg + 1]) seg++;
        pb[i] = __float2bfloat16(ld_any(ct.src[seg], i - ct.off[seg], isbf));
    }
}

// ---------------- fused: CSR build + pre-scaled src offsets + bns zeroing ---------
__global__ void src_scale_ptr(const int* __restrict__ src, const int* __restrict__ dst,
                              unsigned* __restrict__ w384, unsigned* __restrict__ w256,
                              int* __restrict__ ptr,
                              float* __restrict__ z0, float* __restrict__ z1) {
    int i = blockIdx.x * blockDim.x + threadIdx.x;
    if (i < Ee) {
        unsigned s = (unsigned)src[i];
        w384[i] = s * 384u;  // stride HCP*2 bytes (layer-2 pad47 fs)
        w256[i] = s << 8;    // stride HD*2 bytes  (layer-0/1 fs)
    }
    if (i < 2 * HD) { z0[i] = 0.f; z1[i] = 0.f; }   // BN stat accumulators
    if (i <= Nn) {
        if (i == Nn) { ptr[Nn] = Ee; return; }
        int lo = 0, hi = Ee;
        while (lo < hi) {
            int mid = (lo + hi) >> 1;
            if (dst[mid] < i) lo = mid + 1; else hi = mid;
        }
        ptr[i] = lo;
    }
}

// ---------------- degree-descending LPT permutation (block counting sort) ---------
// NO global atomics, NO serial single-CU scans. cnt/base are BIN-MAJOR
// [bin][NBLK] so per-bin walks coalesce across lanes.
__global__ void deg_hist_blk(const int* __restrict__ ptr, int* __restrict__ cnt) {
    __shared__ int lh[256];
    int t = threadIdx.x;
    lh[t] = 0;
    __syncthreads();
    int n = blockIdx.x * 256 + t;
    if (n < Nn) {
        int dg = ptr[n + 1] - ptr[n]; if (dg > 255) dg = 255;
        atomicAdd(&lh[dg], 1);
    }
    __syncthreads();
    cnt[t * NBLK + blockIdx.x] = lh[t];
}

// one wave per bin (64 blocks x 4 waves): lane-strided coalesced total
__global__ void deg_totals(const int* __restrict__ cnt, int* __restrict__ totals) {
    int wave = threadIdx.x >> 6, lane = threadIdx.x & 63;
    int bin = blockIdx.x * 4 + wave;
    int s = 0;
    for (int k = lane; k < NBLK; k += 64) s += cnt[bin * NBLK + k];
#pragma unroll
    for (int o = 1; o < 64; o <<= 1) s += __shfl_xor(s, o);
    if (lane == 0) totals[bin] = s;
}

// one wave per bin: binbase = sum of totals over HIGHER-degree bins, then
// chunked 64-lane exclusive prefix over the NBLK per-block counts.
__global__ void deg_bases(const int* __restrict__ cnt, const int* __restrict__ totals,
                          int* __restrict__ base) {
    int wave = threadIdx.x >> 6, lane = threadIdx.x & 63;
    int bin = blockIdx.x * 4 + wave;
    int bb = 0;
    for (int b = bin + 1 + lane; b < 256; b += 64) bb += totals[b];
#pragma unroll
    for (int o = 1; o < 64; o <<= 1) bb += __shfl_xor(bb, o);
    int run = bb;   // descending-degree base for this bin
    for (int k0 = 0; k0 < NBLK; k0 += 64) {
        int k = k0 + lane;
        int c = (k < NBLK) ? cnt[bin * NBLK + k] : 0;
        int p = c;
#pragma unroll
        for (int o = 1; o < 64; o <<= 1) {
            int t = __shfl_up(p, o);
            if (lane >= o) p += t;
        }
        if (k < NBLK) base[bin * NBLK + k] = run + (p - c);
        run += __shfl(p, 63);
    }
}

__global__ void deg_scatter_blk(const int* __restrict__ ptr, const int* __restrict__ base,
                                int* __restrict__ perm) {
    __shared__ int lh[256];
    int t = threadIdx.x;
    lh[t] = 0;
    __syncthreads();
    int n = blockIdx.x * 256 + t;
    if (n < Nn) {
        int dg = ptr[n + 1] - ptr[n]; if (dg > 255) dg = 255;
        int loc = atomicAdd(&lh[dg], 1);   // LDS atomic: one CU, cheap
        perm[base[dg * NBLK + blockIdx.x] + loc] = n;
    }
}

// ---------------- big-tile MFMA GEMM: 64 rows x (64*CS) cols per block -------------
// y-grid column split (deep grid hides scattered-store latency; NY-in-kernel
// loop regressed 41us - keep grid). PAD47 (layer-2): store col lc at
// lc + lc/47 (head-major 48-pad), row stride OSTR=192.
template <int MP, int NOUT, int CS, bool ABN, bool PAD47, int OSTR>
__global__ __launch_bounds__(256, 4) void gemm_big(
    const bf16* __restrict__ A, const bf16* __restrict__ Wt,
    const bf16* __restrict__ b0, const bf16* __restrict__ b1,
    const bf16* __restrict__ b2,
    bf16* __restrict__ o0, bf16* __restrict__ o1, bf16* __restrict__ o2,
    int MR, const float* __restrict__ bnp) {
    __shared__ __align__(16) bf16 Al[64 * 136];
    const int row0 = blockIdx.x * 64;
    const int tid = threadIdx.x;
#pragma unroll
    for (int j = 0; j < 4; ++j) {
        int idx = tid + j * 256;          // 0..1023 int4 slots
        int r = idx >> 4, kk = (idx & 15) * 8;
        int4 val = {0, 0, 0, 0};
        if (row0 + r < Nn) {
            val = *(const int4*)&A[(size_t)(row0 + r) * 128 + kk];
            if (ABN) {
                short8 av = *(short8*)&val;
                bf16 tmp[8];
#pragma unroll
                for (int u = 0; u < 8; ++u) {
                    float v = b2f((unsigned short)av[u]);
                    v = fmaxf(fmaf(v, bnp[kk + u], bnp[128 + kk + u]), 0.f);
                    tmp[u] = __float2bfloat16(v);
                }
                val = *(int4*)tmp;
            }
        }
        *(int4*)&Al[r * 136 + kk] = val;
    }
    __syncthreads();
    const int wave = tid >> 6, lane = tid & 63;
    const int n16 = lane & 15, quad = lane >> 4;
    const int colbase = blockIdx.y * (64 * CS) + wave * (16 * CS);
    f32x4 acc[4][CS];
#pragma unroll
    for (int rt = 0; rt < 4; ++rt)
#pragma unroll
        for (int c = 0; c < CS; ++c) acc[rt][c] = (f32x4){0.f, 0.f, 0.f, 0.f};
    const bf16* wb[CS];
#pragma unroll
    for (int c = 0; c < CS; ++c)
        wb[c] = Wt + (size_t)(colbase + c * 16 + n16) * 128 + quad * 8;
    const bf16* ap = Al + n16 * 136 + quad * 8;
#pragma unroll
    for (int ks = 0; ks < 4; ++ks) {
        short8 bf[CS];
#pragma unroll
        for (int c = 0; c < CS; ++c) bf[c] = *(const short8*)(wb[c] + ks * 32);
#pragma unroll
        for (int rt = 0; rt < 4; ++rt) {
            short8 af = *(const short8*)(ap + rt * 16 * 136 + ks * 32);
#pragma unroll
            for (int c = 0; c < CS; ++c)
                acc[rt][c] = __builtin_amdgcn_mfma_f32_16x16x32_bf16(af, bf[c], acc[rt][c], 0, 0, 0);
        }
    }
#pragma unroll
    for (int c = 0; c < CS; ++c) {
        int col = colbase + c * 16 + n16;
        int oi = col / MP, lc = col - oi * MP;
        if (oi >= NOUT || lc >= MR) continue;
        const bf16* bp = (oi == 0) ? b0 : (oi == 1) ? b1 : b2;
        bf16* o = (oi == 0) ? o0 : (oi == 1) ? o1 : o2;
        float bb = tof(bp[lc]);
        int st = PAD47 ? (lc + lc / 47) : lc;
#pragma unroll
        for (int rt = 0; rt < 4; ++rt) {
#pragma unroll
            for (int i = 0; i < 4; ++i) {
                int row = row0 + rt * 16 + quad * 4 + i;
                if (row < Nn)
                    o[(size_t)row * OSTR + st] = __float2bfloat16(acc[rt][c][i] + bb);
            }
        }
    }
}

// ---------------- fused GATv2 edge kernel, M=128 (layers 0,1) ----------------
// 256 threads = 4 dsts/block (512-thread blocks regressed 83->95us - keep 256).
// Lane holds cols (2*lane, 2*lane+1). MAX-FREE softmax, log2e folded into attn.
// Packed-FP32 math; aligned uint4 srcW prefetch (1 VMEM per 4 edges).
template <bool RESBN>
__global__ __launch_bounds__(256) void gat_fused_128(
    const bf16* __restrict__ fs, const bf16* __restrict__ fd,
    const unsigned* __restrict__ srcW, const int* __restrict__ ptr,
    const int* __restrict__ perm,
    const bf16* __restrict__ attn, const bf16* __restrict__ resb,
    const float* __restrict__ bnp, bf16* __restrict__ hout) {
    const int wave = threadIdx.x >> 6, lane = threadIdx.x & 63;
    const int di = blockIdx.x * 4 + wave;
    if (di >= Nn) return;
    const int d = perm[di];
    const int c0 = lane * 2;
    const unsigned c0b = (unsigned)c0 * 2u;
    ushort2 aq = *(const ushort2*)&attn[c0];
    float a0 = b2f(aq.x) * L2E, a1 = b2f(aq.y) * L2E;
    const f32x2 Av = pk2(0.6f * a0, 0.6f * a1);
    const f32x2 Bv = pk2(0.4f * a0, 0.4f * a1);
    ushort2 dq = *(const ushort2*)&fd[(size_t)d * HD + c0];
    const f32x2 fdv = pk2(b2f(dq.x), b2f(dq.y));
    const char* fsb = (const char*)fs;
    float l = 0.f;
    f32x2 Ov = pk2(0.f, 0.f);
    int e = ptr[d];
    const int e1 = ptr[d + 1];
    // peel to 4-alignment so the main loop can use one aligned uint4 load
    for (; e < e1 && (e & 3); ++e) {
        unsigned v = srcW[e] + c0b;
        ushort2 fq = *(const ushort2*)(fsb + v);
        f32x2 f = pk2(b2f(fq.x), b2f(fq.y));
        f32x2 x = f + fdv;
        f32x2 t = pfma2(pabs2(x), Bv, x * Av);
        float p = sum16(t.x + t.y);
        float pe = __builtin_amdgcn_exp2f(p);
        l += pe;
        Ov = pfma2(pk2(pe, pe), f, Ov);
    }
    for (; e + 3 < e1; e += 4) {
        uint4 sw = *(const uint4*)&srcW[e];
        unsigned vA = sw.x + c0b, vB = sw.y + c0b;
        unsigned vC = sw.z + c0b, vD = sw.w + c0b;
        ushort2 qA = *(const ushort2*)(fsb + vA);
        ushort2 qB = *(const ushort2*)(fsb + vB);
        ushort2 qC = *(const ushort2*)(fsb + vC);
        ushort2 qD = *(const ushort2*)(fsb + vD);
        f32x2 fA = pk2(b2f(qA.x), b2f(qA.y));
        f32x2 fB = pk2(b2f(qB.x), b2f(qB.y));
        f32x2 fC = pk2(b2f(qC.x), b2f(qC.y));
        f32x2 fD = pk2(b2f(qD.x), b2f(qD.y));
        f32x2 xA = fA + fdv, xB = fB + fdv, xC = fC + fdv, xD = fD + fdv;
        f32x2 tA = pfma2(pabs2(xA), Bv, xA * Av);
        f32x2 tB = pfma2(pabs2(xB), Bv, xB * Av);
        f32x2 tC = pfma2(pabs2(xC), Bv, xC * Av);
        f32x2 tD = pfma2(pabs2(xD), Bv, xD * Av);
        float pA = tA.x + tA.y, pB = tB.x + tB.y;
        float pC = tC.x + tC.y, pD = tD.x + tD.y;
        pA = sum16(pA); pB = sum16(pB); pC = sum16(pC); pD = sum16(pD);
        float eA = __builtin_amdgcn_exp2f(pA), eB = __builtin_amdgcn_exp2f(pB);
        float eC = __builtin_amdgcn_exp2f(pC), eD = __builtin_amdgcn_exp2f(pD);
        l += (eA + eB) + (eC + eD);
        Ov = pfma2(pk2(eA, eA), fA, Ov);
        Ov = pfma2(pk2(eB, eB), fB, Ov);
        Ov = pfma2(pk2(eC, eC), fC, Ov);
        Ov = pfma2(pk2(eD, eD), fD, Ov);
    }
    for (; e < e1; ++e) {
        unsigned v = srcW[e] + c0b;
        ushort2 fq = *(const ushort2*)(fsb + v);
        f32x2 f = pk2(b2f(fq.x), b2f(fq.y));
        f32x2 x = f + fdv;
        f32x2 t = pfma2(pabs2(x), Bv, x * Av);
        float p = sum16(t.x + t.y);
        float pe = __builtin_amdgcn_exp2f(p);
        l += pe;
        Ov = pfma2(pk2(pe, pe), f, Ov);
    }
    float inv = l > 0.f ? 1.f / l : 0.f;
    ushort2 rq = *(const ushort2*)&resb[(size_t)d * HD + c0];
    float r0 = b2f(rq.x), r1 = b2f(rq.y);
    if (RESBN) {
        r0 = fmaxf(fmaf(r0, bnp[c0], bnp[HD + c0]), 0.f);
        r1 = fmaxf(fmaf(r1, bnp[c0 + 1], bnp[HD + c0 + 1]), 0.f);
    }
    float v0 = fmaxf(fmaf(Ov.x, inv, r0), 0.f);  // conv activation relu
    float v1 = fmaxf(fmaf(Ov.y, inv, r1), 0.f);
    ushort2 ov; ov.x = f2u(v0); ov.y = f2u(v1);
    *(ushort2*)&hout[(size_t)d * HD + c0] = ov;
}

// ---------------- fused GATv2 edge kernel, layer 2, PAD47 stride 192 -------------
// MEASURED-BEST variant (r2: 79.9us vs split-pack/pk/peel r5: 83.3us).
// Lane = 16*h + j owns cc {j, j+16, j+32} at c0=h*48+j; 3 scalar ushort gathers
// per edge; scalar fmaf chain; scalar srcW loads; NO alignment peel (peel's
// ~1.5 extra single-edge iters at mean degree 10 cost more than 3 VMEM slots).
__global__ __launch_bounds__(256) void gat_fused_188(
    const bf16* __restrict__ fs, const bf16* __restrict__ fd,
    const unsigned* __restrict__ srcW, const int* __restrict__ ptr,
    const int* __restrict__ perm,
    const bf16* __restrict__ attn, const bf16* __restrict__ rs,
    void* __restrict__ out, const int* __restrict__ flag) {
    const int wave = threadIdx.x >> 6, lane = threadIdx.x & 63;
    const int di = blockIdx.x * 4 + wave;
    if (di >= Nn) return;
    const int d = perm[di];
    const int h = lane >> 4, j = lane & 15;
    const int c0 = h * 48 + j;        // padded layout
    const unsigned c0b = (unsigned)c0 * 2u;
    const int ca = h * Cc + j;        // attn is unpadded [188]
    const bool has2 = (j < 15);
    float a0 = ldb(&attn[ca]) * L2E;
    float a1 = ldb(&attn[ca + 16]) * L2E;
    float a2 = has2 ? ldb(&attn[ca + 32]) * L2E : 0.f;
    float A0 = 0.6f * a0, B0 = 0.4f * a0;
    float A1 = 0.6f * a1, B1 = 0.4f * a1;
    float A2 = 0.6f * a2, B2 = 0.4f * a2;
    const bf16* fdr = fd + (size_t)d * HCP;
    float fd0 = ldb(&fdr[c0]);
    float fd1 = ldb(&fdr[c0 + 16]);
    float fd2 = ldb(&fdr[c0 + 32]);   // pad garbage OK: A2=B2=0 masks
    const char* fsb = (const char*)fs;
    float l = 0.f, O0 = 0.f, O1 = 0.f, O2 = 0.f;
    int e = ptr[d];
    const int e1 = ptr[d + 1];
    for (; e + 3 < e1; e += 4) {
        unsigned vA = srcW[e] + c0b, vB = srcW[e + 1] + c0b;
        unsigned vC = srcW[e + 2] + c0b, vD = srcW[e + 3] + c0b;
        float fA0 = b2f(*(const unsigned short*)(fsb + vA));
        float fA1 = b2f(*(const unsigned short*)(fsb + vA + 32));
        float fA2 = b2f(*(const unsigned short*)(fsb + vA + 64));
        float fB0 = b2f(*(const unsigned short*)(fsb + vB));
        float fB1 = b2f(*(const unsigned short*)(fsb + vB + 32));
        float fB2 = b2f(*(const unsigned short*)(fsb + vB + 64));
        float fC0 = b2f(*(const unsigned short*)(fsb + vC));
        float fC1 = b2f(*(const unsigned short*)(fsb + vC + 32));
        float fC2 = b2f(*(const unsigned short*)(fsb + vC + 64));
        float fD0 = b2f(*(const unsigned short*)(fsb + vD));
        float fD1 = b2f(*(const unsigned short*)(fsb + vD + 32));
        float fD2 = b2f(*(const unsigned short*)(fsb + vD + 64));
        float xA0 = fA0 + fd0, xA1 = fA1 + fd1, xA2 = fA2 + fd2;
        float xB0 = fB0 + fd0, xB1 = fB1 + fd1, xB2 = fB2 + fd2;
        float xC0 = fC0 + fd0, xC1 = fC1 + fd1, xC2 = fC2 + fd2;
        float xD0 = fD0 + fd0, xD1 = fD1 + fd1, xD2 = fD2 + fd2;
        float pA = fmaf(xA0, A0, fmaf(fabsf(xA0), B0, fmaf(xA1, A1, fmaf(fabsf(xA1), B1,
                   fmaf(xA2, A2, fabsf(xA2) * B2)))));
        float pB = fmaf(xB0, A0, fmaf(fabsf(xB0), B0, fmaf(xB1, A1, fmaf(fabsf(xB1), B1,
                   fmaf(xB2, A2, fabsf(xB2) * B2)))));
        float pC = fmaf(xC0, A0, fmaf(fabsf(xC0), B0, fmaf(xC1, A1, fmaf(fabsf(xC1), B1,
                   fmaf(xC2, A2, fabsf(xC2) * B2)))));
        float pD = fmaf(xD0, A0, fmaf(fabsf(xD0), B0, fmaf(xD1, A1, fmaf(fabsf(xD1), B1,
                   fmaf(xD2, A2, fabsf(xD2) * B2)))));
        pA = sum16(pA); pB = sum16(pB); pC = sum16(pC); pD = sum16(pD);
        float eA = __builtin_amdgcn_exp2f(pA), eB = __builtin_amdgcn_exp2f(pB);
        float eC = __builtin_amdgcn_exp2f(pC), eD = __builtin_amdgcn_exp2f(pD);
        l += (eA + eB) + (eC + eD);
        O0 = fmaf(eA, fA0, O0); O0 = fmaf(eB, fB0, O0);
        O0 = fmaf(eC, fC0, O0); O0 = fmaf(eD, fD0, O0);
        O1 = fmaf(eA, fA1, O1); O1 = fmaf(eB, fB1, O1);
        O1 = fmaf(eC, fC1, O1); O1 = fmaf(eD, fD1, O1);
        O2 = fmaf(eA, fA2, O2); O2 = fmaf(eB, fB2, O2);
        O2 = fmaf(eC, fC2, O2); O2 = fmaf(eD, fD2, O2);
    }
    for (; e < e1; ++e) {
        unsigned v = srcW[e] + c0b;
        float f0 = b2f(*(const unsigned short*)(fsb + v));
        float f1 = b2f(*(const unsigned short*)(fsb + v + 32));
        float f2 = b2f(*(const unsigned short*)(fsb + v + 64));
        float x0 = f0 + fd0, x1 = f1 + fd1, x2 = f2 + fd2;
        float p = fmaf(x0, A0, fmaf(fabsf(x0), B0, fmaf(x1, A1, fmaf(fabsf(x1), B1,
                  fmaf(x2, A2, fabsf(x2) * B2)))));
        p = sum16(p);
        float pe = __builtin_amdgcn_exp2f(p);
        l += pe;
        O0 = fmaf(pe, f0, O0);
        O1 = fmaf(pe, f1, O1);
        O2 = fmaf(pe, f2, O2);
    }
    // epilogue: +res, head-mean across lane groups, log_softmax, store
    float inv = l > 0.f ? 1.f / l : 0.f;
    const bf16* rr = rs + (size_t)d * HCP;
    float v0 = fmaf(O0, inv, ldb(&rr[c0]));
    float v1 = fmaf(O1, inv, ldb(&rr[c0 + 16]));
    float v2 = has2 ? fmaf(O2, inv, ldb(&rr[c0 + 32])) : 0.f;
    v0 += __shfl_xor(v0, 16); v0 += __shfl_xor(v0, 32); v0 *= 0.25f;
    v1 += __shfl_xor(v1, 16); v1 += __shfl_xor(v1, 32); v1 *= 0.25f;
    v2 += __shfl_xor(v2, 16); v2 += __shfl_xor(v2, 32); v2 *= 0.25f;
    float mx = fmaxf(v0, v1);
    if (has2) mx = fmaxf(mx, v2);
    mx = max16(mx);
    float sm = __expf(v0 - mx) + __expf(v1 - mx) + (has2 ? __expf(v2 - mx) : 0.f);
    sm = sum16(sm);
    if (h == 0) {
        float ls = mx + __log2f(sm) * LN2;
        if (*flag) {
            bf16* o = (bf16*)out + (size_t)d * Cc;
            o[j] = __float2bfloat16(v0 - ls);
            o[j + 16] = __float2bfloat16(v1 - ls);
            if (has2) o[j + 32] = __float2bfloat16(v2 - ls);
        } else {
            float* o = (float*)out + (size_t)d * Cc;
            o[j] = v0 - ls;
            o[j + 16] = v1 - ls;
            if (has2) o[j + 32] = v2 - ls;
        }
    }
}

// ---------------- per-column BN stats over bf16 h (atomic combine) ----------------
// 391 blocks x 128 threads; ONE atomicAdd per thread per stat (block-reduced
// first). ~100K total atomics over 256 addrs = a few us. (A single-block
// serial finalize regressed to 92us - do NOT revisit that design.)
__global__ void col_stats(const bf16* __restrict__ in, float* __restrict__ sums) {
    int c = threadIdx.x;  // 128
    int r0 = blockIdx.x * 256;
    int r1 = r0 + 256; if (r1 > Nn) r1 = Nn;
    float s = 0.f, s2 = 0.f;
    for (int r = r0; r < r1; ++r) {
        float v = ldb(&in[(size_t)r * HD + c]);
        s += v; s2 += v * v;
    }
    atomicAdd(&sums[c], s);
    atomicAdd(&sums[HD + c], s2);
}

__global__ void bn_finalize(const float* __restrict__ sums, const bf16* __restrict__ g,
                            const bf16* __restrict__ be, float* __restrict__ ss) {
    int c = threadIdx.x;  // 128
    float mu = sums[c] * (1.f / Nn);
    float var = sums[HD + c] * (1.f / Nn) - mu * mu;
    float sc = tof(g[c]) * rsqrtf(var + EPSV);
    ss[c] = sc;
    ss[HD + c] = tof(be[c]) - mu * sc;
}

extern "C" void kernel_launch(void* const* d_in, const int* in_sizes, int n_in,
                              void* d_out, int out_size, void* d_ws, size_t ws_size,
                              hipStream_t stream) {
    (void)in_sizes; (void)n_in; (void)out_size; (void)ws_size;
    const void* x = d_in[0];
    const int* src = (const int*)d_in[1];
    const int* dst = (const int*)d_in[2];

    char* ws = (char*)d_ws;
    size_t off = 0;
    auto alloc = [&](size_t bytes) {
        void* p = ws + off;
        off += (bytes + 255) & ~(size_t)255;
        return p;
    };
    // rs (38.4 MB, [Nn][192]) aliases xb+rb (51.2 MB): both dead before L2 GEMM.
    bf16* xb = (bf16*)alloc((size_t)Nn * 128 * 2);    // 25.6 MB (stride-128 padded x)
    bf16* rb = (bf16*)alloc((size_t)Nn * HD * 2);     // 25.6 MB
    bf16* rs = xb;                                    // [Nn][HCP] alias
    bf16* fs = (bf16*)alloc((size_t)Nn * HCP * 2);    // 38.4 MB
    bf16* fd = (bf16*)alloc((size_t)Nn * HCP * 2);    // 38.4 MB
    bf16* hbA = (bf16*)alloc((size_t)Nn * HD * 2);    // 25.6 MB
    bf16* hbB = (bf16*)alloc((size_t)Nn * HD * 2);    // 25.6 MB
    int* ptr = (int*)alloc((Nn + 1) * 4);             // 400 KB
    bf16* wtb = (bf16*)alloc((size_t)WROWS * 128 * 2);// 328 KB
    float* bns0 = (float*)alloc(2 * HD * 4);
    float* bns1 = (float*)alloc(2 * HD * 4);
    float* bnss0 = (float*)alloc(2 * HD * 4);
    float* bnss1 = (float*)alloc(2 * HD * 4);
    bf16* pb = (bf16*)alloc(4096 * 2);
    int* flag = (int*)alloc(256);
    unsigned* w384 = (unsigned*)alloc((size_t)Ee * 4);// 4 MB
    unsigned* w256 = (unsigned*)alloc((size_t)Ee * 4);// 4 MB
    int* cnt = (int*)alloc((size_t)256 * NBLK * 4);   // 400 KB
    int* cbase = (int*)alloc((size_t)256 * NBLK * 4); // 400 KB
    int* totals = (int*)alloc(256 * 4);
    int* perm = (int*)alloc((size_t)Nn * 4);          // 400 KB

    // ---- small-param conversion (biases/attn/bn): d_in idx -> pb arena ----
    static const int spIdx[NSP] = {4, 6, 7, 9, 11, 13, 14, 16, 18, 19, 21, 22, 23, 24, 25};
    static const int spSz[NSP]  = {HD, HD, HD, HD, HD, HD, HD, HC, HC, HC, HC, HD, HD, HD, HD};
    CvtTab tab;
    int tot = 0;
    for (int i = 0; i < NSP; ++i) { tab.src[i] = d_in[spIdx[i]]; tab.off[i] = tot; tot += spSz[i]; }
    tab.off[NSP] = tot;
    const bf16 *bsrc0 = pb + tab.off[0], *bdst0 = pb + tab.off[1], *attn0 = pb + tab.off[2],
               *bres0 = pb + tab.off[3], *bsrc1 = pb + tab.off[4], *bdst1 = pb + tab.off[5],
               *attn1 = pb + tab.off[6], *bsrc2 = pb + tab.off[7], *bdst2 = pb + tab.off[8],
               *attn2 = pb + tab.off[9], *bres2 = pb + tab.off[10],
               *g0 = pb + tab.off[11], *be0 = pb + tab.off[12],
               *g1 = pb + tab.off[13], *be1 = pb + tab.off[14];

    // ---- packed Wt: rows [0,384)=L0, [384,640)=L1, [640,1216)=L2 @MP=192, pad->1280 ----
    PrepTab pt;
    static const int wIdx[8] = {3, 5, 8, 10, 12, 15, 17, 20};
    static const int wK[8]   = {INF_, INF_, INF_, HD, HD, HD, HD, HD};
    static const int wM[8]   = {HD, HD, HD, HD, HD, HC, HC, HC};
    static const int wMP[8]  = {128, 128, 128, 128, 128, 192, 192, 192};
    static const int wR0[8]  = {0, 128, 256, 384, 512, 640, 832, 1024};
    for (int i = 0; i < 8; ++i) {
        pt.src[i] = d_in[wIdx[i]]; pt.row0[i] = wR0[i];
        pt.K[i] = wK[i]; pt.M[i] = wM[i]; pt.MP[i] = wMP[i];
    }

    detect_dtype<<<1, 64, 0, stream>>>((const unsigned*)x, flag);
    cvt_x<<<(Nn * 128 + 255) / 256, 256, 0, stream>>>(x, xb, flag);
    prep_all<<<(WROWS * 128 + 255) / 256, 256, 0, stream>>>(pt, tab, wtb, pb, tot, flag);
    src_scale_ptr<<<(Ee + 255) / 256, 256, 0, stream>>>(src, dst, w384, w256, ptr,
                                                        bns0, bns1);
    deg_hist_blk<<<NBLK, 256, 0, stream>>>(ptr, cnt);
    deg_totals<<<64, 256, 0, stream>>>(cnt, totals);
    deg_bases<<<64, 256, 0, stream>>>(cnt, totals, cbase);
    deg_scatter_blk<<<NBLK, 256, 0, stream>>>(ptr, cbase, perm);

    const int fusedGrid = (Nn + 3) / 4;   // 256-thread blocks, 4 dsts each
    const int statsGrid = NBLK;
    const int rowBlk = (Nn + 63) / 64;  // 1563

    // ---------------- layer 0 (384 cols: y=2 x CS=3) ----------------
    gemm_big<128, 3, 3, false, false, HD><<<dim3(rowBlk, 2), 256, 0, stream>>>(
        xb, wtb, bsrc0, bdst0, bres0, fs, fd, rb, HD, nullptr);
    gat_fused_128<false><<<fusedGrid, 256, 0, stream>>>(fs, fd, w256, ptr, perm,
                                                        attn0, rb, nullptr, hbA);
    col_stats<<<statsGrid, 128, 0, stream>>>(hbA, bns0);
    bn_finalize<<<1, HD, 0, stream>>>(bns0, g0, be0, bnss0);

    // ---------------- layer 1 (256 cols: y=2 x CS=2) ----------------
    gemm_big<128, 2, 2, true, false, HD><<<dim3(rowBlk, 2), 256, 0, stream>>>(
        hbA, wtb + (size_t)384 * 128, bsrc1, bdst1, nullptr, fs, fd, nullptr, HD, bnss0);
    gat_fused_128<true><<<fusedGrid, 256, 0, stream>>>(fs, fd, w256, ptr, perm,
                                                       attn1, hbA, bnss0, hbB);
    col_stats<<<statsGrid, 128, 0, stream>>>(hbB, bns1);
    bn_finalize<<<1, HD, 0, stream>>>(bns1, g1, be1, bnss1);

    // ---------------- layer 2 (576 cols: y=3 x CS=3, pad47 outputs) ---------------
    gemm_big<192, 3, 3, true, true, HCP><<<dim3(rowBlk, 3), 256, 0, stream>>>(
        hbB, wtb + (size_t)640 * 128, bsrc2, bdst2, bres2, fs, fd, rs, HC, bnss1);
    gat_fused_188<<<fusedGrid, 256, 0, stream>>>(fs, fd, w384, ptr, perm, attn2, rs,
                                                 d_out, flag);
}

// Round 9
// 663.739 us; speedup vs baseline: 1.0619x; 1.0198x over previous
//
#include <hip/hip_runtime.h>
#include <hip/hip_bf16.h>

#define Nn 100000
#define Ee 1000000
#define INF_ 100
#define Hh 4
#define Dd 32
#define HD 128
#define Cc 47
#define HC 188
#define HCP 192
#define EPSV 1e-5f
#define SLOPE 0.2f
#define NBLK ((Nn + 255) / 256)

typedef __hip_bfloat16 bf16;
typedef __attribute__((ext_vector_type(8))) short short8;
typedef __attribute__((ext_vector_type(4))) float f32x4;
typedef __attribute__((ext_vector_type(2))) float f32x2;

__device__ __forceinline__ float tof(bf16 v) { return __bfloat162float(v); }
__device__ __forceinline__ float b2f(unsigned short u) {
    return __uint_as_float((unsigned)u << 16);
}
__device__ __forceinline__ float ldb(const bf16* p) {
    return b2f(*(const unsigned short*)p);
}
__device__ __forceinline__ unsigned short f2u(float v) {
    bf16 t = __float2bfloat16(v);
    return *(unsigned short*)&t;
}
__device__ __forceinline__ f32x2 pk2(float x, float y) {
    f32x2 r; r.x = x; r.y = y; return r;
}
__device__ __forceinline__ f32x2 pabs2(f32x2 v) {          // v_pk_max_f32 v, -v
    return __builtin_elementwise_max(v, -v);
}
__device__ __forceinline__ f32x2 pfma2(f32x2 a, f32x2 b, f32x2 c) {
    return __builtin_elementwise_fma(a, b, c);             // v_pk_fma_f32
}

// DPP-fused 16-lane reduces (quad_perm swaps + row rotates; row=16 lanes).
template <int C>
__device__ __forceinline__ float dppadd(float v) {
    int m = __builtin_amdgcn_update_dpp(0, __float_as_int(v), C, 0xF, 0xF, false);
    return v + __int_as_float(m);
}
template <int C>
__device__ __forceinline__ float dppmax(float v) {
    int m = __builtin_amdgcn_update_dpp(0, __float_as_int(v), C, 0xF, 0xF, false);
    return fmaxf(v, __int_as_float(m));
}
__device__ __forceinline__ float sum16(float p) {
    p = dppadd<0xB1>(p);   // quad_perm [1,0,3,2]
    p = dppadd<0x4E>(p);   // quad_perm [2,3,0,1]
    p = dppadd<0x124>(p);  // row_ror:4
    p = dppadd<0x128>(p);  // row_ror:8
    return p;
}
__device__ __forceinline__ float max16(float p) {
    p = dppmax<0xB1>(p); p = dppmax<0x4E>(p);
    p = dppmax<0x124>(p); p = dppmax<0x128>(p);
    return p;
}

#define L2E 1.4426950408889634f
#define LN2 0.6931471805599453f

// ---------------- dtype detect: 1 = bf16 buffers, 0 = fp32 buffers ----------------
__global__ void detect_dtype(const unsigned* __restrict__ x, int* __restrict__ flag) {
    if (blockIdx.x == 0 && threadIdx.x == 0) {
        int good = 0;
        for (int i = 0; i < 256; ++i) {
            unsigned lo = x[i] & 0xFFFFu;
            float v = __uint_as_float(lo << 16);
            float a = fabsf(v);
            if (a > 1e-4f && a < 10.f) good++;
        }
        *flag = (good >= 128) ? 1 : 0;
    }
}

__device__ __forceinline__ float ld_any(const void* p, int i, int isbf) {
    return isbf ? tof(((const bf16*)p)[i]) : ((const float*)p)[i];
}

// ---------------- x -> canonical bf16, padded to row stride 128 ----------------
__global__ void cvt_x(const void* __restrict__ in, bf16* __restrict__ out,
                      const int* __restrict__ flag) {
    int i = blockIdx.x * blockDim.x + threadIdx.x;
    if (i >= Nn * 128) return;
    int row = i >> 7, col = i & 127;
    float v = (col < INF_) ? ld_any(in, row * INF_ + col, *flag) : 0.f;
    out[i] = __float2bfloat16(v);
}

// ---------------- weights -> packed transposed Wt[1280][128]  (+ small params) ----
#define WROWS 1280
#define NSP 15
struct PrepTab { const void* src[8]; int row0[8]; int K[8]; int M[8]; int MP[8]; };
struct CvtTab { const void* src[NSP]; int off[NSP + 1]; };

__global__ void prep_all(PrepTab t, CvtTab ct, bf16* __restrict__ wtb,
                         bf16* __restrict__ pb, int total,
                         const int* __restrict__ flag) {
    int i = blockIdx.x * blockDim.x + threadIdx.x;
    int isbf = *flag;
    if (i < WROWS * 128) {
        int row = i >> 7, k = i & 127;
        float v = 0.f;
#pragma unroll
        for (int q = 0; q < 8; ++q) {
            if (row >= t.row0[q] && row < t.row0[q] + t.MP[q]) {
                int m = row - t.row0[q];
                if (m < t.M[q] && k < t.K[q])
                    v = ld_any(t.src[q], k * t.M[q] + m, isbf);
            }
        }
        wtb[i] = __float2bfloat16(v);
    }
    if (i < total) {   // small params (biases/attn/bn) -> canonical bf16
        int seg = 0;
        while (i >= ct.off[seg + 1]) seg++;
        pb[i] = __float2bfloat16(ld_any(ct.src[seg], i - ct.off[seg], isbf));
    }
}

// ---------------- fused: CSR build + pre-scaled src offsets + bns zeroing ---------
__global__ void src_scale_ptr(const int* __restrict__ src, const int* __restrict__ dst,
                              unsigned* __restrict__ w384, unsigned* __restrict__ w256,
                              int* __restrict__ ptr,
                              float* __restrict__ z0, float* __restrict__ z1) {
    int i = blockIdx.x * blockDim.x + threadIdx.x;
    if (i < Ee) {
        unsigned s = (unsigned)src[i];
        w384[i] = s * 384u;  // stride HCP*2 bytes (layer-2 pad47 fs)
        w256[i] = s << 8;    // stride HD*2 bytes  (layer-0/1 fs)
    }
    if (i < 2 * HD) { z0[i] = 0.f; z1[i] = 0.f; }   // BN stat accumulators
    if (i <= Nn) {
        if (i == Nn) { ptr[Nn] = Ee; return; }
        int lo = 0, hi = Ee;
        while (lo < hi) {
            int mid = (lo + hi) >> 1;
            if (dst[mid] < i) lo = mid + 1; else hi = mid;
        }
        ptr[i] = lo;
    }
}

// ---------------- degree-descending LPT permutation (block counting sort) ---------
// NO global atomics, NO serial single-CU scans. cnt/base are BIN-MAJOR
// [bin][NBLK] so per-bin walks coalesce across lanes.
__global__ void deg_hist_blk(const int* __restrict__ ptr, int* __restrict__ cnt) {
    __shared__ int lh[256];
    int t = threadIdx.x;
    lh[t] = 0;
    __syncthreads();
    int n = blockIdx.x * 256 + t;
    if (n < Nn) {
        int dg = ptr[n + 1] - ptr[n]; if (dg > 255) dg = 255;
        atomicAdd(&lh[dg], 1);
    }
    __syncthreads();
    cnt[t * NBLK + blockIdx.x] = lh[t];
}

// one wave per bin (64 blocks x 4 waves): lane-strided coalesced total
__global__ void deg_totals(const int* __restrict__ cnt, int* __restrict__ totals) {
    int wave = threadIdx.x >> 6, lane = threadIdx.x & 63;
    int bin = blockIdx.x * 4 + wave;
    int s = 0;
    for (int k = lane; k < NBLK; k += 64) s += cnt[bin * NBLK + k];
#pragma unroll
    for (int o = 1; o < 64; o <<= 1) s += __shfl_xor(s, o);
    if (lane == 0) totals[bin] = s;
}

// one wave per bin: binbase = sum of totals over HIGHER-degree bins, then
// chunked 64-lane exclusive prefix over the NBLK per-block counts.
__global__ void deg_bases(const int* __restrict__ cnt, const int* __restrict__ totals,
                          int* __restrict__ base) {
    int wave = threadIdx.x >> 6, lane = threadIdx.x & 63;
    int bin = blockIdx.x * 4 + wave;
    int bb = 0;
    for (int b = bin + 1 + lane; b < 256; b += 64) bb += totals[b];
#pragma unroll
    for (int o = 1; o < 64; o <<= 1) bb += __shfl_xor(bb, o);
    int run = bb;   // descending-degree base for this bin
    for (int k0 = 0; k0 < NBLK; k0 += 64) {
        int k = k0 + lane;
        int c = (k < NBLK) ? cnt[bin * NBLK + k] : 0;
        int p = c;
#pragma unroll
        for (int o = 1; o < 64; o <<= 1) {
            int t = __shfl_up(p, o);
            if (lane >= o) p += t;
        }
        if (k < NBLK) base[bin * NBLK + k] = run + (p - c);
        run += __shfl(p, 63);
    }
}

__global__ void deg_scatter_blk(const int* __restrict__ ptr, const int* __restrict__ base,
                                int* __restrict__ perm) {
    __shared__ int lh[256];
    int t = threadIdx.x;
    lh[t] = 0;
    __syncthreads();
    int n = blockIdx.x * 256 + t;
    if (n < Nn) {
        int dg = ptr[n + 1] - ptr[n]; if (dg > 255) dg = 255;
        int loc = atomicAdd(&lh[dg], 1);   // LDS atomic: one CU, cheap
        perm[base[dg * NBLK + blockIdx.x] + loc] = n;
    }
}

// ---------------- big-tile MFMA GEMM: 64 rows x (64*CS) cols per block -------------
// y-grid column split (deep grid hides store latency; NY-in-kernel regressed).
// NEW: LDS-staged COALESCED epilogue. Old epilogue = 48 scattered 2B stores per
// thread -> WRITE_SIZE 1.85x amplified (213MB vs 115MB, r6 counters). Now: acc ->
// LDS stage [64][CS*64+8] (bias + PAD47 mapping applied, pads zeroed), sync,
// then 16B int4 row-stores (coalesced 384B runs). Stage reuses Al (reads done).
template <int MP, int NOUT, int CS, bool ABN, bool PAD47, int OSTR>
__global__ __launch_bounds__(256, 4) void gemm_big(
    const bf16* __restrict__ A, const bf16* __restrict__ Wt,
    const bf16* __restrict__ b0, const bf16* __restrict__ b1,
    const bf16* __restrict__ b2,
    bf16* __restrict__ o0, bf16* __restrict__ o1, bf16* __restrict__ o2,
    int MR, const float* __restrict__ bnp) {
    constexpr int CS64 = CS * 64;
    constexpr int PITCH = CS64 + 8;                 // 16B-aligned row stride
    constexpr int LSZ = (64 * PITCH > 64 * 136) ? 64 * PITCH : 64 * 136;
    __shared__ __align__(16) bf16 Al[LSZ];
    const int row0 = blockIdx.x * 64;
    const int tid = threadIdx.x;
#pragma unroll
    for (int j = 0; j < 4; ++j) {
        int idx = tid + j * 256;          // 0..1023 int4 slots
        int r = idx >> 4, kk = (idx & 15) * 8;
        int4 val = {0, 0, 0, 0};
        if (row0 + r < Nn) {
            val = *(const int4*)&A[(size_t)(row0 + r) * 128 + kk];
            if (ABN) {
                short8 av = *(short8*)&val;
                bf16 tmp[8];
#pragma unroll
                for (int u = 0; u < 8; ++u) {
                    float v = b2f((unsigned short)av[u]);
                    v = fmaxf(fmaf(v, bnp[kk + u], bnp[128 + kk + u]), 0.f);
                    tmp[u] = __float2bfloat16(v);
                }
                val = *(int4*)tmp;
            }
        }
        *(int4*)&Al[r * 136 + kk] = val;
    }
    __syncthreads();
    const int wave = tid >> 6, lane = tid & 63;
    const int n16 = lane & 15, quad = lane >> 4;
    const int colbase = blockIdx.y * CS64 + wave * (16 * CS);
    f32x4 acc[4][CS];
#pragma unroll
    for (int rt = 0; rt < 4; ++rt)
#pragma unroll
        for (int c = 0; c < CS; ++c) acc[rt][c] = (f32x4){0.f, 0.f, 0.f, 0.f};
    const bf16* wb[CS];
#pragma unroll
    for (int c = 0; c < CS; ++c)
        wb[c] = Wt + (size_t)(colbase + c * 16 + n16) * 128 + quad * 8;
    const bf16* ap = Al + n16 * 136 + quad * 8;
#pragma unroll
    for (int ks = 0; ks < 4; ++ks) {
        short8 bf[CS];
#pragma unroll
        for (int c = 0; c < CS; ++c) bf[c] = *(const short8*)(wb[c] + ks * 32);
#pragma unroll
        for (int rt = 0; rt < 4; ++rt) {
            short8 af = *(const short8*)(ap + rt * 16 * 136 + ks * 32);
#pragma unroll
            for (int c = 0; c < CS; ++c)
                acc[rt][c] = __builtin_amdgcn_mfma_f32_16x16x32_bf16(af, bf[c], acc[rt][c], 0, 0, 0);
        }
    }
    // ---- stage epilogue: Al reads done, reuse as [64][PITCH] ----
    __syncthreads();
    if (PAD47) {   // zero pad slots (47,95,143,191 and lc>=MR): finite for masks
        for (int z = tid; z < 64 * PITCH; z += 256) Al[z] = __float2bfloat16(0.f);
        __syncthreads();
    }
#pragma unroll
    for (int c = 0; c < CS; ++c) {
        int pos = wave * (16 * CS) + c * 16 + n16;    // within-block col
        int col = colbase + c * 16 + n16;
        int oi = col / MP, lc = col - oi * MP;
        bool valid = (oi < NOUT) && (lc < MR);
        float bb = 0.f;
        if (valid) {
            const bf16* bp = (oi == 0) ? b0 : (oi == 1) ? b1 : b2;
            bb = tof(bp[lc]);
        }
        int stp = PAD47 ? (lc + lc / 47) : pos;
#pragma unroll
        for (int rt = 0; rt < 4; ++rt) {
#pragma unroll
            for (int i = 0; i < 4; ++i) {
                int rl = rt * 16 + quad * 4 + i;
                if (valid) Al[rl * PITCH + stp] = __float2bfloat16(acc[rt][c][i] + bb);
            }
        }
    }
    __syncthreads();
    // ---- coalesced store: 8-elem (16B) groups; PAD47 stage IS padded layout ----
    constexpr int NG = CS64 / 8;
    for (int t = tid; t < 64 * NG; t += 256) {
        int rl = t / NG, g = t % NG;
        int row = row0 + rl;
        if (row >= Nn) continue;
        int pos0 = g * 8;
        int oi, lc0;
        if (PAD47) { oi = blockIdx.y; lc0 = pos0; }   // y-block = full oi zone
        else {
            int col0 = blockIdx.y * CS64 + pos0;      // 8-group within one oi
            oi = col0 / MP; lc0 = col0 - oi * MP;
        }
        if (oi >= NOUT) continue;
        bf16* o = (oi == 0) ? o0 : (oi == 1) ? o1 : o2;
        int4 v = *(int4*)&Al[rl * PITCH + pos0];
        *(int4*)&o[(size_t)row * OSTR + lc0] = v;
    }
}

// ---------------- fused GATv2 edge kernel, M=128 (layers 0,1) ----------------
// 256 threads = 4 dsts/block (512-thread blocks regressed 83->95us - keep 256).
// Lane holds cols (2*lane, 2*lane+1). MAX-FREE softmax, log2e folded into attn.
// Packed-FP32 math; aligned uint4 srcW prefetch (1 VMEM per 4 edges).
template <bool RESBN>
__global__ __launch_bounds__(256) void gat_fused_128(
    const bf16* __restrict__ fs, const bf16* __restrict__ fd,
    const unsigned* __restrict__ srcW, const int* __restrict__ ptr,
    const int* __restrict__ perm,
    const bf16* __restrict__ attn, const bf16* __restrict__ resb,
    const float* __restrict__ bnp, bf16* __restrict__ hout) {
    const int wave = threadIdx.x >> 6, lane = threadIdx.x & 63;
    const int di = blockIdx.x * 4 + wave;
    if (di >= Nn) return;
    const int d = perm[di];
    const int c0 = lane * 2;
    const unsigned c0b = (unsigned)c0 * 2u;
    ushort2 aq = *(const ushort2*)&attn[c0];
    float a0 = b2f(aq.x) * L2E, a1 = b2f(aq.y) * L2E;
    const f32x2 Av = pk2(0.6f * a0, 0.6f * a1);
    const f32x2 Bv = pk2(0.4f * a0, 0.4f * a1);
    ushort2 dq = *(const ushort2*)&fd[(size_t)d * HD + c0];
    const f32x2 fdv = pk2(b2f(dq.x), b2f(dq.y));
    const char* fsb = (const char*)fs;
    float l = 0.f;
    f32x2 Ov = pk2(0.f, 0.f);
    int e = ptr[d];
    const int e1 = ptr[d + 1];
    // peel to 4-alignment so the main loop can use one aligned uint4 load
    for (; e < e1 && (e & 3); ++e) {
        unsigned v = srcW[e] + c0b;
        ushort2 fq = *(const ushort2*)(fsb + v);
        f32x2 f = pk2(b2f(fq.x), b2f(fq.y));
        f32x2 x = f + fdv;
        f32x2 t = pfma2(pabs2(x), Bv, x * Av);
        float p = sum16(t.x + t.y);
        float pe = __builtin_amdgcn_exp2f(p);
        l += pe;
        Ov = pfma2(pk2(pe, pe), f, Ov);
    }
    for (; e + 3 < e1; e += 4) {
        uint4 sw = *(const uint4*)&srcW[e];
        unsigned vA = sw.x + c0b, vB = sw.y + c0b;
        unsigned vC = sw.z + c0b, vD = sw.w + c0b;
        ushort2 qA = *(const ushort2*)(fsb + vA);
        ushort2 qB = *(const ushort2*)(fsb + vB);
        ushort2 qC = *(const ushort2*)(fsb + vC);
        ushort2 qD = *(const ushort2*)(fsb + vD);
        f32x2 fA = pk2(b2f(qA.x), b2f(qA.y));
        f32x2 fB = pk2(b2f(qB.x), b2f(qB.y));
        f32x2 fC = pk2(b2f(qC.x), b2f(qC.y));
        f32x2 fD = pk2(b2f(qD.x), b2f(qD.y));
        f32x2 xA = fA + fdv, xB = fB + fdv, xC = fC + fdv, xD = fD + fdv;
        f32x2 tA = pfma2(pabs2(xA), Bv, xA * Av);
        f32x2 tB = pfma2(pabs2(xB), Bv, xB * Av);
        f32x2 tC = pfma2(pabs2(xC), Bv, xC * Av);
        f32x2 tD = pfma2(pabs2(xD), Bv, xD * Av);
        float pA = tA.x + tA.y, pB = tB.x + tB.y;
        float pC = tC.x + tC.y, pD = tD.x + tD.y;
        pA = sum16(pA); pB = sum16(pB); pC = sum16(pC); pD = sum16(pD);
        float eA = __builtin_amdgcn_exp2f(pA), eB = __builtin_amdgcn_exp2f(pB);
        float eC = __builtin_amdgcn_exp2f(pC), eD = __builtin_amdgcn_exp2f(pD);
        l += (eA + eB) + (eC + eD);
        Ov = pfma2(pk2(eA, eA), fA, Ov);
        Ov = pfma2(pk2(eB, eB), fB, Ov);
        Ov = pfma2(pk2(eC, eC), fC, Ov);
        Ov = pfma2(pk2(eD, eD), fD, Ov);
    }
    for (; e < e1; ++e) {
        unsigned v = srcW[e] + c0b;
        ushort2 fq = *(const ushort2*)(fsb + v);
        f32x2 f = pk2(b2f(fq.x), b2f(fq.y));
        f32x2 x = f + fdv;
        f32x2 t = pfma2(pabs2(x), Bv, x * Av);
        float p = sum16(t.x + t.y);
        float pe = __builtin_amdgcn_exp2f(p);
        l += pe;
        Ov = pfma2(pk2(pe, pe), f, Ov);
    }
    float inv = l > 0.f ? 1.f / l : 0.f;
    ushort2 rq = *(const ushort2*)&resb[(size_t)d * HD + c0];
    float r0 = b2f(rq.x), r1 = b2f(rq.y);
    if (RESBN) {
        r0 = fmaxf(fmaf(r0, bnp[c0], bnp[HD + c0]), 0.f);
        r1 = fmaxf(fmaf(r1, bnp[c0 + 1], bnp[HD + c0 + 1]), 0.f);
    }
    float v0 = fmaxf(fmaf(Ov.x, inv, r0), 0.f);  // conv activation relu
    float v1 = fmaxf(fmaf(Ov.y, inv, r1), 0.f);
    ushort2 ov; ov.x = f2u(v0); ov.y = f2u(v1);
    *(ushort2*)&hout[(size_t)d * HD + c0] = ov;
}

// ---------------- fused GATv2 edge kernel, layer 2, PAD47 stride 192 -------------
// MEASURED-BEST variant (r2/r8: ~80us vs split-pack/pk/peel r5: 83.3us).
// Lane = 16*h + j owns cc {j, j+16, j+32} at c0=h*48+j; 3 scalar ushort gathers
// per edge; scalar fmaf chain; scalar srcW loads; NO alignment peel.
__global__ __launch_bounds__(256) void gat_fused_188(
    const bf16* __restrict__ fs, const bf16* __restrict__ fd,
    const unsigned* __restrict__ srcW, const int* __restrict__ ptr,
    const int* __restrict__ perm,
    const bf16* __restrict__ attn, const bf16* __restrict__ rs,
    void* __restrict__ out, const int* __restrict__ flag) {
    const int wave = threadIdx.x >> 6, lane = threadIdx.x & 63;
    const int di = blockIdx.x * 4 + wave;
    if (di >= Nn) return;
    const int d = perm[di];
    const int h = lane >> 4, j = lane & 15;
    const int c0 = h * 48 + j;        // padded layout
    const unsigned c0b = (unsigned)c0 * 2u;
    const int ca = h * Cc + j;        // attn is unpadded [188]
    const bool has2 = (j < 15);
    float a0 = ldb(&attn[ca]) * L2E;
    float a1 = ldb(&attn[ca + 16]) * L2E;
    float a2 = has2 ? ldb(&attn[ca + 32]) * L2E : 0.f;
    float A0 = 0.6f * a0, B0 = 0.4f * a0;
    float A1 = 0.6f * a1, B1 = 0.4f * a1;
    float A2 = 0.6f * a2, B2 = 0.4f * a2;
    const bf16* fdr = fd + (size_t)d * HCP;
    float fd0 = ldb(&fdr[c0]);
    float fd1 = ldb(&fdr[c0 + 16]);
    float fd2 = ldb(&fdr[c0 + 32]);   // pad = 0 (gemm zero-fills): A2=B2=0 masks
    const char* fsb = (const char*)fs;
    float l = 0.f, O0 = 0.f, O1 = 0.f, O2 = 0.f;
    int e = ptr[d];
    const int e1 = ptr[d + 1];
    for (; e + 3 < e1; e += 4) {
        unsigned vA = srcW[e] + c0b, vB = srcW[e + 1] + c0b;
        unsigned vC = srcW[e + 2] + c0b, vD = srcW[e + 3] + c0b;
        float fA0 = b2f(*(const unsigned short*)(fsb + vA));
        float fA1 = b2f(*(const unsigned short*)(fsb + vA + 32));
        float fA2 = b2f(*(const unsigned short*)(fsb + vA + 64));
        float fB0 = b2f(*(const unsigned short*)(fsb + vB));
        float fB1 = b2f(*(const unsigned short*)(fsb + vB + 32));
        float fB2 = b2f(*(const unsigned short*)(fsb + vB + 64));
        float fC0 = b2f(*(const unsigned short*)(fsb + vC));
        float fC1 = b2f(*(const unsigned short*)(fsb + vC + 32));
        float fC2 = b2f(*(const unsigned short*)(fsb + vC + 64));
        float fD0 = b2f(*(const unsigned short*)(fsb + vD));
        float fD1 = b2f(*(const unsigned short*)(fsb + vD + 32));
        float fD2 = b2f(*(const unsigned short*)(fsb + vD + 64));
        float xA0 = fA0 + fd0, xA1 = fA1 + fd1, xA2 = fA2 + fd2;
        float xB0 = fB0 + fd0, xB1 = fB1 + fd1, xB2 = fB2 + fd2;
        float xC0 = fC0 + fd0, xC1 = fC1 + fd1, xC2 = fC2 + fd2;
        float xD0 = fD0 + fd0, xD1 = fD1 + fd1, xD2 = fD2 + fd2;
        float pA = fmaf(xA0, A0, fmaf(fabsf(xA0), B0, fmaf(xA1, A1, fmaf(fabsf(xA1), B1,
                   fmaf(xA2, A2, fabsf(xA2) * B2)))));
        float pB = fmaf(xB0, A0, fmaf(fabsf(xB0), B0, fmaf(xB1, A1, fmaf(fabsf(xB1), B1,
                   fmaf(xB2, A2, fabsf(xB2) * B2)))));
        float pC = fmaf(xC0, A0, fmaf(fabsf(xC0), B0, fmaf(xC1, A1, fmaf(fabsf(xC1), B1,
                   fmaf(xC2, A2, fabsf(xC2) * B2)))));
        float pD = fmaf(xD0, A0, fmaf(fabsf(xD0), B0, fmaf(xD1, A1, fmaf(fabsf(xD1), B1,
                   fmaf(xD2, A2, fabsf(xD2) * B2)))));
        pA = sum16(pA); pB = sum16(pB); pC = sum16(pC); pD = sum16(pD);
        float eA = __builtin_amdgcn_exp2f(pA), eB = __builtin_amdgcn_exp2f(pB);
        float eC = __builtin_amdgcn_exp2f(pC), eD = __builtin_amdgcn_exp2f(pD);
        l += (eA + eB) + (eC + eD);
        O0 = fmaf(eA, fA0, O0); O0 = fmaf(eB, fB0, O0);
        O0 = fmaf(eC, fC0, O0); O0 = fmaf(eD, fD0, O0);
        O1 = fmaf(eA, fA1, O1); O1 = fmaf(eB, fB1, O1);
        O1 = fmaf(eC, fC1, O1); O1 = fmaf(eD, fD1, O1);
        O2 = fmaf(eA, fA2, O2); O2 = fmaf(eB, fB2, O2);
        O2 = fmaf(eC, fC2, O2); O2 = fmaf(eD, fD2, O2);
    }
    for (; e < e1; ++e) {
        unsigned v = srcW[e] + c0b;
        float f0 = b2f(*(const unsigned short*)(fsb + v));
        float f1 = b2f(*(const unsigned short*)(fsb + v + 32));
        float f2 = b2f(*(const unsigned short*)(fsb + v + 64));
        float x0 = f0 + fd0, x1 = f1 + fd1, x2 = f2 + fd2;
        float p = fmaf(x0, A0, fmaf(fabsf(x0), B0, fmaf(x1, A1, fmaf(fabsf(x1), B1,
                  fmaf(x2, A2, fabsf(x2) * B2)))));
        p = sum16(p);
        float pe = __builtin_amdgcn_exp2f(p);
        l += pe;
        O0 = fmaf(pe, f0, O0);
        O1 = fmaf(pe, f1, O1);
        O2 = fmaf(pe, f2, O2);
    }
    // epilogue: +res, head-mean across lane groups, log_softmax, store
    float inv = l > 0.f ? 1.f / l : 0.f;
    const bf16* rr = rs + (size_t)d * HCP;
    float v0 = fmaf(O0, inv, ldb(&rr[c0]));
    float v1 = fmaf(O1, inv, ldb(&rr[c0 + 16]));
    float v2 = has2 ? fmaf(O2, inv, ldb(&rr[c0 + 32])) : 0.f;
    v0 += __shfl_xor(v0, 16); v0 += __shfl_xor(v0, 32); v0 *= 0.25f;
    v1 += __shfl_xor(v1, 16); v1 += __shfl_xor(v1, 32); v1 *= 0.25f;
    v2 += __shfl_xor(v2, 16); v2 += __shfl_xor(v2, 32); v2 *= 0.25f;
    float mx = fmaxf(v0, v1);
    if (has2) mx = fmaxf(mx, v2);
    mx = max16(mx);
    float sm = __expf(v0 - mx) + __expf(v1 - mx) + (has2 ? __expf(v2 - mx) : 0.f);
    sm = sum16(sm);
    if (h == 0) {
        float ls = mx + __log2f(sm) * LN2;
        if (*flag) {
            bf16* o = (bf16*)out + (size_t)d * Cc;
            o[j] = __float2bfloat16(v0 - ls);
            o[j + 16] = __float2bfloat16(v1 - ls);
            if (has2) o[j + 32] = __float2bfloat16(v2 - ls);
        } else {
            float* o = (float*)out + (size_t)d * Cc;
            o[j] = v0 - ls;
            o[j + 16] = v1 - ls;
            if (has2) o[j + 32] = v2 - ls;
        }
    }
}

// ---------------- per-column BN stats over bf16 h (atomic combine) ----------------
// 391 blocks x 128 threads; ONE atomicAdd per thread per stat (block-reduced
// first). ~100K total atomics over 256 addrs = a few us. (A single-block
// serial finalize regressed to 92us - do NOT revisit that design.)
__global__ void col_stats(const bf16* __restrict__ in, float* __restrict__ sums) {
    int c = threadIdx.x;  // 128
    int r0 = blockIdx.x * 256;
    int r1 = r0 + 256; if (r1 > Nn) r1 = Nn;
    float s = 0.f, s2 = 0.f;
    for (int r = r0; r < r1; ++r) {
        float v = ldb(&in[(size_t)r * HD + c]);
        s += v; s2 += v * v;
    }
    atomicAdd(&sums[c], s);
    atomicAdd(&sums[HD + c], s2);
}

__global__ void bn_finalize(const float* __restrict__ sums, const bf16* __restrict__ g,
                            const bf16* __restrict__ be, float* __restrict__ ss) {
    int c = threadIdx.x;  // 128
    float mu = sums[c] * (1.f / Nn);
    float var = sums[HD + c] * (1.f / Nn) - mu * mu;
    float sc = tof(g[c]) * rsqrtf(var + EPSV);
    ss[c] = sc;
    ss[HD + c] = tof(be[c]) - mu * sc;
}

extern "C" void kernel_launch(void* const* d_in, const int* in_sizes, int n_in,
                              void* d_out, int out_size, void* d_ws, size_t ws_size,
                              hipStream_t stream) {
    (void)in_sizes; (void)n_in; (void)out_size; (void)ws_size;
    const void* x = d_in[0];
    const int* src = (const int*)d_in[1];
    const int* dst = (const int*)d_in[2];

    char* ws = (char*)d_ws;
    size_t off = 0;
    auto alloc = [&](size_t bytes) {
        void* p = ws + off;
        off += (bytes + 255) & ~(size_t)255;
        return p;
    };
    // rs (38.4 MB, [Nn][192]) aliases xb+rb (51.2 MB): both dead before L2 GEMM.
    bf16* xb = (bf16*)alloc((size_t)Nn * 128 * 2);    // 25.6 MB (stride-128 padded x)
    bf16* rb = (bf16*)alloc((size_t)Nn * HD * 2);     // 25.6 MB
    bf16* rs = xb;                                    // [Nn][HCP] alias
    bf16* fs = (bf16*)alloc((size_t)Nn * HCP * 2);    // 38.4 MB
    bf16* fd = (bf16*)alloc((size_t)Nn * HCP * 2);    // 38.4 MB
    bf16* hbA = (bf16*)alloc((size_t)Nn * HD * 2);    // 25.6 MB
    bf16* hbB = (bf16*)alloc((size_t)Nn * HD * 2);    // 25.6 MB
    int* ptr = (int*)alloc((Nn + 1) * 4);             // 400 KB
    bf16* wtb = (bf16*)alloc((size_t)WROWS * 128 * 2);// 328 KB
    float* bns0 = (float*)alloc(2 * HD * 4);
    float* bns1 = (float*)alloc(2 * HD * 4);
    float* bnss0 = (float*)alloc(2 * HD * 4);
    float* bnss1 = (float*)alloc(2 * HD * 4);
    bf16* pb = (bf16*)alloc(4096 * 2);
    int* flag = (int*)alloc(256);
    unsigned* w384 = (unsigned*)alloc((size_t)Ee * 4);// 4 MB
    unsigned* w256 = (unsigned*)alloc((size_t)Ee * 4);// 4 MB
    int* cnt = (int*)alloc((size_t)256 * NBLK * 4);   // 400 KB
    int* cbase = (int*)alloc((size_t)256 * NBLK * 4); // 400 KB
    int* totals = (int*)alloc(256 * 4);
    int* perm = (int*)alloc((size_t)Nn * 4);          // 400 KB

    // ---- small-param conversion (biases/attn/bn): d_in idx -> pb arena ----
    static const int spIdx[NSP] = {4, 6, 7, 9, 11, 13, 14, 16, 18, 19, 21, 22, 23, 24, 25};
    static const int spSz[NSP]  = {HD, HD, HD, HD, HD, HD, HD, HC, HC, HC, HC, HD, HD, HD, HD};
    CvtTab tab;
    int tot = 0;
    for (int i = 0; i < NSP; ++i) { tab.src[i] = d_in[spIdx[i]]; tab.off[i] = tot; tot += spSz[i]; }
    tab.off[NSP] = tot;
    const bf16 *bsrc0 = pb + tab.off[0], *bdst0 = pb + tab.off[1], *attn0 = pb + tab.off[2],
               *bres0 = pb + tab.off[3], *bsrc1 = pb + tab.off[4], *bdst1 = pb + tab.off[5],
               *attn1 = pb + tab.off[6], *bsrc2 = pb + tab.off[7], *bdst2 = pb + tab.off[8],
               *attn2 = pb + tab.off[9], *bres2 = pb + tab.off[10],
               *g0 = pb + tab.off[11], *be0 = pb + tab.off[12],
               *g1 = pb + tab.off[13], *be1 = pb + tab.off[14];

    // ---- packed Wt: rows [0,384)=L0, [384,640)=L1, [640,1216)=L2 @MP=192, pad->1280 ----
    PrepTab pt;
    static const int wIdx[8] = {3, 5, 8, 10, 12, 15, 17, 20};
    static const int wK[8]   = {INF_, INF_, INF_, HD, HD, HD, HD, HD};
    static const int wM[8]   = {HD, HD, HD, HD, HD, HC, HC, HC};
    static const int wMP[8]  = {128, 128, 128, 128, 128, 192, 192, 192};
    static const int wR0[8]  = {0, 128, 256, 384, 512, 640, 832, 1024};
    for (int i = 0; i < 8; ++i) {
        pt.src[i] = d_in[wIdx[i]]; pt.row0[i] = wR0[i];
        pt.K[i] = wK[i]; pt.M[i] = wM[i]; pt.MP[i] = wMP[i];
    }

    detect_dtype<<<1, 64, 0, stream>>>((const unsigned*)x, flag);
    cvt_x<<<(Nn * 128 + 255) / 256, 256, 0, stream>>>(x, xb, flag);
    prep_all<<<(WROWS * 128 + 255) / 256, 256, 0, stream>>>(pt, tab, wtb, pb, tot, flag);
    src_scale_ptr<<<(Ee + 255) / 256, 256, 0, stream>>>(src, dst, w384, w256, ptr,
                                                        bns0, bns1);
    deg_hist_blk<<<NBLK, 256, 0, stream>>>(ptr, cnt);
    deg_totals<<<64, 256, 0, stream>>>(cnt, totals);
    deg_bases<<<64, 256, 0, stream>>>(cnt, totals, cbase);
    deg_scatter_blk<<<NBLK, 256, 0, stream>>>(ptr, cbase, perm);

    const int fusedGrid = (Nn + 3) / 4;   // 256-thread blocks, 4 dsts each
    const int statsGrid = NBLK;
    const int rowBlk = (Nn + 63) / 64;  // 1563

    // ---------------- layer 0 (384 cols: y=2 x CS=3) ----------------
    gemm_big<128, 3, 3, false, false, HD><<<dim3(rowBlk, 2), 256, 0, stream>>>(
        xb, wtb, bsrc0, bdst0, bres0, fs, fd, rb, HD, nullptr);
    gat_fused_128<false><<<fusedGrid, 256, 0, stream>>>(fs, fd, w256, ptr, perm,
                                                        attn0, rb, nullptr, hbA);
    col_stats<<<statsGrid, 128, 0, stream>>>(hbA, bns0);
    bn_finalize<<<1, HD, 0, stream>>>(bns0, g0, be0, bnss0);

    // ---------------- layer 1 (256 cols: y=2 x CS=2) ----------------
    gemm_big<128, 2, 2, true, false, HD><<<dim3(rowBlk, 2), 256, 0, stream>>>(
        hbA, wtb + (size_t)384 * 128, bsrc1, bdst1, nullptr, fs, fd, nullptr, HD, bnss0);
    gat_fused_128<true><<<fusedGrid, 256, 0, stream>>>(fs, fd, w256, ptr, perm,
                                                       attn1, hbA, bnss0, hbB);
    col_stats<<<statsGrid, 128, 0, stream>>>(hbB, bns1);
    bn_finalize<<<1, HD, 0, stream>>>(bns1, g1, be1, bnss1);

    // ---------------- layer 2 (576 cols: y=3 x CS=3, pad47 outputs; each y-block
    // covers exactly one of fs/fd/rs full-row -> coalesced padded-row stores) -----
    gemm_big<192, 3, 3, true, true, HCP><<<dim3(rowBlk, 3), 256, 0, stream>>>(
        hbB, wtb + (size_t)640 * 128, bsrc2, bdst2, bres2, fs, fd, rs, HC, bnss1);
    gat_fused_188<<<fusedGrid, 256, 0, stream>>>(fs, fd, w384, ptr, perm, attn2, rs,
                                                 d_out, flag);
}

// Round 10
// 648.713 us; speedup vs baseline: 1.0865x; 1.0232x over previous
//
#include <hip/hip_runtime.h>
#include <hip/hip_bf16.h>

#define Nn 100000
#define Ee 1000000
#define INF_ 100
#define Hh 4
#define Dd 32
#define HD 128
#define Cc 47
#define HC 188
#define HCP 192
#define EPSV 1e-5f
#define SLOPE 0.2f
#define NBLK ((Nn + 255) / 256)

typedef __hip_bfloat16 bf16;
typedef __attribute__((ext_vector_type(8))) short short8;
typedef __attribute__((ext_vector_type(4))) float f32x4;
typedef __attribute__((ext_vector_type(2))) float f32x2;

__device__ __forceinline__ float tof(bf16 v) { return __bfloat162float(v); }
__device__ __forceinline__ float b2f(unsigned short u) {
    return __uint_as_float((unsigned)u << 16);
}
__device__ __forceinline__ float ldb(const bf16* p) {
    return b2f(*(const unsigned short*)p);
}
__device__ __forceinline__ unsigned short f2u(float v) {
    bf16 t = __float2bfloat16(v);
    return *(unsigned short*)&t;
}
__device__ __forceinline__ f32x2 pk2(float x, float y) {
    f32x2 r; r.x = x; r.y = y; return r;
}
__device__ __forceinline__ f32x2 pabs2(f32x2 v) {          // v_pk_max_f32 v, -v
    return __builtin_elementwise_max(v, -v);
}
__device__ __forceinline__ f32x2 pfma2(f32x2 a, f32x2 b, f32x2 c) {
    return __builtin_elementwise_fma(a, b, c);             // v_pk_fma_f32
}

// DPP-fused 16-lane reduces (quad_perm swaps + row rotates; row=16 lanes).
template <int C>
__device__ __forceinline__ float dppadd(float v) {
    int m = __builtin_amdgcn_update_dpp(0, __float_as_int(v), C, 0xF, 0xF, false);
    return v + __int_as_float(m);
}
template <int C>
__device__ __forceinline__ float dppmax(float v) {
    int m = __builtin_amdgcn_update_dpp(0, __float_as_int(v), C, 0xF, 0xF, false);
    return fmaxf(v, __int_as_float(m));
}
__device__ __forceinline__ float sum16(float p) {
    p = dppadd<0xB1>(p);   // quad_perm [1,0,3,2]
    p = dppadd<0x4E>(p);   // quad_perm [2,3,0,1]
    p = dppadd<0x124>(p);  // row_ror:4
    p = dppadd<0x128>(p);  // row_ror:8
    return p;
}
__device__ __forceinline__ float max16(float p) {
    p = dppmax<0xB1>(p); p = dppmax<0x4E>(p);
    p = dppmax<0x124>(p); p = dppmax<0x128>(p);
    return p;
}

#define L2E 1.4426950408889634f
#define LN2 0.6931471805599453f

__device__ __forceinline__ float ld_any(const void* p, int i, int isbf) {
    return isbf ? tof(((const bf16*)p)[i]) : ((const float*)p)[i];
}

__device__ __forceinline__ int lbound(const int* __restrict__ dst, int n) {
    int lo = 0, hi = Ee;
    while (lo < hi) {
        int mid = (lo + hi) >> 1;
        if (dst[mid] < n) lo = mid + 1; else hi = mid;
    }
    return lo;
}

// ---------------- MEGA prepare kernel (replaces 5 launches) ----------------
// Each block independently derives the dtype flag (ballot over x[0..255] words,
// L2-hot, deterministic) -> no cross-kernel flag dependency. Jobs partitioned
// by global index: cvt_x | weight pack | small params | src byte-offsets |
// bns zeroing | CSR ptr + BLOCK-LOCAL degree histogram (lower_bounds shared
// through LDS so hist needs no globally-complete ptr).
#define WROWS 1280
#define NSP 15
struct PrepTab { const void* src[8]; int row0[8]; int K[8]; int M[8]; int MP[8]; };
struct CvtTab { const void* src[NSP]; int off[NSP + 1]; };

__global__ __launch_bounds__(256) void prepare(
    const void* __restrict__ x, const int* __restrict__ src,
    const int* __restrict__ dst,
    PrepTab pt, CvtTab ct, int tot,
    bf16* __restrict__ xb, bf16* __restrict__ wtb, bf16* __restrict__ pb,
    unsigned* __restrict__ w384, unsigned* __restrict__ w256,
    int* __restrict__ ptr, int* __restrict__ cnt,
    float* __restrict__ z0, float* __restrict__ z1, int* __restrict__ flag) {
    __shared__ int wc[4];
    __shared__ int lbv[257];
    __shared__ int lh[256];
    const int t = threadIdx.x;
    // ---- per-block dtype detect ----
    unsigned w = ((const unsigned*)x)[t];
    float dv = __uint_as_float((w & 0xFFFFu) << 16);
    float da = fabsf(dv);
    unsigned long long m = __ballot(da > 1e-4f && da < 10.f);
    if ((t & 63) == 0) wc[t >> 6] = __popcll(m);
    __syncthreads();
    const int isbf = (wc[0] + wc[1] + wc[2] + wc[3]) >= 128;
    if (blockIdx.x == 0 && t == 0) *flag = isbf;

    const int gi = blockIdx.x * 256 + t;
    // ---- cvt_x: [Nn][100] -> bf16 [Nn][128] ----
    if (gi < Nn * 128) {
        int row = gi >> 7, col = gi & 127;
        float v = (col < INF_) ? ld_any(x, row * INF_ + col, isbf) : 0.f;
        xb[gi] = __float2bfloat16(v);
    }
    // ---- weights -> packed transposed Wt[1280][128] ----
    if (gi < WROWS * 128) {
        int row = gi >> 7, k = gi & 127;
        float v = 0.f;
#pragma unroll
        for (int q = 0; q < 8; ++q) {
            if (row >= pt.row0[q] && row < pt.row0[q] + pt.MP[q]) {
                int mm = row - pt.row0[q];
                if (mm < pt.M[q] && k < pt.K[q])
                    v = ld_any(pt.src[q], k * pt.M[q] + mm, isbf);
            }
        }
        wtb[gi] = __float2bfloat16(v);
    }
    // ---- small params ----
    if (gi < tot) {
        int seg = 0;
        while (gi >= ct.off[seg + 1]) seg++;
        pb[gi] = __float2bfloat16(ld_any(ct.src[seg], gi - ct.off[seg], isbf));
    }
    // ---- pre-scaled src byte offsets ----
    if (gi < Ee) {
        unsigned s = (unsigned)src[gi];
        w384[gi] = s * 384u;  // stride HCP*2 bytes (layer-2 pad47 fs)
        w256[gi] = s << 8;    // stride HD*2 bytes  (layer-0/1 fs)
    }
    // ---- BN accumulator zeroing ----
    if (gi < 2 * HD) { z0[gi] = 0.f; z1[gi] = 0.f; }
    // ---- CSR ptr + block-local degree histogram ----
    if (blockIdx.x < NBLK) {
        int nn = gi;
        int lb = Ee;
        if (nn <= Nn) { lb = lbound(dst, nn); ptr[nn] = lb; }
        lbv[t] = lb;
        if (t == 255) lbv[256] = (nn + 1 <= Nn) ? lbound(dst, nn + 1) : Ee;
        lh[t] = 0;
        __syncthreads();
        if (nn < Nn) {
            int dg = lbv[t + 1] - lbv[t]; if (dg > 255) dg = 255;
            atomicAdd(&lh[dg], 1);
        }
        __syncthreads();
        cnt[t * NBLK + blockIdx.x] = lh[t];
    }
}

// ---------------- degree-descending LPT permutation (continued) -------------------
// one wave per bin (64 blocks x 4 waves): lane-strided coalesced total
__global__ void deg_totals(const int* __restrict__ cnt, int* __restrict__ totals) {
    int wave = threadIdx.x >> 6, lane = threadIdx.x & 63;
    int bin = blockIdx.x * 4 + wave;
    int s = 0;
    for (int k = lane; k < NBLK; k += 64) s += cnt[bin * NBLK + k];
#pragma unroll
    for (int o = 1; o < 64; o <<= 1) s += __shfl_xor(s, o);
    if (lane == 0) totals[bin] = s;
}

// one wave per bin: binbase = sum of totals over HIGHER-degree bins, then
// chunked 64-lane exclusive prefix over the NBLK per-block counts.
__global__ void deg_bases(const int* __restrict__ cnt, const int* __restrict__ totals,
                          int* __restrict__ base) {
    int wave = threadIdx.x >> 6, lane = threadIdx.x & 63;
    int bin = blockIdx.x * 4 + wave;
    int bb = 0;
    for (int b = bin + 1 + lane; b < 256; b += 64) bb += totals[b];
#pragma unroll
    for (int o = 1; o < 64; o <<= 1) bb += __shfl_xor(bb, o);
    int run = bb;   // descending-degree base for this bin
    for (int k0 = 0; k0 < NBLK; k0 += 64) {
        int k = k0 + lane;
        int c = (k < NBLK) ? cnt[bin * NBLK + k] : 0;
        int p = c;
#pragma unroll
        for (int o = 1; o < 64; o <<= 1) {
            int t = __shfl_up(p, o);
            if (lane >= o) p += t;
        }
        if (k < NBLK) base[bin * NBLK + k] = run + (p - c);
        run += __shfl(p, 63);
    }
}

__global__ void deg_scatter_blk(const int* __restrict__ ptr, const int* __restrict__ base,
                                int* __restrict__ perm) {
    __shared__ int lh[256];
    int t = threadIdx.x;
    lh[t] = 0;
    __syncthreads();
    int n = blockIdx.x * 256 + t;
    if (n < Nn) {
        int dg = ptr[n + 1] - ptr[n]; if (dg > 255) dg = 255;
        int loc = atomicAdd(&lh[dg], 1);   // LDS atomic: one CU, cheap
        perm[base[dg * NBLK + blockIdx.x] + loc] = n;
    }
}

// ---------------- big-tile MFMA GEMM: 64 rows x (64*CS) cols per block -------------
// y-grid column split (deep grid hides store latency; NY-in-kernel regressed).
// LDS-staged COALESCED epilogue (48 scattered 2B stores -> 16B row stores;
// killed the 1.85x WRITE amplification seen in r6). ABN: BN scale/offset
// computed ON THE FLY from raw sums+gamma+beta into a small LDS table
// (replaces the bn_finalize launch entirely; identical f32 math).
template <int MP, int NOUT, int CS, bool ABN, bool PAD47, int OSTR>
__global__ __launch_bounds__(256, 4) void gemm_big(
    const bf16* __restrict__ A, const bf16* __restrict__ Wt,
    const bf16* __restrict__ b0, const bf16* __restrict__ b1,
    const bf16* __restrict__ b2,
    bf16* __restrict__ o0, bf16* __restrict__ o1, bf16* __restrict__ o2,
    int MR, const float* __restrict__ sums,
    const bf16* __restrict__ gg, const bf16* __restrict__ bbn) {
    constexpr int CS64 = CS * 64;
    constexpr int PITCH = CS64 + 8;                 // 16B-aligned row stride
    constexpr int LSZ = (64 * PITCH > 64 * 136) ? 64 * PITCH : 64 * 136;
    __shared__ __align__(16) bf16 Al[LSZ];
    __shared__ float scb[ABN ? HD : 1], ofb[ABN ? HD : 1];
    const int row0 = blockIdx.x * 64;
    const int tid = threadIdx.x;
    if (ABN) {
        if (tid < HD) {
            float mu = sums[tid] * (1.f / Nn);
            float var = sums[HD + tid] * (1.f / Nn) - mu * mu;
            float sc = tof(gg[tid]) * rsqrtf(var + EPSV);
            scb[tid] = sc;
            ofb[tid] = tof(bbn[tid]) - mu * sc;
        }
        __syncthreads();
    }
#pragma unroll
    for (int j = 0; j < 4; ++j) {
        int idx = tid + j * 256;          // 0..1023 int4 slots
        int r = idx >> 4, kk = (idx & 15) * 8;
        int4 val = {0, 0, 0, 0};
        if (row0 + r < Nn) {
            val = *(const int4*)&A[(size_t)(row0 + r) * 128 + kk];
            if (ABN) {
                short8 av = *(short8*)&val;
                bf16 tmp[8];
#pragma unroll
                for (int u = 0; u < 8; ++u) {
                    float v = b2f((unsigned short)av[u]);
                    v = fmaxf(fmaf(v, scb[kk + u], ofb[kk + u]), 0.f);
                    tmp[u] = __float2bfloat16(v);
                }
                val = *(int4*)tmp;
            }
        }
        *(int4*)&Al[r * 136 + kk] = val;
    }
    __syncthreads();
    const int wave = tid >> 6, lane = tid & 63;
    const int n16 = lane & 15, quad = lane >> 4;
    const int colbase = blockIdx.y * CS64 + wave * (16 * CS);
    f32x4 acc[4][CS];
#pragma unroll
    for (int rt = 0; rt < 4; ++rt)
#pragma unroll
        for (int c = 0; c < CS; ++c) acc[rt][c] = (f32x4){0.f, 0.f, 0.f, 0.f};
    const bf16* wb[CS];
#pragma unroll
    for (int c = 0; c < CS; ++c)
        wb[c] = Wt + (size_t)(colbase + c * 16 + n16) * 128 + quad * 8;
    const bf16* ap = Al + n16 * 136 + quad * 8;
#pragma unroll
    for (int ks = 0; ks < 4; ++ks) {
        short8 bf[CS];
#pragma unroll
        for (int c = 0; c < CS; ++c) bf[c] = *(const short8*)(wb[c] + ks * 32);
#pragma unroll
        for (int rt = 0; rt < 4; ++rt) {
            short8 af = *(const short8*)(ap + rt * 16 * 136 + ks * 32);
#pragma unroll
            for (int c = 0; c < CS; ++c)
                acc[rt][c] = __builtin_amdgcn_mfma_f32_16x16x32_bf16(af, bf[c], acc[rt][c], 0, 0, 0);
        }
    }
    // ---- stage epilogue: Al reads done, reuse as [64][PITCH] ----
    __syncthreads();
    if (PAD47) {   // zero pad slots (47,95,143,191 and lc>=MR): finite for masks
        for (int z = tid; z < 64 * PITCH; z += 256) Al[z] = __float2bfloat16(0.f);
        __syncthreads();
    }
#pragma unroll
    for (int c = 0; c < CS; ++c) {
        int pos = wave * (16 * CS) + c * 16 + n16;    // within-block col
        int col = colbase + c * 16 + n16;
        int oi = col / MP, lc = col - oi * MP;
        bool valid = (oi < NOUT) && (lc < MR);
        float bb = 0.f;
        if (valid) {
            const bf16* bp = (oi == 0) ? b0 : (oi == 1) ? b1 : b2;
            bb = tof(bp[lc]);
        }
        int stp = PAD47 ? (lc + lc / 47) : pos;
#pragma unroll
        for (int rt = 0; rt < 4; ++rt) {
#pragma unroll
            for (int i = 0; i < 4; ++i) {
                int rl = rt * 16 + quad * 4 + i;
                if (valid) Al[rl * PITCH + stp] = __float2bfloat16(acc[rt][c][i] + bb);
            }
        }
    }
    __syncthreads();
    // ---- coalesced store: 8-elem (16B) groups; PAD47 stage IS padded layout ----
    constexpr int NG = CS64 / 8;
    for (int t = tid; t < 64 * NG; t += 256) {
        int rl = t / NG, g = t % NG;
        int row = row0 + rl;
        if (row >= Nn) continue;
        int pos0 = g * 8;
        int oi, lc0;
        if (PAD47) { oi = blockIdx.y; lc0 = pos0; }   // y-block = full oi zone
        else {
            int col0 = blockIdx.y * CS64 + pos0;      // 8-group within one oi
            oi = col0 / MP; lc0 = col0 - oi * MP;
        }
        if (oi >= NOUT) continue;
        bf16* o = (oi == 0) ? o0 : (oi == 1) ? o1 : o2;
        int4 v = *(int4*)&Al[rl * PITCH + pos0];
        *(int4*)&o[(size_t)row * OSTR + lc0] = v;
    }
}

// ---------------- fused GATv2 edge kernel, M=128 (layers 0,1) ----------------
// 256 threads = 4 dsts/block (512-thread blocks regressed 83->95us - keep 256).
// Lane holds cols (2*lane, 2*lane+1). MAX-FREE softmax, log2e folded into attn.
// Packed-FP32 math; aligned uint4 srcW prefetch. RESBN: BN scale/offset derived
// from raw sums+gamma+beta in the epilogue (bn_finalize launch eliminated).
template <bool RESBN>
__global__ __launch_bounds__(256) void gat_fused_128(
    const bf16* __restrict__ fs, const bf16* __restrict__ fd,
    const unsigned* __restrict__ srcW, const int* __restrict__ ptr,
    const int* __restrict__ perm,
    const bf16* __restrict__ attn, const bf16* __restrict__ resb,
    const float* __restrict__ sums, const bf16* __restrict__ gv,
    const bf16* __restrict__ bev, bf16* __restrict__ hout) {
    const int wave = threadIdx.x >> 6, lane = threadIdx.x & 63;
    const int di = blockIdx.x * 4 + wave;
    if (di >= Nn) return;
    const int d = perm[di];
    const int c0 = lane * 2;
    const unsigned c0b = (unsigned)c0 * 2u;
    ushort2 aq = *(const ushort2*)&attn[c0];
    float a0 = b2f(aq.x) * L2E, a1 = b2f(aq.y) * L2E;
    const f32x2 Av = pk2(0.6f * a0, 0.6f * a1);
    const f32x2 Bv = pk2(0.4f * a0, 0.4f * a1);
    ushort2 dq = *(const ushort2*)&fd[(size_t)d * HD + c0];
    const f32x2 fdv = pk2(b2f(dq.x), b2f(dq.y));
    const char* fsb = (const char*)fs;
    float l = 0.f;
    f32x2 Ov = pk2(0.f, 0.f);
    int e = ptr[d];
    const int e1 = ptr[d + 1];
    // peel to 4-alignment so the main loop can use one aligned uint4 load
    for (; e < e1 && (e & 3); ++e) {
        unsigned v = srcW[e] + c0b;
        ushort2 fq = *(const ushort2*)(fsb + v);
        f32x2 f = pk2(b2f(fq.x), b2f(fq.y));
        f32x2 x = f + fdv;
        f32x2 t = pfma2(pabs2(x), Bv, x * Av);
        float p = sum16(t.x + t.y);
        float pe = __builtin_amdgcn_exp2f(p);
        l += pe;
        Ov = pfma2(pk2(pe, pe), f, Ov);
    }
    for (; e + 3 < e1; e += 4) {
        uint4 sw = *(const uint4*)&srcW[e];
        unsigned vA = sw.x + c0b, vB = sw.y + c0b;
        unsigned vC = sw.z + c0b, vD = sw.w + c0b;
        ushort2 qA = *(const ushort2*)(fsb + vA);
        ushort2 qB = *(const ushort2*)(fsb + vB);
        ushort2 qC = *(const ushort2*)(fsb + vC);
        ushort2 qD = *(const ushort2*)(fsb + vD);
        f32x2 fA = pk2(b2f(qA.x), b2f(qA.y));
        f32x2 fB = pk2(b2f(qB.x), b2f(qB.y));
        f32x2 fC = pk2(b2f(qC.x), b2f(qC.y));
        f32x2 fD = pk2(b2f(qD.x), b2f(qD.y));
        f32x2 xA = fA + fdv, xB = fB + fdv, xC = fC + fdv, xD = fD + fdv;
        f32x2 tA = pfma2(pabs2(xA), Bv, xA * Av);
        f32x2 tB = pfma2(pabs2(xB), Bv, xB * Av);
        f32x2 tC = pfma2(pabs2(xC), Bv, xC * Av);
        f32x2 tD = pfma2(pabs2(xD), Bv, xD * Av);
        float pA = tA.x + tA.y, pB = tB.x + tB.y;
        float pC = tC.x + tC.y, pD = tD.x + tD.y;
        pA = sum16(pA); pB = sum16(pB); pC = sum16(pC); pD = sum16(pD);
        float eA = __builtin_amdgcn_exp2f(pA), eB = __builtin_amdgcn_exp2f(pB);
        float eC = __builtin_amdgcn_exp2f(pC), eD = __builtin_amdgcn_exp2f(pD);
        l += (eA + eB) + (eC + eD);
        Ov = pfma2(pk2(eA, eA), fA, Ov);
        Ov = pfma2(pk2(eB, eB), fB, Ov);
        Ov = pfma2(pk2(eC, eC), fC, Ov);
        Ov = pfma2(pk2(eD, eD), fD, Ov);
    }
    for (; e < e1; ++e) {
        unsigned v = srcW[e] + c0b;
        ushort2 fq = *(const ushort2*)(fsb + v);
        f32x2 f = pk2(b2f(fq.x), b2f(fq.y));
        f32x2 x = f + fdv;
        f32x2 t = pfma2(pabs2(x), Bv, x * Av);
        float p = sum16(t.x + t.y);
        float pe = __builtin_amdgcn_exp2f(p);
        l += pe;
        Ov = pfma2(pk2(pe, pe), f, Ov);
    }
    float inv = l > 0.f ? 1.f / l : 0.f;
    ushort2 rq = *(const ushort2*)&resb[(size_t)d * HD + c0];
    float r0 = b2f(rq.x), r1 = b2f(rq.y);
    if (RESBN) {
        float mu0 = sums[c0] * (1.f / Nn), mu1 = sums[c0 + 1] * (1.f / Nn);
        float va0 = sums[HD + c0] * (1.f / Nn) - mu0 * mu0;
        float va1 = sums[HD + c0 + 1] * (1.f / Nn) - mu1 * mu1;
        float sc0 = tof(gv[c0]) * rsqrtf(va0 + EPSV);
        float sc1 = tof(gv[c0 + 1]) * rsqrtf(va1 + EPSV);
        float of0 = tof(bev[c0]) - mu0 * sc0;
        float of1 = tof(bev[c0 + 1]) - mu1 * sc1;
        r0 = fmaxf(fmaf(r0, sc0, of0), 0.f);
        r1 = fmaxf(fmaf(r1, sc1, of1), 0.f);
    }
    float v0 = fmaxf(fmaf(Ov.x, inv, r0), 0.f);  // conv activation relu
    float v1 = fmaxf(fmaf(Ov.y, inv, r1), 0.f);
    ushort2 ov; ov.x = f2u(v0); ov.y = f2u(v1);
    *(ushort2*)&hout[(size_t)d * HD + c0] = ov;
}

// ---------------- fused GATv2 edge kernel, layer 2, PAD47 stride 192 -------------
// MEASURED-BEST variant (r2/r8/r9: ~80us). Lane = 16*h + j owns cc {j, j+16,
// j+32} at c0=h*48+j; 3 scalar ushort gathers/edge; scalar fmaf chain; scalar
// srcW loads; NO alignment peel.
__global__ __launch_bounds__(256) void gat_fused_188(
    const bf16* __restrict__ fs, const bf16* __restrict__ fd,
    const unsigned* __restrict__ srcW, const int* __restrict__ ptr,
    const int* __restrict__ perm,
    const bf16* __restrict__ attn, const bf16* __restrict__ rs,
    void* __restrict__ out, const int* __restrict__ flag) {
    const int wave = threadIdx.x >> 6, lane = threadIdx.x & 63;
    const int di = blockIdx.x * 4 + wave;
    if (di >= Nn) return;
    const int d = perm[di];
    const int h = lane >> 4, j = lane & 15;
    const int c0 = h * 48 + j;        // padded layout
    const unsigned c0b = (unsigned)c0 * 2u;
    const int ca = h * Cc + j;        // attn is unpadded [188]
    const bool has2 = (j < 15);
    float a0 = ldb(&attn[ca]) * L2E;
    float a1 = ldb(&attn[ca + 16]) * L2E;
    float a2 = has2 ? ldb(&attn[ca + 32]) * L2E : 0.f;
    float A0 = 0.6f * a0, B0 = 0.4f * a0;
    float A1 = 0.6f * a1, B1 = 0.4f * a1;
    float A2 = 0.6f * a2, B2 = 0.4f * a2;
    const bf16* fdr = fd + (size_t)d * HCP;
    float fd0 = ldb(&fdr[c0]);
    float fd1 = ldb(&fdr[c0 + 16]);
    float fd2 = ldb(&fdr[c0 + 32]);   // pad = 0 (gemm zero-fills): A2=B2=0 masks
    const char* fsb = (const char*)fs;
    float l = 0.f, O0 = 0.f, O1 = 0.f, O2 = 0.f;
    int e = ptr[d];
    const int e1 = ptr[d + 1];
    for (; e + 3 < e1; e += 4) {
        unsigned vA = srcW[e] + c0b, vB = srcW[e + 1] + c0b;
        unsigned vC = srcW[e + 2] + c0b, vD = srcW[e + 3] + c0b;
        float fA0 = b2f(*(const unsigned short*)(fsb + vA));
        float fA1 = b2f(*(const unsigned short*)(fsb + vA + 32));
        float fA2 = b2f(*(const unsigned short*)(fsb + vA + 64));
        float fB0 = b2f(*(const unsigned short*)(fsb + vB));
        float fB1 = b2f(*(const unsigned short*)(fsb + vB + 32));
        float fB2 = b2f(*(const unsigned short*)(fsb + vB + 64));
        float fC0 = b2f(*(const unsigned short*)(fsb + vC));
        float fC1 = b2f(*(const unsigned short*)(fsb + vC + 32));
        float fC2 = b2f(*(const unsigned short*)(fsb + vC + 64));
        float fD0 = b2f(*(const unsigned short*)(fsb + vD));
        float fD1 = b2f(*(const unsigned short*)(fsb + vD + 32));
        float fD2 = b2f(*(const unsigned short*)(fsb + vD + 64));
        float xA0 = fA0 + fd0, xA1 = fA1 + fd1, xA2 = fA2 + fd2;
        float xB0 = fB0 + fd0, xB1 = fB1 + fd1, xB2 = fB2 + fd2;
        float xC0 = fC0 + fd0, xC1 = fC1 + fd1, xC2 = fC2 + fd2;
        float xD0 = fD0 + fd0, xD1 = fD1 + fd1, xD2 = fD2 + fd2;
        float pA = fmaf(xA0, A0, fmaf(fabsf(xA0), B0, fmaf(xA1, A1, fmaf(fabsf(xA1), B1,
                   fmaf(xA2, A2, fabsf(xA2) * B2)))));
        float pB = fmaf(xB0, A0, fmaf(fabsf(xB0), B0, fmaf(xB1, A1, fmaf(fabsf(xB1), B1,
                   fmaf(xB2, A2, fabsf(xB2) * B2)))));
        float pC = fmaf(xC0, A0, fmaf(fabsf(xC0), B0, fmaf(xC1, A1, fmaf(fabsf(xC1), B1,
                   fmaf(xC2, A2, fabsf(xC2) * B2)))));
        float pD = fmaf(xD0, A0, fmaf(fabsf(xD0), B0, fmaf(xD1, A1, fmaf(fabsf(xD1), B1,
                   fmaf(xD2, A2, fabsf(xD2) * B2)))));
        pA = sum16(pA); pB = sum16(pB); pC = sum16(pC); pD = sum16(pD);
        float eA = __builtin_amdgcn_exp2f(pA), eB = __builtin_amdgcn_exp2f(pB);
        float eC = __builtin_amdgcn_exp2f(pC), eD = __builtin_amdgcn_exp2f(pD);
        l += (eA + eB) + (eC + eD);
        O0 = fmaf(eA, fA0, O0); O0 = fmaf(eB, fB0, O0);
        O0 = fmaf(eC, fC0, O0); O0 = fmaf(eD, fD0, O0);
        O1 = fmaf(eA, fA1, O1); O1 = fmaf(eB, fB1, O1);
        O1 = fmaf(eC, fC1, O1); O1 = fmaf(eD, fD1, O1);
        O2 = fmaf(eA, fA2, O2); O2 = fmaf(eB, fB2, O2);
        O2 = fmaf(eC, fC2, O2); O2 = fmaf(eD, fD2, O2);
    }
    for (; e < e1; ++e) {
        unsigned v = srcW[e] + c0b;
        float f0 = b2f(*(const unsigned short*)(fsb + v));
        float f1 = b2f(*(const unsigned short*)(fsb + v + 32));
        float f2 = b2f(*(const unsigned short*)(fsb + v + 64));
        float x0 = f0 + fd0, x1 = f1 + fd1, x2 = f2 + fd2;
        float p = fmaf(x0, A0, fmaf(fabsf(x0), B0, fmaf(x1, A1, fmaf(fabsf(x1), B1,
                  fmaf(x2, A2, fabsf(x2) * B2)))));
        p = sum16(p);
        float pe = __builtin_amdgcn_exp2f(p);
        l += pe;
        O0 = fmaf(pe, f0, O0);
        O1 = fmaf(pe, f1, O1);
        O2 = fmaf(pe, f2, O2);
    }
    // epilogue: +res, head-mean across lane groups, log_softmax, store
    float inv = l > 0.f ? 1.f / l : 0.f;
    const bf16* rr = rs + (size_t)d * HCP;
    float v0 = fmaf(O0, inv, ldb(&rr[c0]));
    float v1 = fmaf(O1, inv, ldb(&rr[c0 + 16]));
    float v2 = has2 ? fmaf(O2, inv, ldb(&rr[c0 + 32])) : 0.f;
    v0 += __shfl_xor(v0, 16); v0 += __shfl_xor(v0, 32); v0 *= 0.25f;
    v1 += __shfl_xor(v1, 16); v1 += __shfl_xor(v1, 32); v1 *= 0.25f;
    v2 += __shfl_xor(v2, 16); v2 += __shfl_xor(v2, 32); v2 *= 0.25f;
    float mx = fmaxf(v0, v1);
    if (has2) mx = fmaxf(mx, v2);
    mx = max16(mx);
    float sm = __expf(v0 - mx) + __expf(v1 - mx) + (has2 ? __expf(v2 - mx) : 0.f);
    sm = sum16(sm);
    if (h == 0) {
        float ls = mx + __log2f(sm) * LN2;
        if (*flag) {
            bf16* o = (bf16*)out + (size_t)d * Cc;
            o[j] = __float2bfloat16(v0 - ls);
            o[j + 16] = __float2bfloat16(v1 - ls);
            if (has2) o[j + 32] = __float2bfloat16(v2 - ls);
        } else {
            float* o = (float*)out + (size_t)d * Cc;
            o[j] = v0 - ls;
            o[j + 16] = v1 - ls;
            if (has2) o[j + 32] = v2 - ls;
        }
    }
}

// ---------------- per-column BN stats over bf16 h (atomic combine) ----------------
// 391 blocks x 128 threads; ONE atomicAdd per thread per stat (block-reduced
// first). ~100K total atomics over 256 addrs = a few us. (A single-block
// serial finalize regressed to 92us - do NOT revisit that design.)
__global__ void col_stats(const bf16* __restrict__ in, float* __restrict__ sums) {
    int c = threadIdx.x;  // 128
    int r0 = blockIdx.x * 256;
    int r1 = r0 + 256; if (r1 > Nn) r1 = Nn;
    float s = 0.f, s2 = 0.f;
    for (int r = r0; r < r1; ++r) {
        float v = ldb(&in[(size_t)r * HD + c]);
        s += v; s2 += v * v;
    }
    atomicAdd(&sums[c], s);
    atomicAdd(&sums[HD + c], s2);
}

extern "C" void kernel_launch(void* const* d_in, const int* in_sizes, int n_in,
                              void* d_out, int out_size, void* d_ws, size_t ws_size,
                              hipStream_t stream) {
    (void)in_sizes; (void)n_in; (void)out_size; (void)ws_size;
    const void* x = d_in[0];
    const int* src = (const int*)d_in[1];
    const int* dst = (const int*)d_in[2];

    char* ws = (char*)d_ws;
    size_t off = 0;
    auto alloc = [&](size_t bytes) {
        void* p = ws + off;
        off += (bytes + 255) & ~(size_t)255;
        return p;
    };
    // rs (38.4 MB, [Nn][192]) aliases xb+rb (51.2 MB): both dead before L2 GEMM.
    bf16* xb = (bf16*)alloc((size_t)Nn * 128 * 2);    // 25.6 MB (stride-128 padded x)
    bf16* rb = (bf16*)alloc((size_t)Nn * HD * 2);     // 25.6 MB
    bf16* rs = xb;                                    // [Nn][HCP] alias
    bf16* fs = (bf16*)alloc((size_t)Nn * HCP * 2);    // 38.4 MB
    bf16* fd = (bf16*)alloc((size_t)Nn * HCP * 2);    // 38.4 MB
    bf16* hbA = (bf16*)alloc((size_t)Nn * HD * 2);    // 25.6 MB
    bf16* hbB = (bf16*)alloc((size_t)Nn * HD * 2);    // 25.6 MB
    int* ptr = (int*)alloc((Nn + 1) * 4);             // 400 KB
    bf16* wtb = (bf16*)alloc((size_t)WROWS * 128 * 2);// 328 KB
    float* bns0 = (float*)alloc(2 * HD * 4);
    float* bns1 = (float*)alloc(2 * HD * 4);
    bf16* pb = (bf16*)alloc(4096 * 2);
    int* flag = (int*)alloc(256);
    unsigned* w384 = (unsigned*)alloc((size_t)Ee * 4);// 4 MB
    unsigned* w256 = (unsigned*)alloc((size_t)Ee * 4);// 4 MB
    int* cnt = (int*)alloc((size_t)256 * NBLK * 4);   // 400 KB
    int* cbase = (int*)alloc((size_t)256 * NBLK * 4); // 400 KB
    int* totals = (int*)alloc(256 * 4);
    int* perm = (int*)alloc((size_t)Nn * 4);          // 400 KB

    // ---- small-param conversion (biases/attn/bn): d_in idx -> pb arena ----
    static const int spIdx[NSP] = {4, 6, 7, 9, 11, 13, 14, 16, 18, 19, 21, 22, 23, 24, 25};
    static const int spSz[NSP]  = {HD, HD, HD, HD, HD, HD, HD, HC, HC, HC, HC, HD, HD, HD, HD};
    CvtTab tab;
    int tot = 0;
    for (int i = 0; i < NSP; ++i) { tab.src[i] = d_in[spIdx[i]]; tab.off[i] = tot; tot += spSz[i]; }
    tab.off[NSP] = tot;
    const bf16 *bsrc0 = pb + tab.off[0], *bdst0 = pb + tab.off[1], *attn0 = pb + tab.off[2],
               *bres0 = pb + tab.off[3], *bsrc1 = pb + tab.off[4], *bdst1 = pb + tab.off[5],
               *attn1 = pb + tab.off[6], *bsrc2 = pb + tab.off[7], *bdst2 = pb + tab.off[8],
               *attn2 = pb + tab.off[9], *bres2 = pb + tab.off[10],
               *g0 = pb + tab.off[11], *be0 = pb + tab.off[12],
               *g1 = pb + tab.off[13], *be1 = pb + tab.off[14];

    // ---- packed Wt: rows [0,384)=L0, [384,640)=L1, [640,1216)=L2 @MP=192, pad->1280 ----
    PrepTab pt;
    static const int wIdx[8] = {3, 5, 8, 10, 12, 15, 17, 20};
    static const int wK[8]   = {INF_, INF_, INF_, HD, HD, HD, HD, HD};
    static const int wM[8]   = {HD, HD, HD, HD, HD, HC, HC, HC};
    static const int wMP[8]  = {128, 128, 128, 128, 128, 192, 192, 192};
    static const int wR0[8]  = {0, 128, 256, 384, 512, 640, 832, 1024};
    for (int i = 0; i < 8; ++i) {
        pt.src[i] = d_in[wIdx[i]]; pt.row0[i] = wR0[i];
        pt.K[i] = wK[i]; pt.M[i] = wM[i]; pt.MP[i] = wMP[i];
    }

    // ---- mega prepare (detect + cvt_x + weights + params + src offsets + ptr/hist) --
    const int prepGrid = (Nn * 128 + 255) / 256;   // 50000 blocks, covers all jobs
    prepare<<<prepGrid, 256, 0, stream>>>(x, src, dst, pt, tab, tot,
                                          xb, wtb, pb, w384, w256, ptr, cnt,
                                          bns0, bns1, flag);
    deg_totals<<<64, 256, 0, stream>>>(cnt, totals);
    deg_bases<<<64, 256, 0, stream>>>(cnt, totals, cbase);
    deg_scatter_blk<<<NBLK, 256, 0, stream>>>(ptr, cbase, perm);

    const int fusedGrid = (Nn + 3) / 4;   // 256-thread blocks, 4 dsts each
    const int statsGrid = NBLK;
    const int rowBlk = (Nn + 63) / 64;  // 1563

    // ---------------- layer 0 (384 cols: y=2 x CS=3) ----------------
    gemm_big<128, 3, 3, false, false, HD><<<dim3(rowBlk, 2), 256, 0, stream>>>(
        xb, wtb, bsrc0, bdst0, bres0, fs, fd, rb, HD, nullptr, nullptr, nullptr);
    gat_fused_128<false><<<fusedGrid, 256, 0, stream>>>(fs, fd, w256, ptr, perm,
                                                        attn0, rb, nullptr, nullptr,
                                                        nullptr, hbA);
    col_stats<<<statsGrid, 128, 0, stream>>>(hbA, bns0);

    // ---------------- layer 1 (256 cols: y=2 x CS=2) ----------------
    gemm_big<128, 2, 2, true, false, HD><<<dim3(rowBlk, 2), 256, 0, stream>>>(
        hbA, wtb + (size_t)384 * 128, bsrc1, bdst1, nullptr, fs, fd, nullptr, HD,
        bns0, g0, be0);
    gat_fused_128<true><<<fusedGrid, 256, 0, stream>>>(fs, fd, w256, ptr, perm,
                                                       attn1, hbA, bns0, g0, be0, hbB);
    col_stats<<<statsGrid, 128, 0, stream>>>(hbB, bns1);

    // ---------------- layer 2 (576 cols: y=3 x CS=3, pad47 coalesced outputs) -----
    gemm_big<192, 3, 3, true, true, HCP><<<dim3(rowBlk, 3), 256, 0, stream>>>(
        hbB, wtb + (size_t)640 * 128, bsrc2, bdst2, bres2, fs, fd, rs, HC,
        bns1, g1, be1);
    gat_fused_188<<<fusedGrid, 256, 0, stream>>>(fs, fd, w384, ptr, perm, attn2, rs,
                                                 d_out, flag);
}

// Round 11
// 627.666 us; speedup vs baseline: 1.1229x; 1.0335x over previous
//
#include <hip/hip_runtime.h>
#include <hip/hip_bf16.h>

#define Nn 100000
#define Ee 1000000
#define INF_ 100
#define Hh 4
#define Dd 32
#define HD 128
#define Cc 47
#define HC 188
#define HCP 192
#define EPSV 1e-5f
#define SLOPE 0.2f
#define NBLK ((Nn + 255) / 256)

typedef __hip_bfloat16 bf16;
typedef __attribute__((ext_vector_type(8))) short short8;
typedef __attribute__((ext_vector_type(4))) float f32x4;
typedef __attribute__((ext_vector_type(2))) float f32x2;

__device__ __forceinline__ float tof(bf16 v) { return __bfloat162float(v); }
__device__ __forceinline__ float b2f(unsigned short u) {
    return __uint_as_float((unsigned)u << 16);
}
__device__ __forceinline__ float b2flo(unsigned u) {
    return __uint_as_float(u << 16);
}
__device__ __forceinline__ float b2fhi(unsigned u) {
    return __uint_as_float(u & 0xFFFF0000u);
}
__device__ __forceinline__ float ldb(const bf16* p) {
    return b2f(*(const unsigned short*)p);
}
__device__ __forceinline__ unsigned short f2u(float v) {
    bf16 t = __float2bfloat16(v);
    return *(unsigned short*)&t;
}
__device__ __forceinline__ f32x2 pk2(float x, float y) {
    f32x2 r; r.x = x; r.y = y; return r;
}
__device__ __forceinline__ f32x2 pabs2(f32x2 v) {          // v_pk_max_f32 v, -v
    return __builtin_elementwise_max(v, -v);
}
__device__ __forceinline__ f32x2 pfma2(f32x2 a, f32x2 b, f32x2 c) {
    return __builtin_elementwise_fma(a, b, c);             // v_pk_fma_f32
}

// DPP-fused 16-lane reduces (quad_perm swaps + row rotates; row=16 lanes).
template <int C>
__device__ __forceinline__ float dppadd(float v) {
    int m = __builtin_amdgcn_update_dpp(0, __float_as_int(v), C, 0xF, 0xF, false);
    return v + __int_as_float(m);
}
template <int C>
__device__ __forceinline__ float dppmax(float v) {
    int m = __builtin_amdgcn_update_dpp(0, __float_as_int(v), C, 0xF, 0xF, false);
    return fmaxf(v, __int_as_float(m));
}
__device__ __forceinline__ float sum16(float p) {
    p = dppadd<0xB1>(p);   // quad_perm [1,0,3,2]
    p = dppadd<0x4E>(p);   // quad_perm [2,3,0,1]
    p = dppadd<0x124>(p);  // row_ror:4
    p = dppadd<0x128>(p);  // row_ror:8
    return p;
}
__device__ __forceinline__ float max16(float p) {
    p = dppmax<0xB1>(p); p = dppmax<0x4E>(p);
    p = dppmax<0x124>(p); p = dppmax<0x128>(p);
    return p;
}

#define L2E 1.4426950408889634f
#define LN2 0.6931471805599453f

__device__ __forceinline__ float ld_any(const void* p, int i, int isbf) {
    return isbf ? tof(((const bf16*)p)[i]) : ((const float*)p)[i];
}

__device__ __forceinline__ int lbound(const int* __restrict__ dst, int n) {
    int lo = 0, hi = Ee;
    while (lo < hi) {
        int mid = (lo + hi) >> 1;
        if (dst[mid] < n) lo = mid + 1; else hi = mid;
    }
    return lo;
}

// ---------------- MEGA prepare kernel (replaces 5 launches) ----------------
// Each block independently derives the dtype flag (ballot over x[0..255] words,
// L2-hot, deterministic) -> no cross-kernel flag dependency. Jobs partitioned
// by global index: cvt_x | weight pack | small params | src byte-offsets |
// bns zeroing | CSR ptr + BLOCK-LOCAL degree histogram (lower_bounds shared
// through LDS so hist needs no globally-complete ptr).
#define WROWS 1280
#define NSP 15
struct PrepTab { const void* src[8]; int row0[8]; int K[8]; int M[8]; int MP[8]; };
struct CvtTab { const void* src[NSP]; int off[NSP + 1]; };

__global__ __launch_bounds__(256) void prepare(
    const void* __restrict__ x, const int* __restrict__ src,
    const int* __restrict__ dst,
    PrepTab pt, CvtTab ct, int tot,
    bf16* __restrict__ xb, bf16* __restrict__ wtb, bf16* __restrict__ pb,
    unsigned* __restrict__ w384, unsigned* __restrict__ w256,
    int* __restrict__ ptr, int* __restrict__ cnt,
    float* __restrict__ z0, float* __restrict__ z1, int* __restrict__ flag) {
    __shared__ int wc[4];
    __shared__ int lbv[257];
    __shared__ int lh[256];
    const int t = threadIdx.x;
    // ---- per-block dtype detect ----
    unsigned w = ((const unsigned*)x)[t];
    float dv = __uint_as_float((w & 0xFFFFu) << 16);
    float da = fabsf(dv);
    unsigned long long m = __ballot(da > 1e-4f && da < 10.f);
    if ((t & 63) == 0) wc[t >> 6] = __popcll(m);
    __syncthreads();
    const int isbf = (wc[0] + wc[1] + wc[2] + wc[3]) >= 128;
    if (blockIdx.x == 0 && t == 0) *flag = isbf;

    const int gi = blockIdx.x * 256 + t;
    // ---- cvt_x: [Nn][100] -> bf16 [Nn][128] ----
    if (gi < Nn * 128) {
        int row = gi >> 7, col = gi & 127;
        float v = (col < INF_) ? ld_any(x, row * INF_ + col, isbf) : 0.f;
        xb[gi] = __float2bfloat16(v);
    }
    // ---- weights -> packed transposed Wt[1280][128] ----
    if (gi < WROWS * 128) {
        int row = gi >> 7, k = gi & 127;
        float v = 0.f;
#pragma unroll
        for (int q = 0; q < 8; ++q) {
            if (row >= pt.row0[q] && row < pt.row0[q] + pt.MP[q]) {
                int mm = row - pt.row0[q];
                if (mm < pt.M[q] && k < pt.K[q])
                    v = ld_any(pt.src[q], k * pt.M[q] + mm, isbf);
            }
        }
        wtb[gi] = __float2bfloat16(v);
    }
    // ---- small params ----
    if (gi < tot) {
        int seg = 0;
        while (gi >= ct.off[seg + 1]) seg++;
        pb[gi] = __float2bfloat16(ld_any(ct.src[seg], gi - ct.off[seg], isbf));
    }
    // ---- pre-scaled src byte offsets ----
    if (gi < Ee) {
        unsigned s = (unsigned)src[gi];
        w384[gi] = s * 384u;  // stride HCP*2 bytes (layer-2 split-pack fs)
        w256[gi] = s << 8;    // stride HD*2 bytes  (layer-0/1 fs)
    }
    // ---- BN accumulator zeroing ----
    if (gi < 2 * HD) { z0[gi] = 0.f; z1[gi] = 0.f; }
    // ---- CSR ptr + block-local degree histogram ----
    if (blockIdx.x < NBLK) {
        int nn = gi;
        int lb = Ee;
        if (nn <= Nn) { lb = lbound(dst, nn); ptr[nn] = lb; }
        lbv[t] = lb;
        if (t == 255) lbv[256] = (nn + 1 <= Nn) ? lbound(dst, nn + 1) : Ee;
        lh[t] = 0;
        __syncthreads();
        if (nn < Nn) {
            int dg = lbv[t + 1] - lbv[t]; if (dg > 255) dg = 255;
            atomicAdd(&lh[dg], 1);
        }
        __syncthreads();
        cnt[t * NBLK + blockIdx.x] = lh[t];
    }
}

// ---------------- degree-descending LPT permutation (continued) -------------------
// one wave per bin (64 blocks x 4 waves): lane-strided coalesced total
__global__ void deg_totals(const int* __restrict__ cnt, int* __restrict__ totals) {
    int wave = threadIdx.x >> 6, lane = threadIdx.x & 63;
    int bin = blockIdx.x * 4 + wave;
    int s = 0;
    for (int k = lane; k < NBLK; k += 64) s += cnt[bin * NBLK + k];
#pragma unroll
    for (int o = 1; o < 64; o <<= 1) s += __shfl_xor(s, o);
    if (lane == 0) totals[bin] = s;
}

// one wave per bin: binbase = sum of totals over HIGHER-degree bins, then
// chunked 64-lane exclusive prefix over the NBLK per-block counts.
__global__ void deg_bases(const int* __restrict__ cnt, const int* __restrict__ totals,
                          int* __restrict__ base) {
    int wave = threadIdx.x >> 6, lane = threadIdx.x & 63;
    int bin = blockIdx.x * 4 + wave;
    int bb = 0;
    for (int b = bin + 1 + lane; b < 256; b += 64) bb += totals[b];
#pragma unroll
    for (int o = 1; o < 64; o <<= 1) bb += __shfl_xor(bb, o);
    int run = bb;   // descending-degree base for this bin
    for (int k0 = 0; k0 < NBLK; k0 += 64) {
        int k = k0 + lane;
        int c = (k < NBLK) ? cnt[bin * NBLK + k] : 0;
        int p = c;
#pragma unroll
        for (int o = 1; o < 64; o <<= 1) {
            int t = __shfl_up(p, o);
            if (lane >= o) p += t;
        }
        if (k < NBLK) base[bin * NBLK + k] = run + (p - c);
        run += __shfl(p, 63);
    }
}

__global__ void deg_scatter_blk(const int* __restrict__ ptr, const int* __restrict__ base,
                                int* __restrict__ perm) {
    __shared__ int lh[256];
    int t = threadIdx.x;
    lh[t] = 0;
    __syncthreads();
    int n = blockIdx.x * 256 + t;
    if (n < Nn) {
        int dg = ptr[n + 1] - ptr[n]; if (dg > 255) dg = 255;
        int loc = atomicAdd(&lh[dg], 1);   // LDS atomic: one CU, cheap
        perm[base[dg * NBLK + blockIdx.x] + loc] = n;
    }
}

// ---------------- big-tile MFMA GEMM: 64 rows x (64*CS) cols per block -------------
// y-grid column split (deep grid hides store latency; NY-in-kernel regressed).
// LDS-staged COALESCED epilogue. PACK (layer-2 SPLIT layout): col lc -> h=lc/47,
// cc=lc%47, j=cc&15, k=cc>>4, lane l=16h+j; k<2 -> elem 2l+k (dword zone,
// bytes 0..255); k=2 -> elem 128+l (ushort zone, bytes 256..383). 384B row,
// zero traffic overhead; gat_188 needs only 2 gathers/edge.
template <int MP, int NOUT, int CS, bool ABN, bool PACK, int OSTR>
__global__ __launch_bounds__(256, 4) void gemm_big(
    const bf16* __restrict__ A, const bf16* __restrict__ Wt,
    const bf16* __restrict__ b0, const bf16* __restrict__ b1,
    const bf16* __restrict__ b2,
    bf16* __restrict__ o0, bf16* __restrict__ o1, bf16* __restrict__ o2,
    int MR, const float* __restrict__ sums,
    const bf16* __restrict__ gg, const bf16* __restrict__ bbn) {
    constexpr int CS64 = CS * 64;
    constexpr int PITCH = CS64 + 8;                 // 16B-aligned row stride
    constexpr int LSZ = (64 * PITCH > 64 * 136) ? 64 * PITCH : 64 * 136;
    __shared__ __align__(16) bf16 Al[LSZ];
    __shared__ float scb[ABN ? HD : 1], ofb[ABN ? HD : 1];
    const int row0 = blockIdx.x * 64;
    const int tid = threadIdx.x;
    if (ABN) {
        if (tid < HD) {
            float mu = sums[tid] * (1.f / Nn);
            float var = sums[HD + tid] * (1.f / Nn) - mu * mu;
            float sc = tof(gg[tid]) * rsqrtf(var + EPSV);
            scb[tid] = sc;
            ofb[tid] = tof(bbn[tid]) - mu * sc;
        }
        __syncthreads();
    }
#pragma unroll
    for (int j = 0; j < 4; ++j) {
        int idx = tid + j * 256;          // 0..1023 int4 slots
        int r = idx >> 4, kk = (idx & 15) * 8;
        int4 val = {0, 0, 0, 0};
        if (row0 + r < Nn) {
            val = *(const int4*)&A[(size_t)(row0 + r) * 128 + kk];
            if (ABN) {
                short8 av = *(short8*)&val;
                bf16 tmp[8];
#pragma unroll
                for (int u = 0; u < 8; ++u) {
                    float v = b2f((unsigned short)av[u]);
                    v = fmaxf(fmaf(v, scb[kk + u], ofb[kk + u]), 0.f);
                    tmp[u] = __float2bfloat16(v);
                }
                val = *(int4*)tmp;
            }
        }
        *(int4*)&Al[r * 136 + kk] = val;
    }
    __syncthreads();
    const int wave = tid >> 6, lane = tid & 63;
    const int n16 = lane & 15, quad = lane >> 4;
    const int colbase = blockIdx.y * CS64 + wave * (16 * CS);
    f32x4 acc[4][CS];
#pragma unroll
    for (int rt = 0; rt < 4; ++rt)
#pragma unroll
        for (int c = 0; c < CS; ++c) acc[rt][c] = (f32x4){0.f, 0.f, 0.f, 0.f};
    const bf16* wb[CS];
#pragma unroll
    for (int c = 0; c < CS; ++c)
        wb[c] = Wt + (size_t)(colbase + c * 16 + n16) * 128 + quad * 8;
    const bf16* ap = Al + n16 * 136 + quad * 8;
#pragma unroll
    for (int ks = 0; ks < 4; ++ks) {
        short8 bf[CS];
#pragma unroll
        for (int c = 0; c < CS; ++c) bf[c] = *(const short8*)(wb[c] + ks * 32);
#pragma unroll
        for (int rt = 0; rt < 4; ++rt) {
            short8 af = *(const short8*)(ap + rt * 16 * 136 + ks * 32);
#pragma unroll
            for (int c = 0; c < CS; ++c)
                acc[rt][c] = __builtin_amdgcn_mfma_f32_16x16x32_bf16(af, bf[c], acc[rt][c], 0, 0, 0);
        }
    }
    // ---- stage epilogue: Al reads done, reuse as [64][PITCH] ----
    __syncthreads();
    if (PACK) {   // zero pad slots (ushort-zone j=15 lanes + pitch cols)
        for (int z = tid; z < 64 * PITCH; z += 256) Al[z] = __float2bfloat16(0.f);
        __syncthreads();
    }
#pragma unroll
    for (int c = 0; c < CS; ++c) {
        int pos = wave * (16 * CS) + c * 16 + n16;    // within-block col
        int col = colbase + c * 16 + n16;
        int oi = col / MP, lc = col - oi * MP;
        bool valid = (oi < NOUT) && (lc < MR);
        float bb = 0.f;
        if (valid) {
            const bf16* bp = (oi == 0) ? b0 : (oi == 1) ? b1 : b2;
            bb = tof(bp[lc]);
        }
        int stp;
        if (PACK) {
            int hh = lc / 47, cc2 = lc - hh * 47;
            int jj = cc2 & 15, kk2 = cc2 >> 4;
            int l = hh * 16 + jj;
            stp = (kk2 < 2) ? (2 * l + kk2) : (128 + l);
        } else {
            stp = pos;
        }
#pragma unroll
        for (int rt = 0; rt < 4; ++rt) {
#pragma unroll
            for (int i = 0; i < 4; ++i) {
                int rl = rt * 16 + quad * 4 + i;
                if (valid) Al[rl * PITCH + stp] = __float2bfloat16(acc[rt][c][i] + bb);
            }
        }
    }
    __syncthreads();
    // ---- coalesced store: 8-elem (16B) groups; PACK stage IS the split layout ----
    constexpr int NG = CS64 / 8;
    for (int t = tid; t < 64 * NG; t += 256) {
        int rl = t / NG, g = t % NG;
        int row = row0 + rl;
        if (row >= Nn) continue;
        int pos0 = g * 8;
        int oi, lc0;
        if (PACK) { oi = blockIdx.y; lc0 = pos0; }    // y-block = full oi zone
        else {
            int col0 = blockIdx.y * CS64 + pos0;      // 8-group within one oi
            oi = col0 / MP; lc0 = col0 - oi * MP;
        }
        if (oi >= NOUT) continue;
        bf16* o = (oi == 0) ? o0 : (oi == 1) ? o1 : o2;
        int4 v = *(int4*)&Al[rl * PITCH + pos0];
        *(int4*)&o[(size_t)row * OSTR + lc0] = v;
    }
}

// ---------------- fused GATv2 edge kernel, M=128 (layers 0,1) ----------------
// 256 threads = 4 dsts/block. Lane holds cols (2*lane, 2*lane+1). MAX-FREE
// softmax, log2e folded into attn. Packed-FP32 math. srcW loads are WAVE-
// UNIFORM -> s_load (near-free); NO alignment peel (peel added ~1.5 single-edge
// iters/dst for negligible scalar-load savings).
template <bool RESBN>
__global__ __launch_bounds__(256) void gat_fused_128(
    const bf16* __restrict__ fs, const bf16* __restrict__ fd,
    const unsigned* __restrict__ srcW, const int* __restrict__ ptr,
    const int* __restrict__ perm,
    const bf16* __restrict__ attn, const bf16* __restrict__ resb,
    const float* __restrict__ sums, const bf16* __restrict__ gv,
    const bf16* __restrict__ bev, bf16* __restrict__ hout) {
    const int wave = threadIdx.x >> 6, lane = threadIdx.x & 63;
    const int di = blockIdx.x * 4 + wave;
    if (di >= Nn) return;
    const int d = perm[di];
    const int c0 = lane * 2;
    const unsigned c0b = (unsigned)c0 * 2u;
    ushort2 aq = *(const ushort2*)&attn[c0];
    float a0 = b2f(aq.x) * L2E, a1 = b2f(aq.y) * L2E;
    const f32x2 Av = pk2(0.6f * a0, 0.6f * a1);
    const f32x2 Bv = pk2(0.4f * a0, 0.4f * a1);
    ushort2 dq = *(const ushort2*)&fd[(size_t)d * HD + c0];
    const f32x2 fdv = pk2(b2f(dq.x), b2f(dq.y));
    const char* fsb = (const char*)fs;
    float l = 0.f;
    f32x2 Ov = pk2(0.f, 0.f);
    int e = ptr[d];
    const int e1 = ptr[d + 1];
    for (; e + 3 < e1; e += 4) {
        unsigned vA = srcW[e] + c0b, vB = srcW[e + 1] + c0b;
        unsigned vC = srcW[e + 2] + c0b, vD = srcW[e + 3] + c0b;
        ushort2 qA = *(const ushort2*)(fsb + vA);
        ushort2 qB = *(const ushort2*)(fsb + vB);
        ushort2 qC = *(const ushort2*)(fsb + vC);
        ushort2 qD = *(const ushort2*)(fsb + vD);
        f32x2 fA = pk2(b2f(qA.x), b2f(qA.y));
        f32x2 fB = pk2(b2f(qB.x), b2f(qB.y));
        f32x2 fC = pk2(b2f(qC.x), b2f(qC.y));
        f32x2 fD = pk2(b2f(qD.x), b2f(qD.y));
        f32x2 xA = fA + fdv, xB = fB + fdv, xC = fC + fdv, xD = fD + fdv;
        f32x2 tA = pfma2(pabs2(xA), Bv, xA * Av);
        f32x2 tB = pfma2(pabs2(xB), Bv, xB * Av);
        f32x2 tC = pfma2(pabs2(xC), Bv, xC * Av);
        f32x2 tD = pfma2(pabs2(xD), Bv, xD * Av);
        float pA = tA.x + tA.y, pB = tB.x + tB.y;
        float pC = tC.x + tC.y, pD = tD.x + tD.y;
        pA = sum16(pA); pB = sum16(pB); pC = sum16(pC); pD = sum16(pD);
        float eA = __builtin_amdgcn_exp2f(pA), eB = __builtin_amdgcn_exp2f(pB);
        float eC = __builtin_amdgcn_exp2f(pC), eD = __builtin_amdgcn_exp2f(pD);
        l += (eA + eB) + (eC + eD);
        Ov = pfma2(pk2(eA, eA), fA, Ov);
        Ov = pfma2(pk2(eB, eB), fB, Ov);
        Ov = pfma2(pk2(eC, eC), fC, Ov);
        Ov = pfma2(pk2(eD, eD), fD, Ov);
    }
    for (; e < e1; ++e) {
        unsigned v = srcW[e] + c0b;
        ushort2 fq = *(const ushort2*)(fsb + v);
        f32x2 f = pk2(b2f(fq.x), b2f(fq.y));
        f32x2 x = f + fdv;
        f32x2 t = pfma2(pabs2(x), Bv, x * Av);
        float p = sum16(t.x + t.y);
        float pe = __builtin_amdgcn_exp2f(p);
        l += pe;
        Ov = pfma2(pk2(pe, pe), f, Ov);
    }
    float inv = l > 0.f ? 1.f / l : 0.f;
    ushort2 rq = *(const ushort2*)&resb[(size_t)d * HD + c0];
    float r0 = b2f(rq.x), r1 = b2f(rq.y);
    if (RESBN) {
        float mu0 = sums[c0] * (1.f / Nn), mu1 = sums[c0 + 1] * (1.f / Nn);
        float va0 = sums[HD + c0] * (1.f / Nn) - mu0 * mu0;
        float va1 = sums[HD + c0 + 1] * (1.f / Nn) - mu1 * mu1;
        float sc0 = tof(gv[c0]) * rsqrtf(va0 + EPSV);
        float sc1 = tof(gv[c0 + 1]) * rsqrtf(va1 + EPSV);
        float of0 = tof(bev[c0]) - mu0 * sc0;
        float of1 = tof(bev[c0 + 1]) - mu1 * sc1;
        r0 = fmaxf(fmaf(r0, sc0, of0), 0.f);
        r1 = fmaxf(fmaf(r1, sc1, of1), 0.f);
    }
    float v0 = fmaxf(fmaf(Ov.x, inv, r0), 0.f);  // conv activation relu
    float v1 = fmaxf(fmaf(Ov.y, inv, r1), 0.f);
    ushort2 ov; ov.x = f2u(v0); ov.y = f2u(v1);
    *(ushort2*)&hout[(size_t)d * HD + c0] = ov;
}

// ---------------- fused GATv2 edge kernel, layer 2, SPLIT-PACK stride 192 --------
// Lane l=16h+j owns cc {j, j+16} as ONE dword at byte 4l and {j+32} as ONE
// ushort at byte 256+2l (2 gathers/edge vs pad47's 3; same 384B row = same
// FETCH). Scalar fmaf chain (pk hadd breaks pairs); scalar uniform srcW
// (s_load); NO alignment peel. j=15 lanes: pad zero-filled, A2=B2=0 masks.
__global__ __launch_bounds__(256) void gat_fused_188(
    const bf16* __restrict__ fs, const bf16* __restrict__ fd,
    const unsigned* __restrict__ srcW, const int* __restrict__ ptr,
    const int* __restrict__ perm,
    const bf16* __restrict__ attn, const bf16* __restrict__ rs,
    void* __restrict__ out, const int* __restrict__ flag) {
    const int wave = threadIdx.x >> 6, lane = threadIdx.x & 63;
    const int di = blockIdx.x * 4 + wave;
    if (di >= Nn) return;
    const int d = perm[di];
    const int h = lane >> 4, j = lane & 15;
    const unsigned cbA = (unsigned)lane * 4u;          // dword zone
    const unsigned cbB = 256u + (unsigned)lane * 2u;   // ushort zone
    const int ca = h * Cc + j;                         // attn is unpadded [188]
    const bool has2 = (j < 15);
    float a0 = ldb(&attn[ca]) * L2E;
    float a1 = ldb(&attn[ca + 16]) * L2E;
    float a2 = has2 ? ldb(&attn[ca + 32]) * L2E : 0.f;
    float A0 = 0.6f * a0, B0 = 0.4f * a0;
    float A1 = 0.6f * a1, B1 = 0.4f * a1;
    float A2 = 0.6f * a2, B2 = 0.4f * a2;
    const char* fdb = (const char*)fd;
    const size_t drow = (size_t)d * 384u;
    unsigned dqa = *(const unsigned*)(fdb + drow + cbA);
    unsigned short dqb = *(const unsigned short*)(fdb + drow + cbB);
    float fd0 = b2flo(dqa), fd1 = b2fhi(dqa);
    float fd2 = b2f(dqb);   // j=15: zero-filled pad, A2=B2=0 masks
    const char* fsb = (const char*)fs;
    float l = 0.f, O0 = 0.f, O1 = 0.f, O2 = 0.f;
    int e = ptr[d];
    const int e1 = ptr[d + 1];
    for (; e + 3 < e1; e += 4) {
        unsigned bA = srcW[e], bB = srcW[e + 1], bC = srcW[e + 2], bD = srcW[e + 3];
        unsigned qA = *(const unsigned*)(fsb + bA + cbA);
        unsigned qB = *(const unsigned*)(fsb + bB + cbA);
        unsigned qC = *(const unsigned*)(fsb + bC + cbA);
        unsigned qD = *(const unsigned*)(fsb + bD + cbA);
        unsigned short uA = *(const unsigned short*)(fsb + bA + cbB);
        unsigned short uB = *(const unsigned short*)(fsb + bB + cbB);
        unsigned short uC = *(const unsigned short*)(fsb + bC + cbB);
        unsigned short uD = *(const unsigned short*)(fsb + bD + cbB);
        float fA0 = b2flo(qA), fA1 = b2fhi(qA), fA2 = b2f(uA);
        float fB0 = b2flo(qB), fB1 = b2fhi(qB), fB2 = b2f(uB);
        float fC0 = b2flo(qC), fC1 = b2fhi(qC), fC2 = b2f(uC);
        float fD0 = b2flo(qD), fD1 = b2fhi(qD), fD2 = b2f(uD);
        float xA0 = fA0 + fd0, xA1 = fA1 + fd1, xA2 = fA2 + fd2;
        float xB0 = fB0 + fd0, xB1 = fB1 + fd1, xB2 = fB2 + fd2;
        float xC0 = fC0 + fd0, xC1 = fC1 + fd1, xC2 = fC2 + fd2;
        float xD0 = fD0 + fd0, xD1 = fD1 + fd1, xD2 = fD2 + fd2;
        float pA = fmaf(xA0, A0, fmaf(fabsf(xA0), B0, fmaf(xA1, A1, fmaf(fabsf(xA1), B1,
                   fmaf(xA2, A2, fabsf(xA2) * B2)))));
        float pB = fmaf(xB0, A0, fmaf(fabsf(xB0), B0, fmaf(xB1, A1, fmaf(fabsf(xB1), B1,
                   fmaf(xB2, A2, fabsf(xB2) * B2)))));
        float pC = fmaf(xC0, A0, fmaf(fabsf(xC0), B0, fmaf(xC1, A1, fmaf(fabsf(xC1), B1,
                   fmaf(xC2, A2, fabsf(xC2) * B2)))));
        float pD = fmaf(xD0, A0, fmaf(fabsf(xD0), B0, fmaf(xD1, A1, fmaf(fabsf(xD1), B1,
                   fmaf(xD2, A2, fabsf(xD2) * B2)))));
        pA = sum16(pA); pB = sum16(pB); pC = sum16(pC); pD = sum16(pD);
        float eA = __builtin_amdgcn_exp2f(pA), eB = __builtin_amdgcn_exp2f(pB);
        float eC = __builtin_amdgcn_exp2f(pC), eD = __builtin_amdgcn_exp2f(pD);
        l += (eA + eB) + (eC + eD);
        O0 = fmaf(eA, fA0, O0); O0 = fmaf(eB, fB0, O0);
        O0 = fmaf(eC, fC0, O0); O0 = fmaf(eD, fD0, O0);
        O1 = fmaf(eA, fA1, O1); O1 = fmaf(eB, fB1, O1);
        O1 = fmaf(eC, fC1, O1); O1 = fmaf(eD, fD1, O1);
        O2 = fmaf(eA, fA2, O2); O2 = fmaf(eB, fB2, O2);
        O2 = fmaf(eC, fC2, O2); O2 = fmaf(eD, fD2, O2);
    }
    for (; e < e1; ++e) {
        unsigned b = srcW[e];
        unsigned q = *(const unsigned*)(fsb + b + cbA);
        unsigned short u = *(const unsigned short*)(fsb + b + cbB);
        float f0 = b2flo(q), f1 = b2fhi(q), f2 = b2f(u);
        float x0 = f0 + fd0, x1 = f1 + fd1, x2 = f2 + fd2;
        float p = fmaf(x0, A0, fmaf(fabsf(x0), B0, fmaf(x1, A1, fmaf(fabsf(x1), B1,
                  fmaf(x2, A2, fabsf(x2) * B2)))));
        p = sum16(p);
        float pe = __builtin_amdgcn_exp2f(p);
        l += pe;
        O0 = fmaf(pe, f0, O0);
        O1 = fmaf(pe, f1, O1);
        O2 = fmaf(pe, f2, O2);
    }
    // epilogue: +res, head-mean across lane groups, log_softmax, store
    float inv = l > 0.f ? 1.f / l : 0.f;
    const char* rb_ = (const char*)rs;
    unsigned rqa = *(const unsigned*)(rb_ + drow + cbA);
    unsigned short rqb = *(const unsigned short*)(rb_ + drow + cbB);
    float v0 = fmaf(O0, inv, b2flo(rqa));
    float v1 = fmaf(O1, inv, b2fhi(rqa));
    float v2 = has2 ? fmaf(O2, inv, b2f(rqb)) : 0.f;
    v0 += __shfl_xor(v0, 16); v0 += __shfl_xor(v0, 32); v0 *= 0.25f;
    v1 += __shfl_xor(v1, 16); v1 += __shfl_xor(v1, 32); v1 *= 0.25f;
    v2 += __shfl_xor(v2, 16); v2 += __shfl_xor(v2, 32); v2 *= 0.25f;
    float mx = fmaxf(v0, v1);
    if (has2) mx = fmaxf(mx, v2);
    mx = max16(mx);
    float sm = __expf(v0 - mx) + __expf(v1 - mx) + (has2 ? __expf(v2 - mx) : 0.f);
    sm = sum16(sm);
    if (h == 0) {
        float ls = mx + __log2f(sm) * LN2;
        if (*flag) {
            bf16* o = (bf16*)out + (size_t)d * Cc;
            o[j] = __float2bfloat16(v0 - ls);
            o[j + 16] = __float2bfloat16(v1 - ls);
            if (has2) o[j + 32] = __float2bfloat16(v2 - ls);
        } else {
            float* o = (float*)out + (size_t)d * Cc;
            o[j] = v0 - ls;
            o[j + 16] = v1 - ls;
            if (has2) o[j + 32] = v2 - ls;
        }
    }
}

// ---------------- per-column BN stats over bf16 h (atomic combine) ----------------
// 391 blocks x 128 threads; ONE atomicAdd per thread per stat (block-reduced
// first). ~100K total atomics over 256 addrs = a few us. (A single-block
// serial finalize regressed to 92us - do NOT revisit that design.)
__global__ void col_stats(const bf16* __restrict__ in, float* __restrict__ sums) {
    int c = threadIdx.x;  // 128
    int r0 = blockIdx.x * 256;
    int r1 = r0 + 256; if (r1 > Nn) r1 = Nn;
    float s = 0.f, s2 = 0.f;
    for (int r = r0; r < r1; ++r) {
        float v = ldb(&in[(size_t)r * HD + c]);
        s += v; s2 += v * v;
    }
    atomicAdd(&sums[c], s);
    atomicAdd(&sums[HD + c], s2);
}

extern "C" void kernel_launch(void* const* d_in, const int* in_sizes, int n_in,
                              void* d_out, int out_size, void* d_ws, size_t ws_size,
                              hipStream_t stream) {
    (void)in_sizes; (void)n_in; (void)out_size; (void)ws_size;
    const void* x = d_in[0];
    const int* src = (const int*)d_in[1];
    const int* dst = (const int*)d_in[2];

    char* ws = (char*)d_ws;
    size_t off = 0;
    auto alloc = [&](size_t bytes) {
        void* p = ws + off;
        off += (bytes + 255) & ~(size_t)255;
        return p;
    };
    // rs (38.4 MB, [Nn][192]) aliases xb+rb (51.2 MB): both dead before L2 GEMM.
    bf16* xb = (bf16*)alloc((size_t)Nn * 128 * 2);    // 25.6 MB (stride-128 padded x)
    bf16* rb = (bf16*)alloc((size_t)Nn * HD * 2);     // 25.6 MB
    bf16* rs = xb;                                    // [Nn][HCP] alias
    bf16* fs = (bf16*)alloc((size_t)Nn * HCP * 2);    // 38.4 MB
    bf16* fd = (bf16*)alloc((size_t)Nn * HCP * 2);    // 38.4 MB
    bf16* hbA = (bf16*)alloc((size_t)Nn * HD * 2);    // 25.6 MB
    bf16* hbB = (bf16*)alloc((size_t)Nn * HD * 2);    // 25.6 MB
    int* ptr = (int*)alloc((Nn + 1) * 4);             // 400 KB
    bf16* wtb = (bf16*)alloc((size_t)WROWS * 128 * 2);// 328 KB
    float* bns0 = (float*)alloc(2 * HD * 4);
    float* bns1 = (float*)alloc(2 * HD * 4);
    bf16* pb = (bf16*)alloc(4096 * 2);
    int* flag = (int*)alloc(256);
    unsigned* w384 = (unsigned*)alloc((size_t)Ee * 4);// 4 MB
    unsigned* w256 = (unsigned*)alloc((size_t)Ee * 4);// 4 MB
    int* cnt = (int*)alloc((size_t)256 * NBLK * 4);   // 400 KB
    int* cbase = (int*)alloc((size_t)256 * NBLK * 4); // 400 KB
    int* totals = (int*)alloc(256 * 4);
    int* perm = (int*)alloc((size_t)Nn * 4);          // 400 KB

    // ---- small-param conversion (biases/attn/bn): d_in idx -> pb arena ----
    static const int spIdx[NSP] = {4, 6, 7, 9, 11, 13, 14, 16, 18, 19, 21, 22, 23, 24, 25};
    static const int spSz[NSP]  = {HD, HD, HD, HD, HD, HD, HD, HC, HC, HC, HC, HD, HD, HD, HD};
    CvtTab tab;
    int tot = 0;
    for (int i = 0; i < NSP; ++i) { tab.src[i] = d_in[spIdx[i]]; tab.off[i] = tot; tot += spSz[i]; }
    tab.off[NSP] = tot;
    const bf16 *bsrc0 = pb + tab.off[0], *bdst0 = pb + tab.off[1], *attn0 = pb + tab.off[2],
               *bres0 = pb + tab.off[3], *bsrc1 = pb + tab.off[4], *bdst1 = pb + tab.off[5],
               *attn1 = pb + tab.off[6], *bsrc2 = pb + tab.off[7], *bdst2 = pb + tab.off[8],
               *attn2 = pb + tab.off[9], *bres2 = pb + tab.off[10],
               *g0 = pb + tab.off[11], *be0 = pb + tab.off[12],
               *g1 = pb + tab.off[13], *be1 = pb + tab.off[14];

    // ---- packed Wt: rows [0,384)=L0, [384,640)=L1, [640,1216)=L2 @MP=192, pad->1280 ----
    PrepTab pt;
    static const int wIdx[8] = {3, 5, 8, 10, 12, 15, 17, 20};
    static const int wK[8]   = {INF_, INF_, INF_, HD, HD, HD, HD, HD};
    static const int wM[8]   = {HD, HD, HD, HD, HD, HC, HC, HC};
    static const int wMP[8]  = {128, 128, 128, 128, 128, 192, 192, 192};
    static const int wR0[8]  = {0, 128, 256, 384, 512, 640, 832, 1024};
    for (int i = 0; i < 8; ++i) {
        pt.src[i] = d_in[wIdx[i]]; pt.row0[i] = wR0[i];
        pt.K[i] = wK[i]; pt.M[i] = wM[i]; pt.MP[i] = wMP[i];
    }

    // ---- mega prepare (detect + cvt_x + weights + params + src offsets + ptr/hist) --
    const int prepGrid = (Nn * 128 + 255) / 256;   // 50000 blocks, covers all jobs
    prepare<<<prepGrid, 256, 0, stream>>>(x, src, dst, pt, tab, tot,
                                          xb, wtb, pb, w384, w256, ptr, cnt,
                                          bns0, bns1, flag);
    deg_totals<<<64, 256, 0, stream>>>(cnt, totals);
    deg_bases<<<64, 256, 0, stream>>>(cnt, totals, cbase);
    deg_scatter_blk<<<NBLK, 256, 0, stream>>>(ptr, cbase, perm);

    const int fusedGrid = (Nn + 3) / 4;   // 256-thread blocks, 4 dsts each
    const int statsGrid = NBLK;
    const int rowBlk = (Nn + 63) / 64;  // 1563

    // ---------------- layer 0 (384 cols: y=2 x CS=3) ----------------
    gemm_big<128, 3, 3, false, false, HD><<<dim3(rowBlk, 2), 256, 0, stream>>>(
        xb, wtb, bsrc0, bdst0, bres0, fs, fd, rb, HD, nullptr, nullptr, nullptr);
    gat_fused_128<false><<<fusedGrid, 256, 0, stream>>>(fs, fd, w256, ptr, perm,
                                                        attn0, rb, nullptr, nullptr,
                                                        nullptr, hbA);
    col_stats<<<statsGrid, 128, 0, stream>>>(hbA, bns0);

    // ---------------- layer 1 (256 cols: y=2 x CS=2) ----------------
    gemm_big<128, 2, 2, true, false, HD><<<dim3(rowBlk, 2), 256, 0, stream>>>(
        hbA, wtb + (size_t)384 * 128, bsrc1, bdst1, nullptr, fs, fd, nullptr, HD,
        bns0, g0, be0);
    gat_fused_128<true><<<fusedGrid, 256, 0, stream>>>(fs, fd, w256, ptr, perm,
                                                       attn1, hbA, bns0, g0, be0, hbB);
    col_stats<<<statsGrid, 128, 0, stream>>>(hbB, bns1);

    // ---------------- layer 2 (576 cols: y=3 x CS=3, split-pack coalesced outputs) --
    gemm_big<192, 3, 3, true, true, HCP><<<dim3(rowBlk, 3), 256, 0, stream>>>(
        hbB, wtb + (size_t)640 * 128, bsrc2, bdst2, bres2, fs, fd, rs, HC,
        bns1, g1, be1);
    gat_fused_188<<<fusedGrid, 256, 0, stream>>>(fs, fd, w384, ptr, perm, attn2, rs,
                                                 d_out, flag);
}